// Round 7
// baseline (3799.147 us; speedup 1.0000x reference)
//
#include <hip/hip_runtime.h>
#include <hip/hip_bf16.h>

// Shapes: B=4, N=8192, C=256, H=4, D=64, P=64
#define NN 8192
#define BNC 8388608   // B*N*C

typedef unsigned short u16;
typedef unsigned int u32;

__device__ __forceinline__ float bf2f(u16 u) {
    union { u32 i; float f; } c; c.i = ((u32)u) << 16; return c.f;
}
__device__ __forceinline__ u16 f2bf(float f) {
    union { float f; u32 i; } c; c.f = f;
    u32 x = c.i;
    u32 r = (x + 0x7fffu + ((x >> 16) & 1u)) >> 16;  // RNE
    return (u16)r;
}

// ---------------- diagnostic fill (fp32 now) ----------------
__global__ void fill_kernel(float* __restrict__ out, float val) {
    int base = (blockIdx.x * 256 + threadIdx.x) * 4;
    #pragma unroll
    for (int i = 0; i < 4; ++i) out[base + i] = val;
}

// ---------------- Q/K GEMM: Y = X @ W^T, bf16 out (naive 16x16 tiles) ----------------
__global__ void gemm_qk(const float* __restrict__ x, const float* __restrict__ q,
                        const float* __restrict__ Wq, const float* __restrict__ Wk,
                        u16* __restrict__ Qb, u16* __restrict__ Kb) {
    const int z = blockIdx.z;
    const float* X = z ? x : q;
    const float* W = z ? Wk : Wq;
    u16* Y = z ? Kb : Qb;
    const int m0 = blockIdx.x * 16, c0 = blockIdx.y * 16;
    const int t = threadIdx.x, i = t >> 4, j = t & 15;
    __shared__ float Wt[16][256];
    #pragma unroll
    for (int it = 0; it < 16; ++it) {
        int idx = t + it * 256, r = idx >> 8, k = idx & 255;
        Wt[r][k] = W[(size_t)(c0 + r) * 256 + k];
    }
    __syncthreads();
    float acc = 0.f;
    const float* Xrow = X + (size_t)(m0 + i) * 256;
    for (int k = 0; k < 256; ++k) acc += Xrow[k] * Wt[j][k];
    Y[(size_t)(m0 + i) * 256 + c0 + j] = f2bf(acc);
}

// ---------------- sum of squares over token dim ----------------
__global__ void sqnorm_kernel(const u16* __restrict__ Qb, const u16* __restrict__ Kb,
                              float* __restrict__ nq2, float* __restrict__ nk2) {
    const int b = blockIdx.x, which = blockIdx.y, c = threadIdx.x;
    const u16* S = which ? Kb : Qb;
    float* dst = which ? nk2 : nq2;
    float s = 0.f;
    for (int n = 0; n < NN; ++n) {
        float v = bf2f(S[((size_t)b * NN + n) * 256 + c]);
        s += v * v;
    }
    dst[b * 256 + c] = s;
}

// ---------------- xE[b,k,p] = sum_n x[b,n,k]*Ew[p,n]  (fp32) ----------------
__global__ void xe_kernel(const float* __restrict__ x, const float* __restrict__ Ew,
                          float* __restrict__ xE) {
    const int b = blockIdx.x >> 8, k = blockIdx.x & 255, p = threadIdx.x;
    const float* Erow = Ew + (size_t)p * NN;
    const float* xcol = x + (size_t)b * NN * 256 + k;
    float s = 0.f;
    for (int n = 0; n < NN; ++n) s += xcol[(size_t)n * 256] * Erow[n];
    xE[(size_t)(b * 256 + k) * 64 + p] = s;
}

// ---------------- kp/vp[b,c,p] = sum_k W[c,k]*xE[b,k,p] + E_b[p] ----------------
__global__ void kvproj_kernel(const float* __restrict__ Wk, const float* __restrict__ Wvsa,
                              const float* __restrict__ xE, const float* __restrict__ Eb,
                              float* __restrict__ kp, float* __restrict__ vp) {
    const int b = blockIdx.x >> 8, c = blockIdx.x & 255, z = blockIdx.y, p = threadIdx.x;
    const float* W = z ? Wvsa : Wk;
    float* dst = z ? vp : kp;
    float s = 0.f;
    for (int k = 0; k < 256; ++k)
        s += W[c * 256 + k] * xE[(size_t)(b * 256 + k) * 64 + p];
    dst[(size_t)(b * 256 + c) * 64 + p] = s + Eb[p];
}

// ---------------- calog[b,c,e] = sum_n Q[b,n,c]*K[b,n,(c&~63)+e] ----------------
__global__ void calog_kernel(const u16* __restrict__ Qb, const u16* __restrict__ Kb,
                             float* __restrict__ calog) {
    const int b = blockIdx.x >> 8, c = blockIdx.x & 255, e = threadIdx.x;
    const int ck = (c & 0xC0) + e;
    float s = 0.f;
    for (int n = 0; n < NN; ++n) {
        size_t base = ((size_t)b * NN + n) * 256;
        s += bf2f(Qb[base + c]) * bf2f(Kb[base + ck]);
    }
    calog[(size_t)blockIdx.x * 64 + e] = s;
}

// ---------------- channel-attn softmax (LDS tree) ----------------
__global__ void casoftmax_kernel(const float* __restrict__ calog, const float* __restrict__ nq2,
                                 const float* __restrict__ nk2, const float* __restrict__ temp,
                                 float* __restrict__ caprob) {
    const int row = blockIdx.x;
    const int b = row >> 8, c = row & 255, h = c >> 6;
    const int e = threadIdx.x;
    float nq = fmaxf(sqrtf(nq2[row]), 1e-12f);
    float nk = fmaxf(sqrtf(nk2[b * 256 + h * 64 + e]), 1e-12f);
    float v = calog[row * 64 + e] / (nq * nk) * temp[h];
    __shared__ float red[64];
    red[e] = v; __syncthreads();
    for (int s = 32; s; s >>= 1) { if (e < s) red[e] = fmaxf(red[e], red[e + s]); __syncthreads(); }
    float m = red[0]; __syncthreads();
    float ex = __expf(v - m);
    red[e] = ex; __syncthreads();
    for (int s = 32; s; s >>= 1) { if (e < s) red[e] += red[e + s]; __syncthreads(); }
    caprob[row * 64 + e] = ex / red[0];
}

// ---------------- M[b,j,c] = sum_d Wo2[j,(c&~63)+d]*caprob[...] ----------------
__global__ void buildm_kernel(const float* __restrict__ caprob, const float* __restrict__ Wo2,
                              float* __restrict__ M) {
    const int b = blockIdx.x >> 7, j = blockIdx.x & 127, c = threadIdx.x;
    const int h = c >> 6, e = c & 63;
    float s = 0.f;
    #pragma unroll 8
    for (int d = 0; d < 64; ++d)
        s += Wo2[j * 256 + h * 64 + d] * caprob[(size_t)(b * 256 + h * 64 + d) * 64 + e];
    M[(size_t)blockIdx.x * 256 + c] = s;
}

// ---------------- W2eff[b,j,k] = sum_c M[b,j,c]*Wvca[c,k] ----------------
__global__ void w2eff_kernel(const float* __restrict__ M, const float* __restrict__ Wvca,
                             float* __restrict__ W2eff) {
    const int k = threadIdx.x;
    const float* Mrow = M + (size_t)blockIdx.x * 256;
    float s = 0.f;
    for (int c = 0; c < 256; ++c) s += Mrow[c] * Wvca[c * 256 + k];
    W2eff[(size_t)blockIdx.x * 256 + k] = s;
}

// ---------------- CA half: out[:,128+j] = x @ W2eff[b]^T + bo2  (fp32 out) ----------------
__global__ void outca_kernel(const float* __restrict__ x, const float* __restrict__ W2eff,
                             const float* __restrict__ bo2, float* __restrict__ out) {
    const int m0 = blockIdx.x * 16, j0 = blockIdx.y * 16;
    const int b = blockIdx.x >> 9;
    const int t = threadIdx.x, i = t >> 4, j = t & 15;
    __shared__ float Wt[16][256];
    #pragma unroll
    for (int it = 0; it < 16; ++it) {
        int idx = t + it * 256, r = idx >> 8, k = idx & 255;
        Wt[r][k] = W2eff[(size_t)(b * 128 + j0 + r) * 256 + k];
    }
    __syncthreads();
    float acc = 0.f;
    const float* Xrow = x + (size_t)(m0 + i) * 256;
    for (int k = 0; k < 256; ++k) acc += Xrow[k] * Wt[j][k];
    out[(size_t)(m0 + i) * 256 + 128 + j0 + j] = acc + bo2[j0 + j];
}

// ---------------- NAIVE spatial attention, one block per (b,h,n) ----------------
__global__ void sa_attn_kernel(const u16* __restrict__ Qb, const float* __restrict__ kp,
                               const float* __restrict__ vp, const float* __restrict__ nq2,
                               const float* __restrict__ temp2, u16* __restrict__ xsa) {
    const int n = blockIdx.x, b = blockIdx.y >> 2, h = blockIdx.y & 3;
    const int t = threadIdx.x;
    __shared__ float qrow[64];
    __shared__ float prob[64];
    __shared__ float red[64];
    float rq = 1.f / fmaxf(sqrtf(nq2[b * 256 + h * 64 + t]), 1e-12f);
    qrow[t] = bf2f(Qb[((size_t)b * NN + n) * 256 + h * 64 + t]) * rq;
    __syncthreads();

    const float* kpb = kp + (size_t)(b * 256 + h * 64) * 64;
    float s = 0.f;
    for (int d = 0; d < 64; ++d) s += qrow[d] * kpb[d * 64 + t];
    s *= temp2[h];
    red[t] = s; __syncthreads();
    for (int o = 32; o; o >>= 1) { if (t < o) red[t] = fmaxf(red[t], red[t + o]); __syncthreads(); }
    float m = red[0]; __syncthreads();
    float ex = __expf(s - m);
    red[t] = ex; __syncthreads();
    for (int o = 32; o; o >>= 1) { if (t < o) red[t] += red[t + o]; __syncthreads(); }
    prob[t] = ex / red[0];
    __syncthreads();

    const float* vpb = vp + (size_t)(b * 256 + h * 64) * 64;
    float o = 0.f;
    for (int p = 0; p < 64; ++p) o += prob[p] * vpb[t * 64 + p];

    // scrambled store: row = d*128 + h*32 + (n>>8), col = n&255
    xsa[((size_t)b * NN + t * 128 + h * 32 + (n >> 8)) * 256 + (n & 255)] = f2bf(o);
}

// ---------------- SA half: out[:,0:128] = xsa_scr @ Wo1^T + bo1  (fp32 out) ----------------
__global__ void outsa_kernel(const u16* __restrict__ xsa, const float* __restrict__ Wo1,
                             const float* __restrict__ bo1, float* __restrict__ out) {
    const int m0 = blockIdx.x * 16, j0 = blockIdx.y * 16;
    const int t = threadIdx.x, i = t >> 4, j = t & 15;
    __shared__ float Wt[16][256];
    #pragma unroll
    for (int it = 0; it < 16; ++it) {
        int idx = t + it * 256, r = idx >> 8, k = idx & 255;
        Wt[r][k] = Wo1[(size_t)(j0 + r) * 256 + k];
    }
    __syncthreads();
    float acc = 0.f;
    const u16* Xrow = xsa + (size_t)(m0 + i) * 256;
    for (int k = 0; k < 256; ++k) acc += bf2f(Xrow[k]) * Wt[j][k];
    out[(size_t)(m0 + i) * 256 + j0 + j] = acc + bo1[j0 + j];
}

extern "C" void kernel_launch(void* const* d_in, const int* in_sizes, int n_in,
                              void* d_out, int out_size, void* d_ws, size_t ws_size,
                              hipStream_t stream) {
    float* out = (float*)d_out;

    static const int expect[14] = {8388608, 8388608, 65536, 65536, 65536, 65536,
                                   524288, 64, 4, 4, 32768, 128, 32768, 128};
    bool ok = (n_in == 14) && (out_size == 8388608);
    if (ok) for (int i = 0; i < 14; ++i) ok = ok && (in_sizes[i] == expect[i]);
    if (!ok) {
        fill_kernel<<<dim3(8192), 256, 0, stream>>>(out, 3000.0f);
        return;
    }
    if (ws_size < 36000000u) {
        fill_kernel<<<dim3(8192), 256, 0, stream>>>(out, 1000.0f);
        return;
    }

    const float* x    = (const float*)d_in[0];
    const float* q    = (const float*)d_in[1];
    const float* Wq   = (const float*)d_in[2];
    const float* Wk   = (const float*)d_in[3];
    const float* Wvca = (const float*)d_in[4];
    const float* Wvsa = (const float*)d_in[5];
    const float* Ew   = (const float*)d_in[6];
    const float* Eb   = (const float*)d_in[7];
    const float* temp = (const float*)d_in[8];
    const float* temp2= (const float*)d_in[9];
    const float* Wo1  = (const float*)d_in[10];
    const float* bo1  = (const float*)d_in[11];
    const float* Wo2  = (const float*)d_in[12];
    const float* bo2  = (const float*)d_in[13];

    u16* Qb = (u16*)d_ws;
    u16* Kb = Qb + (size_t)BNC;          // reused as xsa after calog (stream-ordered)
    u16* xsa = Kb;
    float* fs    = (float*)(Kb + (size_t)BNC);
    float* nq2   = fs;
    float* nk2   = nq2 + 1024;
    float* xE    = nk2 + 1024;
    float* kp    = xE + 65536;
    float* vp    = kp + 65536;
    float* calog = vp + 65536;
    float* caprob= calog + 65536;
    float* M     = caprob + 65536;
    float* W2eff = M + 131072;

    gemm_qk<<<dim3(2048, 16, 2), 256, 0, stream>>>(x, q, Wq, Wk, Qb, Kb);
    sqnorm_kernel<<<dim3(4, 2), 256, 0, stream>>>(Qb, Kb, nq2, nk2);
    xe_kernel<<<dim3(1024), 64, 0, stream>>>(x, Ew, xE);
    kvproj_kernel<<<dim3(1024, 2), 64, 0, stream>>>(Wk, Wvsa, xE, Eb, kp, vp);
    calog_kernel<<<dim3(1024), 64, 0, stream>>>(Qb, Kb, calog);
    casoftmax_kernel<<<dim3(1024), 64, 0, stream>>>(calog, nq2, nk2, temp, caprob);
    buildm_kernel<<<dim3(512), 256, 0, stream>>>(caprob, Wo2, M);
    w2eff_kernel<<<dim3(512), 256, 0, stream>>>(M, Wvca, W2eff);
    outca_kernel<<<dim3(2048, 8), 256, 0, stream>>>(x, W2eff, bo2, out);
    sa_attn_kernel<<<dim3(8192, 16), 64, 0, stream>>>(Qb, kp, vp, nq2, temp2, xsa);
    outsa_kernel<<<dim3(2048, 8), 256, 0, stream>>>(xsa, Wo1, bo1, out);
}

// Round 8
// 522.341 us; speedup vs baseline: 7.2733x; 7.2733x over previous
//
#include <hip/hip_runtime.h>
#include <hip/hip_bf16.h>

// Shapes: B=4, N=8192, C=256, H=4, D=64, P=64
#define NN 8192
#define BNC 8388608   // B*N*C

typedef unsigned short u16;
typedef unsigned int u32;
typedef __attribute__((ext_vector_type(8))) short bf16x8;
typedef __attribute__((ext_vector_type(4))) float f32x4;
typedef __attribute__((ext_vector_type(4))) float float4v;

__device__ __forceinline__ float bf2f(u16 u) {
    union { u32 i; float f; } c; c.i = ((u32)u) << 16; return c.f;
}
__device__ __forceinline__ u16 f2bf(float f) {
    union { float f; u32 i; } c; c.f = f;
    u32 x = c.i;
    u32 r = (x + 0x7fffu + ((x >> 16) & 1u)) >> 16;  // RNE
    return (u16)r;
}

// ---------------- diagnostic fill ----------------
__global__ void fill_kernel(float* __restrict__ out, float val) {
    int base = (blockIdx.x * 256 + threadIdx.x) * 4;
    #pragma unroll
    for (int i = 0; i < 4; ++i) out[base + i] = val;
}

// ---------------- zero ----------------
__global__ void zero_kernel(float* __restrict__ p, int n) {
    int i = blockIdx.x * 256 + threadIdx.x;
    if (i < n) p[i] = 0.f;
}

// ================= MFMA GEMM: C[M][*] = A[M][256] @ Bt[N][256]^T =================
// 128x128 tile, 4 waves, each wave 64x64 = 4x4 frags of 16x16, BK=32, K=256.
// ABF: A is bf16 (else fp32, converted during staging). Bt always fp32.
// OBF: write bf16 to Obf[.][256]; else fp32 to Of[.][256] at outoff with bias.
template<int ABF, int OBF>
__global__ __launch_bounds__(256) void gemm128(
    const void* __restrict__ Avoid, const float* __restrict__ Bt, long btstride,
    u16* __restrict__ Obf, float* __restrict__ Of,
    const float* __restrict__ bias, int outoff)
{
    __shared__ u16 As[4096];   // [128][32] bf16 linear
    __shared__ u16 Bs[4096];
    const int t = threadIdx.x, lane = t & 63, w = t >> 6;
    const int wr = w >> 1, wc = w & 1;
    const int fr = lane & 15, fk = (lane >> 4) * 8, r0 = (lane >> 4) * 4;
    const int m0 = blockIdx.x * 128, n0 = blockIdx.y * 128;
    const float* Af = (const float*)Avoid;
    const u16*   Ab = (const u16*)Avoid;
    const float* Btb = Bt + (btstride ? (size_t)(blockIdx.x >> 6) * (size_t)btstride : 0);

    f32x4 acc[4][4];
    #pragma unroll
    for (int i = 0; i < 4; ++i)
        #pragma unroll
        for (int j = 0; j < 4; ++j) acc[i][j] = (f32x4){0.f, 0.f, 0.f, 0.f};

    for (int kt = 0; kt < 8; ++kt) {
        const int k0 = kt * 32;
        #pragma unroll
        for (int i = 0; i < 2; ++i) {
            int c = i * 256 + t, row = c >> 2, k8 = (c & 3) * 8;
            bf16x8 va;
            if (ABF) {
                va = *(const bf16x8*)(Ab + (size_t)(m0 + row) * 256 + k0 + k8);
            } else {
                const float* p = Af + (size_t)(m0 + row) * 256 + k0 + k8;
                float4v f0 = *(const float4v*)p, f1 = *(const float4v*)(p + 4);
                #pragma unroll
                for (int j = 0; j < 4; ++j) {
                    va[j] = (short)f2bf(f0[j]); va[4 + j] = (short)f2bf(f1[j]);
                }
            }
            *(bf16x8*)&As[c * 8] = va;
            const float* pb = Btb + (size_t)(n0 + row) * 256 + k0 + k8;
            float4v g0 = *(const float4v*)pb, g1 = *(const float4v*)(pb + 4);
            bf16x8 vb;
            #pragma unroll
            for (int j = 0; j < 4; ++j) {
                vb[j] = (short)f2bf(g0[j]); vb[4 + j] = (short)f2bf(g1[j]);
            }
            *(bf16x8*)&Bs[c * 8] = vb;
        }
        __syncthreads();
        bf16x8 a[4], b[4];
        #pragma unroll
        for (int fm = 0; fm < 4; ++fm)
            a[fm] = *(const bf16x8*)&As[(wr * 64 + fm * 16 + fr) * 32 + fk];
        #pragma unroll
        for (int fn = 0; fn < 4; ++fn)
            b[fn] = *(const bf16x8*)&Bs[(wc * 64 + fn * 16 + fr) * 32 + fk];
        #pragma unroll
        for (int fm = 0; fm < 4; ++fm)
            #pragma unroll
            for (int fn = 0; fn < 4; ++fn)
                acc[fm][fn] = __builtin_amdgcn_mfma_f32_16x16x32_bf16(
                    a[fm], b[fn], acc[fm][fn], 0, 0, 0);
        __syncthreads();
    }

    #pragma unroll
    for (int fm = 0; fm < 4; ++fm)
        #pragma unroll
        for (int fn = 0; fn < 4; ++fn) {
            int gcol = n0 + wc * 64 + fn * 16 + fr;
            #pragma unroll
            for (int r = 0; r < 4; ++r) {
                size_t grow = (size_t)(m0 + wr * 64 + fm * 16 + r0 + r);
                float v = acc[fm][fn][r];
                if (OBF) Obf[grow * 256 + gcol] = f2bf(v);
                else     Of[grow * 256 + outoff + gcol] = v + bias[gcol];
            }
        }
}

// ================= sqnorm (chunked + atomic) =================
// grid (4 b, 2 which, 16 chunk), 256 thr
__global__ void sqnorm_kernel(const u16* __restrict__ Qb, const u16* __restrict__ Kb,
                              float* __restrict__ nq2, float* __restrict__ nk2) {
    const int b = blockIdx.x, which = blockIdx.y, ch = blockIdx.z;
    const u16* S = which ? Kb : Qb;
    float* dst = which ? nk2 : nq2;
    const int c = threadIdx.x;
    float s = 0.f;
    for (int n = ch * 512; n < ch * 512 + 512; ++n) {
        float v = bf2f(S[((size_t)b * NN + n) * 256 + c]);
        s += v * v;
    }
    atomicAdd(&dst[b * 256 + c], s);
}

// ================= xE tiled: xE[b,k,p] += sum_n x[b,n,k]*Ew[p,n] =================
// grid (4 b, 4 kq, 16 nc), 256 thr
__global__ void xe_tiled(const float* __restrict__ x, const float* __restrict__ Ew,
                         float* __restrict__ xE) {
    __shared__ float xs[64][68];   // [nn][k-local]
    __shared__ float es[64][68];   // [nn][p]
    const int b = blockIdx.x, kq = blockIdx.y, nc = blockIdx.z;
    const int t = threadIdx.x;
    const int kk = t >> 2, pq = (t & 3) * 16;
    float acc[16];
    #pragma unroll
    for (int j = 0; j < 16; ++j) acc[j] = 0.f;

    for (int st = 0; st < 8; ++st) {
        const int n0 = nc * 512 + st * 64;
        {
            int nn = t >> 2, kl = (t & 3) * 16;
            const float* p = x + ((size_t)b * NN + n0 + nn) * 256 + kq * 64 + kl;
            *(float4v*)&xs[nn][kl]      = *(const float4v*)p;
            *(float4v*)&xs[nn][kl + 4]  = *(const float4v*)(p + 4);
            *(float4v*)&xs[nn][kl + 8]  = *(const float4v*)(p + 8);
            *(float4v*)&xs[nn][kl + 12] = *(const float4v*)(p + 12);
        }
        {
            int pp = t >> 2, nq = (t & 3) * 16;
            const float* p = Ew + (size_t)pp * NN + n0 + nq;
            #pragma unroll
            for (int j = 0; j < 16; ++j) es[nq + j][pp] = p[j];
        }
        __syncthreads();
        for (int nn = 0; nn < 64; ++nn) {
            float a = xs[nn][kk];
            float4v e0 = *(const float4v*)&es[nn][pq];
            float4v e1 = *(const float4v*)&es[nn][pq + 4];
            float4v e2 = *(const float4v*)&es[nn][pq + 8];
            float4v e3 = *(const float4v*)&es[nn][pq + 12];
            #pragma unroll
            for (int j = 0; j < 4; ++j) {
                acc[j]      += a * e0[j];
                acc[4 + j]  += a * e1[j];
                acc[8 + j]  += a * e2[j];
                acc[12 + j] += a * e3[j];
            }
        }
        __syncthreads();
    }
    const int base = (b * 256 + kq * 64 + kk) * 64 + pq;
    #pragma unroll
    for (int j = 0; j < 16; ++j) atomicAdd(&xE[base + j], acc[j]);
}

// ---------------- kp/vp[b,c,p] = sum_k W[c,k]*xE[b,k,p] + E_b[p] (kept) ----------------
__global__ void kvproj_kernel(const float* __restrict__ Wk, const float* __restrict__ Wvsa,
                              const float* __restrict__ xE, const float* __restrict__ Eb,
                              float* __restrict__ kp, float* __restrict__ vp) {
    const int b = blockIdx.x >> 8, c = blockIdx.x & 255, z = blockIdx.y, p = threadIdx.x;
    const float* W = z ? Wvsa : Wk;
    float* dst = z ? vp : kp;
    float s = 0.f;
    for (int k = 0; k < 256; ++k)
        s += W[c * 256 + k] * xE[(size_t)(b * 256 + k) * 64 + p];
    dst[(size_t)(b * 256 + c) * 64 + p] = s + Eb[p];
}

// ---------------- calog (kept naive, validated) ----------------
__global__ void calog_kernel(const u16* __restrict__ Qb, const u16* __restrict__ Kb,
                             float* __restrict__ calog) {
    const int b = blockIdx.x >> 8, c = blockIdx.x & 255, e = threadIdx.x;
    const int ck = (c & 0xC0) + e;
    float s = 0.f;
    for (int n = 0; n < NN; ++n) {
        size_t base = ((size_t)b * NN + n) * 256;
        s += bf2f(Qb[base + c]) * bf2f(Kb[base + ck]);
    }
    calog[(size_t)blockIdx.x * 64 + e] = s;
}

// ---------------- casoftmax (kept) ----------------
__global__ void casoftmax_kernel(const float* __restrict__ calog, const float* __restrict__ nq2,
                                 const float* __restrict__ nk2, const float* __restrict__ temp,
                                 float* __restrict__ caprob) {
    const int row = blockIdx.x;
    const int b = row >> 8, c = row & 255, h = c >> 6;
    const int e = threadIdx.x;
    float nq = fmaxf(sqrtf(nq2[row]), 1e-12f);
    float nk = fmaxf(sqrtf(nk2[b * 256 + h * 64 + e]), 1e-12f);
    float v = calog[row * 64 + e] / (nq * nk) * temp[h];
    __shared__ float red[64];
    red[e] = v; __syncthreads();
    for (int s = 32; s; s >>= 1) { if (e < s) red[e] = fmaxf(red[e], red[e + s]); __syncthreads(); }
    float m = red[0]; __syncthreads();
    float ex = __expf(v - m);
    red[e] = ex; __syncthreads();
    for (int s = 32; s; s >>= 1) { if (e < s) red[e] += red[e + s]; __syncthreads(); }
    caprob[row * 64 + e] = ex / red[0];
}

// ---------------- buildm (kept) ----------------
__global__ void buildm_kernel(const float* __restrict__ caprob, const float* __restrict__ Wo2,
                              float* __restrict__ M) {
    const int b = blockIdx.x >> 7, j = blockIdx.x & 127, c = threadIdx.x;
    const int h = c >> 6, e = c & 63;
    float s = 0.f;
    #pragma unroll 8
    for (int d = 0; d < 64; ++d)
        s += Wo2[j * 256 + h * 64 + d] * caprob[(size_t)(b * 256 + h * 64 + d) * 64 + e];
    M[(size_t)blockIdx.x * 256 + c] = s;
}

// ---------------- w2eff (kept) ----------------
__global__ void w2eff_kernel(const float* __restrict__ M, const float* __restrict__ Wvca,
                             float* __restrict__ W2eff) {
    const int k = threadIdx.x;
    const float* Mrow = M + (size_t)blockIdx.x * 256;
    float s = 0.f;
    for (int c = 0; c < 256; ++c) s += Mrow[c] * Wvca[c * 256 + k];
    W2eff[(size_t)blockIdx.x * 256 + k] = s;
}

// ================= MFMA spatial attention =================
// grid (32 nc, 16 bh), 256 thr. Per block: 256 tokens of one (b,h).
// S = Q @ (kp*rq*t2) ; P = softmax(S) ; X = P @ vp^T ; scrambled coalesced store.
__global__ __launch_bounds__(256) void sa_mfma(
    const u16* __restrict__ Qb, const float* __restrict__ kp,
    const float* __restrict__ vp, const float* __restrict__ nq2,
    const float* __restrict__ temp2, u16* __restrict__ xsa)
{
    __shared__ char smem[49152];
    u16* Qs = (u16*)smem;               // phase1: [256 tok][64 d] ; phase2: Pl[4][64][64] ; phase3: X2[256][64]
    u16* KT = (u16*)(smem + 32768);     // [64 p][64 d], pre-scaled by rq[d]*t2
    u16* VT = (u16*)(smem + 40960);     // [64 d][64 p]
    const int nc = blockIdx.x, bh = blockIdx.y, b = bh >> 2, h = bh & 3;
    const int t = threadIdx.x, lane = t & 63, w = t >> 6;
    const int fr = lane & 15, fk = (lane >> 4) * 8, r0 = (lane >> 4) * 4;

    // stage Qs [tok][d]
    #pragma unroll
    for (int i = 0; i < 8; ++i) {
        int c = i * 256 + t, tok = c >> 3, ch8 = (c & 7) * 8;
        *(bf16x8*)&Qs[c * 8] =
            *(const bf16x8*)(Qb + ((size_t)b * NN + nc * 256 + tok) * 256 + h * 64 + ch8);
    }
    // stage KT[p][d] = kp[d][p] * rq[d] * t2
    {
        const int d = t >> 2, p0 = (t & 3) * 16;
        const float rqv = 1.0f / fmaxf(sqrtf(nq2[b * 256 + h * 64 + d]), 1e-12f);
        const float t2 = temp2[h];
        const float* kr = kp + (size_t)(b * 256 + h * 64 + d) * 64 + p0;
        #pragma unroll
        for (int j = 0; j < 16; ++j)
            KT[(p0 + j) * 64 + d] = f2bf(kr[j] * rqv * t2);
    }
    // stage VT[d][p] = vp[d][p]
    {
        const float* vs = vp + (size_t)(b * 256 + h * 64) * 64;
        #pragma unroll
        for (int i = 0; i < 2; ++i) {
            int c = i * 256 + t;
            bf16x8 v;
            #pragma unroll
            for (int j = 0; j < 8; ++j) v[j] = (short)f2bf(vs[c * 8 + j]);
            *(bf16x8*)&VT[c * 8] = v;
        }
    }
    __syncthreads();

    // QK^T: wave w owns tokens w*64 .. w*64+63
    f32x4 acc[4][4];
    #pragma unroll
    for (int i = 0; i < 4; ++i)
        #pragma unroll
        for (int j = 0; j < 4; ++j) acc[i][j] = (f32x4){0.f, 0.f, 0.f, 0.f};
    #pragma unroll
    for (int ks = 0; ks < 2; ++ks) {
        bf16x8 a[4], bb[4];
        #pragma unroll
        for (int fm = 0; fm < 4; ++fm)
            a[fm] = *(const bf16x8*)&Qs[(w * 64 + fm * 16 + fr) * 64 + ks * 32 + fk];
        #pragma unroll
        for (int fn = 0; fn < 4; ++fn)
            bb[fn] = *(const bf16x8*)&KT[(fn * 16 + fr) * 64 + ks * 32 + fk];
        #pragma unroll
        for (int fm = 0; fm < 4; ++fm)
            #pragma unroll
            for (int fn = 0; fn < 4; ++fn)
                acc[fm][fn] = __builtin_amdgcn_mfma_f32_16x16x32_bf16(
                    a[fm], bb[fn], acc[fm][fn], 0, 0, 0);
    }
    __syncthreads();   // all waves done reading Qs; Qs region becomes Pl

    // softmax per row, write P (bf16) to per-wave region
    u16* Pw = Qs + w * 4096;
    #pragma unroll
    for (int fm = 0; fm < 4; ++fm) {
        #pragma unroll
        for (int r = 0; r < 4; ++r) {
            float m = fmaxf(fmaxf(acc[fm][0][r], acc[fm][1][r]),
                            fmaxf(acc[fm][2][r], acc[fm][3][r]));
            m = fmaxf(m, __shfl_xor(m, 1));
            m = fmaxf(m, __shfl_xor(m, 2));
            m = fmaxf(m, __shfl_xor(m, 4));
            m = fmaxf(m, __shfl_xor(m, 8));
            float e0 = __expf(acc[fm][0][r] - m), e1 = __expf(acc[fm][1][r] - m);
            float e2 = __expf(acc[fm][2][r] - m), e3 = __expf(acc[fm][3][r] - m);
            float s = e0 + e1 + e2 + e3;
            s += __shfl_xor(s, 1); s += __shfl_xor(s, 2);
            s += __shfl_xor(s, 4); s += __shfl_xor(s, 8);
            float rs = 1.0f / s;
            int row = fm * 16 + r0 + r;
            Pw[row * 64 +  0 + fr] = f2bf(e0 * rs);
            Pw[row * 64 + 16 + fr] = f2bf(e1 * rs);
            Pw[row * 64 + 32 + fr] = f2bf(e2 * rs);
            Pw[row * 64 + 48 + fr] = f2bf(e3 * rs);
        }
    }

    // PV
    f32x4 acc2[4][4];
    #pragma unroll
    for (int i = 0; i < 4; ++i)
        #pragma unroll
        for (int j = 0; j < 4; ++j) acc2[i][j] = (f32x4){0.f, 0.f, 0.f, 0.f};
    #pragma unroll
    for (int ks = 0; ks < 2; ++ks) {
        bf16x8 a[4], bb[4];
        #pragma unroll
        for (int fm = 0; fm < 4; ++fm)
            a[fm] = *(const bf16x8*)&Pw[(fm * 16 + fr) * 64 + ks * 32 + fk];
        #pragma unroll
        for (int fn = 0; fn < 4; ++fn)
            bb[fn] = *(const bf16x8*)&VT[(fn * 16 + fr) * 64 + ks * 32 + fk];
        #pragma unroll
        for (int fm = 0; fm < 4; ++fm)
            #pragma unroll
            for (int fn = 0; fn < 4; ++fn)
                acc2[fm][fn] = __builtin_amdgcn_mfma_f32_16x16x32_bf16(
                    a[fm], bb[fn], acc2[fm][fn], 0, 0, 0);
    }
    __syncthreads();   // P dead; region becomes X2

    // X2[tok][d]
    u16* X2 = Qs;
    #pragma unroll
    for (int fm = 0; fm < 4; ++fm)
        #pragma unroll
        for (int fn = 0; fn < 4; ++fn)
            #pragma unroll
            for (int r = 0; r < 4; ++r)
                X2[(w * 64 + fm * 16 + r0 + r) * 64 + fn * 16 + fr] = f2bf(acc2[fm][fn][r]);
    __syncthreads();

    // coalesced scrambled store: out-row = d*128 + h*32 + nc, cols = token&255
    {
        const int d = t >> 2, cq = (t & 3) * 64;
        u16* orow = xsa + ((size_t)b * NN + d * 128 + h * 32 + nc) * 256 + cq;
        #pragma unroll
        for (int i = 0; i < 8; ++i) {
            bf16x8 v;
            #pragma unroll
            for (int j = 0; j < 8; ++j) v[j] = (short)X2[(cq + i * 8 + j) * 64 + d];
            *(bf16x8*)&orow[i * 8] = v;
        }
    }
}

extern "C" void kernel_launch(void* const* d_in, const int* in_sizes, int n_in,
                              void* d_out, int out_size, void* d_ws, size_t ws_size,
                              hipStream_t stream) {
    float* out = (float*)d_out;

    static const int expect[14] = {8388608, 8388608, 65536, 65536, 65536, 65536,
                                   524288, 64, 4, 4, 32768, 128, 32768, 128};
    bool ok = (n_in == 14) && (out_size == 8388608);
    if (ok) for (int i = 0; i < 14; ++i) ok = ok && (in_sizes[i] == expect[i]);
    if (!ok) {
        fill_kernel<<<dim3(8192), 256, 0, stream>>>(out, 3000.0f);
        return;
    }
    if (ws_size < 36000000u) {
        fill_kernel<<<dim3(8192), 256, 0, stream>>>(out, 1000.0f);
        return;
    }

    const float* x    = (const float*)d_in[0];
    const float* q    = (const float*)d_in[1];
    const float* Wq   = (const float*)d_in[2];
    const float* Wk   = (const float*)d_in[3];
    const float* Wvca = (const float*)d_in[4];
    const float* Wvsa = (const float*)d_in[5];
    const float* Ew   = (const float*)d_in[6];
    const float* Eb   = (const float*)d_in[7];
    const float* temp = (const float*)d_in[8];
    const float* temp2= (const float*)d_in[9];
    const float* Wo1  = (const float*)d_in[10];
    const float* bo1  = (const float*)d_in[11];
    const float* Wo2  = (const float*)d_in[12];
    const float* bo2  = (const float*)d_in[13];

    u16* Qb = (u16*)d_ws;
    u16* Kb = Qb + (size_t)BNC;          // reused as xsa after calog (stream-ordered)
    u16* xsa = Kb;
    float* fs    = (float*)(Kb + (size_t)BNC);
    float* nq2   = fs;                   // 1024
    float* nk2   = nq2 + 1024;           // 1024
    float* xE    = nk2 + 1024;           // 65536
    float* kp    = xE + 65536;           // 65536
    float* vp    = kp + 65536;           // 65536
    float* calog = vp + 65536;           // 65536
    float* caprob= calog + 65536;        // 65536
    float* M     = caprob + 65536;       // 131072
    float* W2eff = M + 131072;           // 131072

    zero_kernel<<<dim3(264), 256, 0, stream>>>(nq2, 67584);   // nq2,nk2,xE
    gemm128<0, 1><<<dim3(256, 2), 256, 0, stream>>>(q, Wq, 0, Qb, nullptr, nullptr, 0);
    gemm128<0, 1><<<dim3(256, 2), 256, 0, stream>>>(x, Wk, 0, Kb, nullptr, nullptr, 0);
    sqnorm_kernel<<<dim3(4, 2, 16), 256, 0, stream>>>(Qb, Kb, nq2, nk2);
    xe_tiled<<<dim3(4, 4, 16), 256, 0, stream>>>(x, Ew, xE);
    kvproj_kernel<<<dim3(1024, 2), 64, 0, stream>>>(Wk, Wvsa, xE, Eb, kp, vp);
    calog_kernel<<<dim3(1024), 64, 0, stream>>>(Qb, Kb, calog);
    casoftmax_kernel<<<dim3(1024), 64, 0, stream>>>(calog, nq2, nk2, temp, caprob);
    buildm_kernel<<<dim3(512), 256, 0, stream>>>(caprob, Wo2, M);
    w2eff_kernel<<<dim3(512), 256, 0, stream>>>(M, Wvca, W2eff);
    gemm128<0, 0><<<dim3(256, 1), 256, 0, stream>>>(x, W2eff, 128 * 256, nullptr, out, bo2, 128);
    sa_mfma<<<dim3(32, 16), 256, 0, stream>>>(Qb, kp, vp, nq2, temp2, xsa);
    gemm128<1, 0><<<dim3(256, 1), 256, 0, stream>>>(xsa, Wo1, 0, nullptr, out, bo1, 0);
}

// Round 10
// 258.704 us; speedup vs baseline: 14.6853x; 2.0191x over previous
//
#include <hip/hip_runtime.h>
#include <hip/hip_bf16.h>

// Shapes: B=4, N=8192, C=256, H=4, D=64, P=64
#define NN 8192
#define BNC 8388608   // B*N*C

typedef unsigned short u16;
typedef unsigned int u32;
typedef __attribute__((ext_vector_type(8))) short bf16x8;
typedef __attribute__((ext_vector_type(4))) float f32x4;
typedef __attribute__((ext_vector_type(4))) float float4v;

__device__ __forceinline__ float bf2f(u16 u) {
    union { u32 i; float f; } c; c.i = ((u32)u) << 16; return c.f;
}
__device__ __forceinline__ u16 f2bf(float f) {
    union { float f; u32 i; } c; c.f = f;
    u32 x = c.i;
    u32 r = (x + 0x7fffu + ((x >> 16) & 1u)) >> 16;  // RNE
    return (u16)r;
}

// ---------------- diagnostic fill ----------------
__global__ void fill_kernel(float* __restrict__ out, float val) {
    int base = (blockIdx.x * 256 + threadIdx.x) * 4;
    #pragma unroll
    for (int i = 0; i < 4; ++i) out[base + i] = val;
}

// ---------------- zero ----------------
__global__ void zero_kernel(float* __restrict__ p, int n) {
    int i = blockIdx.x * 256 + threadIdx.x;
    if (i < n) p[i] = 0.f;
}

// ================= MFMA GEMM: C[M][*] = A[M][256] @ Bt[N][256]^T =================
// 128x128 tile, 4 waves, each wave 64x64 = 4x4 frags of 16x16, BK=32, K=256.
template<int ABF, int OBF>
__global__ __launch_bounds__(256) void gemm128(
    const void* __restrict__ Avoid, const float* __restrict__ Bt, long btstride,
    u16* __restrict__ Obf, float* __restrict__ Of,
    const float* __restrict__ bias, int outoff)
{
    __shared__ u16 As[4096];   // [128][32] bf16 linear
    __shared__ u16 Bs[4096];
    const int t = threadIdx.x, lane = t & 63, w = t >> 6;
    const int wr = w >> 1, wc = w & 1;
    const int fr = lane & 15, fk = (lane >> 4) * 8, r0 = (lane >> 4) * 4;
    const int m0 = blockIdx.x * 128, n0 = blockIdx.y * 128;
    const float* Af = (const float*)Avoid;
    const u16*   Ab = (const u16*)Avoid;
    const float* Btb = Bt + (btstride ? (size_t)(blockIdx.x >> 6) * (size_t)btstride : 0);

    f32x4 acc[4][4];
    #pragma unroll
    for (int i = 0; i < 4; ++i)
        #pragma unroll
        for (int j = 0; j < 4; ++j) acc[i][j] = (f32x4){0.f, 0.f, 0.f, 0.f};

    for (int kt = 0; kt < 8; ++kt) {
        const int k0 = kt * 32;
        #pragma unroll
        for (int i = 0; i < 2; ++i) {
            int c = i * 256 + t, row = c >> 2, k8 = (c & 3) * 8;
            bf16x8 va;
            if (ABF) {
                va = *(const bf16x8*)(Ab + (size_t)(m0 + row) * 256 + k0 + k8);
            } else {
                const float* p = Af + (size_t)(m0 + row) * 256 + k0 + k8;
                float4v f0 = *(const float4v*)p, f1 = *(const float4v*)(p + 4);
                #pragma unroll
                for (int j = 0; j < 4; ++j) {
                    va[j] = (short)f2bf(f0[j]); va[4 + j] = (short)f2bf(f1[j]);
                }
            }
            *(bf16x8*)&As[c * 8] = va;
            const float* pb = Btb + (size_t)(n0 + row) * 256 + k0 + k8;
            float4v g0 = *(const float4v*)pb, g1 = *(const float4v*)(pb + 4);
            bf16x8 vb;
            #pragma unroll
            for (int j = 0; j < 4; ++j) {
                vb[j] = (short)f2bf(g0[j]); vb[4 + j] = (short)f2bf(g1[j]);
            }
            *(bf16x8*)&Bs[c * 8] = vb;
        }
        __syncthreads();
        bf16x8 a[4], b[4];
        #pragma unroll
        for (int fm = 0; fm < 4; ++fm)
            a[fm] = *(const bf16x8*)&As[(wr * 64 + fm * 16 + fr) * 32 + fk];
        #pragma unroll
        for (int fn = 0; fn < 4; ++fn)
            b[fn] = *(const bf16x8*)&Bs[(wc * 64 + fn * 16 + fr) * 32 + fk];
        #pragma unroll
        for (int fm = 0; fm < 4; ++fm)
            #pragma unroll
            for (int fn = 0; fn < 4; ++fn)
                acc[fm][fn] = __builtin_amdgcn_mfma_f32_16x16x32_bf16(
                    a[fm], b[fn], acc[fm][fn], 0, 0, 0);
        __syncthreads();
    }

    #pragma unroll
    for (int fm = 0; fm < 4; ++fm)
        #pragma unroll
        for (int fn = 0; fn < 4; ++fn) {
            int gcol = n0 + wc * 64 + fn * 16 + fr;
            #pragma unroll
            for (int r = 0; r < 4; ++r) {
                size_t grow = (size_t)(m0 + wr * 64 + fm * 16 + r0 + r);
                float v = acc[fm][fn][r];
                if (OBF) Obf[grow * 256 + gcol] = f2bf(v);
                else     Of[grow * 256 + outoff + gcol] = v + bias[gcol];
            }
        }
}

// ================= sqnorm (chunked + atomic; replay-stable since R8) =================
__global__ void sqnorm_kernel(const u16* __restrict__ Qb, const u16* __restrict__ Kb,
                              float* __restrict__ nq2, float* __restrict__ nk2) {
    const int b = blockIdx.x, which = blockIdx.y, ch = blockIdx.z;
    const u16* S = which ? Kb : Qb;
    float* dst = which ? nk2 : nq2;
    const int c = threadIdx.x;
    float s = 0.f;
    for (int n = ch * 512; n < ch * 512 + 512; ++n) {
        float v = bf2f(S[((size_t)b * NN + n) * 256 + c]);
        s += v * v;
    }
    atomicAdd(&dst[b * 256 + c], s);
}

// ================= xE tiled (replay-stable since R8) =================
__global__ void xe_tiled(const float* __restrict__ x, const float* __restrict__ Ew,
                         float* __restrict__ xE) {
    __shared__ float xs[64][68];
    __shared__ float es[64][68];
    const int b = blockIdx.x, kq = blockIdx.y, nc = blockIdx.z;
    const int t = threadIdx.x;
    const int kk = t >> 2, pq = (t & 3) * 16;
    float acc[16];
    #pragma unroll
    for (int j = 0; j < 16; ++j) acc[j] = 0.f;

    for (int st = 0; st < 8; ++st) {
        const int n0 = nc * 512 + st * 64;
        {
            int nn = t >> 2, kl = (t & 3) * 16;
            const float* p = x + ((size_t)b * NN + n0 + nn) * 256 + kq * 64 + kl;
            *(float4v*)&xs[nn][kl]      = *(const float4v*)p;
            *(float4v*)&xs[nn][kl + 4]  = *(const float4v*)(p + 4);
            *(float4v*)&xs[nn][kl + 8]  = *(const float4v*)(p + 8);
            *(float4v*)&xs[nn][kl + 12] = *(const float4v*)(p + 12);
        }
        {
            int pp = t >> 2, nq = (t & 3) * 16;
            const float* p = Ew + (size_t)pp * NN + n0 + nq;
            #pragma unroll
            for (int j = 0; j < 16; ++j) es[nq + j][pp] = p[j];
        }
        __syncthreads();
        for (int nn = 0; nn < 64; ++nn) {
            float a = xs[nn][kk];
            float4v e0 = *(const float4v*)&es[nn][pq];
            float4v e1 = *(const float4v*)&es[nn][pq + 4];
            float4v e2 = *(const float4v*)&es[nn][pq + 8];
            float4v e3 = *(const float4v*)&es[nn][pq + 12];
            #pragma unroll
            for (int j = 0; j < 4; ++j) {
                acc[j]      += a * e0[j];
                acc[4 + j]  += a * e1[j];
                acc[8 + j]  += a * e2[j];
                acc[12 + j] += a * e3[j];
            }
        }
        __syncthreads();
    }
    const int base = (b * 256 + kq * 64 + kk) * 64 + pq;
    #pragma unroll
    for (int j = 0; j < 16; ++j) atomicAdd(&xE[base + j], acc[j]);
}

// ---------------- kp/vp (kept) ----------------
__global__ void kvproj_kernel(const float* __restrict__ Wk, const float* __restrict__ Wvsa,
                              const float* __restrict__ xE, const float* __restrict__ Eb,
                              float* __restrict__ kp, float* __restrict__ vp) {
    const int b = blockIdx.x >> 8, c = blockIdx.x & 255, z = blockIdx.y, p = threadIdx.x;
    const float* W = z ? Wvsa : Wk;
    float* dst = z ? vp : kp;
    float s = 0.f;
    for (int k = 0; k < 256; ++k)
        s += W[c * 256 + k] * xE[(size_t)(b * 256 + k) * 64 + p];
    dst[(size_t)(b * 256 + c) * 64 + p] = s + Eb[p];
}

// ================= calog via MFMA, deterministic split-N =================
// grid (16 bh, 4 nc), 256 thr (4 waves). Each block: 2048 tokens -> partial[nc].
// C[d][e] = sum_n Q[n][d]*K[n][e] ; staged transposed [64 d][136 tok] (pad -> 2-way banks).
__global__ __launch_bounds__(256) void calog_part(
    const u16* __restrict__ Qb, const u16* __restrict__ Kb, float* __restrict__ part)
{
    __shared__ u16 QsT[64][136];
    __shared__ u16 KsT[64][136];
    const int bh = blockIdx.x, b = bh >> 2, h = bh & 3, nc = blockIdx.y;
    const int t = threadIdx.x, lane = t & 63, w = t >> 6;
    const int fr = lane & 15, fk = (lane >> 4) * 8, r0 = (lane >> 4) * 4;

    f32x4 acc[4][4];
    #pragma unroll
    for (int i = 0; i < 4; ++i)
        #pragma unroll
        for (int j = 0; j < 4; ++j) acc[i][j] = (f32x4){0.f, 0.f, 0.f, 0.f};

    for (int it = 0; it < 16; ++it) {
        const int n0 = nc * 2048 + it * 128;
        #pragma unroll
        for (int i = 0; i < 4; ++i) {
            int c = i * 256 + t, tok = c >> 3, ch8 = (c & 7) * 8;
            size_t g = ((size_t)b * NN + n0 + tok) * 256 + h * 64 + ch8;
            bf16x8 vq = *(const bf16x8*)(Qb + g);
            bf16x8 vk = *(const bf16x8*)(Kb + g);
            #pragma unroll
            for (int j = 0; j < 8; ++j) {
                QsT[ch8 + j][tok] = (u16)vq[j];
                KsT[ch8 + j][tok] = (u16)vk[j];
            }
        }
        __syncthreads();
        // wave w consumes tokens w*32..w*32+31 (one K=32 step)
        bf16x8 a[4], bb[4];
        #pragma unroll
        for (int fm = 0; fm < 4; ++fm)
            a[fm] = *(const bf16x8*)&QsT[fm * 16 + fr][w * 32 + fk];
        #pragma unroll
        for (int fn = 0; fn < 4; ++fn)
            bb[fn] = *(const bf16x8*)&KsT[fn * 16 + fr][w * 32 + fk];
        #pragma unroll
        for (int fm = 0; fm < 4; ++fm)
            #pragma unroll
            for (int fn = 0; fn < 4; ++fn)
                acc[fm][fn] = __builtin_amdgcn_mfma_f32_16x16x32_bf16(
                    a[fm], bb[fn], acc[fm][fn], 0, 0, 0);
        __syncthreads();
    }

    // fixed-order wave reduction into Cred (aliases QsT region, 16KB)
    float* Cred = (float*)&QsT[0][0];
    for (int ph = 0; ph < 4; ++ph) {
        if (w == ph) {
            #pragma unroll
            for (int fm = 0; fm < 4; ++fm)
                #pragma unroll
                for (int fn = 0; fn < 4; ++fn)
                    #pragma unroll
                    for (int r = 0; r < 4; ++r) {
                        int idx = (fm * 16 + r0 + r) * 64 + fn * 16 + fr;
                        if (ph == 0) Cred[idx] = acc[fm][fn][r];
                        else         Cred[idx] += acc[fm][fn][r];
                    }
        }
        __syncthreads();
    }
    float* dst = part + (size_t)nc * 65536 + (size_t)bh * 4096;
    #pragma unroll
    for (int i = 0; i < 16; ++i) dst[i * 256 + t] = Cred[i * 256 + t];
}

// fixed-order 4-way sum: calog[i] = sum_nc part[nc][i]
__global__ void calog_reduce(const float* __restrict__ part, float* __restrict__ calog) {
    int i = blockIdx.x * 256 + threadIdx.x;
    calog[i] = ((part[i] + part[65536 + i]) + part[131072 + i]) + part[196608 + i];
}

// ---------------- casoftmax (kept) ----------------
__global__ void casoftmax_kernel(const float* __restrict__ calog, const float* __restrict__ nq2,
                                 const float* __restrict__ nk2, const float* __restrict__ temp,
                                 float* __restrict__ caprob) {
    const int row = blockIdx.x;
    const int b = row >> 8, c = row & 255, h = c >> 6;
    const int e = threadIdx.x;
    float nq = fmaxf(sqrtf(nq2[row]), 1e-12f);
    float nk = fmaxf(sqrtf(nk2[b * 256 + h * 64 + e]), 1e-12f);
    float v = calog[row * 64 + e] / (nq * nk) * temp[h];
    __shared__ float red[64];
    red[e] = v; __syncthreads();
    for (int s = 32; s; s >>= 1) { if (e < s) red[e] = fmaxf(red[e], red[e + s]); __syncthreads(); }
    float m = red[0]; __syncthreads();
    float ex = __expf(v - m);
    red[e] = ex; __syncthreads();
    for (int s = 32; s; s >>= 1) { if (e < s) red[e] += red[e + s]; __syncthreads(); }
    caprob[row * 64 + e] = ex / red[0];
}

// ---------------- buildm (kept) ----------------
__global__ void buildm_kernel(const float* __restrict__ caprob, const float* __restrict__ Wo2,
                              float* __restrict__ M) {
    const int b = blockIdx.x >> 7, j = blockIdx.x & 127, c = threadIdx.x;
    const int h = c >> 6, e = c & 63;
    float s = 0.f;
    #pragma unroll 8
    for (int d = 0; d < 64; ++d)
        s += Wo2[j * 256 + h * 64 + d] * caprob[(size_t)(b * 256 + h * 64 + d) * 64 + e];
    M[(size_t)blockIdx.x * 256 + c] = s;
}

// ---------------- w2eff (kept) ----------------
__global__ void w2eff_kernel(const float* __restrict__ M, const float* __restrict__ Wvca,
                             float* __restrict__ W2eff) {
    const int k = threadIdx.x;
    const float* Mrow = M + (size_t)blockIdx.x * 256;
    float s = 0.f;
    for (int c = 0; c < 256; ++c) s += Mrow[c] * Wvca[c * 256 + k];
    W2eff[(size_t)blockIdx.x * 256 + k] = s;
}

// ================= MFMA spatial attention (kept, replay-stable since R8) =================
__global__ __launch_bounds__(256) void sa_mfma(
    const u16* __restrict__ Qb, const float* __restrict__ kp,
    const float* __restrict__ vp, const float* __restrict__ nq2,
    const float* __restrict__ temp2, u16* __restrict__ xsa)
{
    __shared__ char smem[49152];
    u16* Qs = (u16*)smem;
    u16* KT = (u16*)(smem + 32768);
    u16* VT = (u16*)(smem + 40960);
    const int nc = blockIdx.x, bh = blockIdx.y, b = bh >> 2, h = bh & 3;
    const int t = threadIdx.x, lane = t & 63, w = t >> 6;
    const int fr = lane & 15, fk = (lane >> 4) * 8, r0 = (lane >> 4) * 4;

    #pragma unroll
    for (int i = 0; i < 8; ++i) {
        int c = i * 256 + t, tok = c >> 3, ch8 = (c & 7) * 8;
        *(bf16x8*)&Qs[c * 8] =
            *(const bf16x8*)(Qb + ((size_t)b * NN + nc * 256 + tok) * 256 + h * 64 + ch8);
    }
    {
        const int d = t >> 2, p0 = (t & 3) * 16;
        const float rqv = 1.0f / fmaxf(sqrtf(nq2[b * 256 + h * 64 + d]), 1e-12f);
        const float t2 = temp2[h];
        const float* kr = kp + (size_t)(b * 256 + h * 64 + d) * 64 + p0;
        #pragma unroll
        for (int j = 0; j < 16; ++j)
            KT[(p0 + j) * 64 + d] = f2bf(kr[j] * rqv * t2);
    }
    {
        const float* vs = vp + (size_t)(b * 256 + h * 64) * 64;
        #pragma unroll
        for (int i = 0; i < 2; ++i) {
            int c = i * 256 + t;
            bf16x8 v;
            #pragma unroll
            for (int j = 0; j < 8; ++j) v[j] = (short)f2bf(vs[c * 8 + j]);
            *(bf16x8*)&VT[c * 8] = v;
        }
    }
    __syncthreads();

    f32x4 acc[4][4];
    #pragma unroll
    for (int i = 0; i < 4; ++i)
        #pragma unroll
        for (int j = 0; j < 4; ++j) acc[i][j] = (f32x4){0.f, 0.f, 0.f, 0.f};
    #pragma unroll
    for (int ks = 0; ks < 2; ++ks) {
        bf16x8 a[4], bb[4];
        #pragma unroll
        for (int fm = 0; fm < 4; ++fm)
            a[fm] = *(const bf16x8*)&Qs[(w * 64 + fm * 16 + fr) * 64 + ks * 32 + fk];
        #pragma unroll
        for (int fn = 0; fn < 4; ++fn)
            bb[fn] = *(const bf16x8*)&KT[(fn * 16 + fr) * 64 + ks * 32 + fk];
        #pragma unroll
        for (int fm = 0; fm < 4; ++fm)
            #pragma unroll
            for (int fn = 0; fn < 4; ++fn)
                acc[fm][fn] = __builtin_amdgcn_mfma_f32_16x16x32_bf16(
                    a[fm], bb[fn], acc[fm][fn], 0, 0, 0);
    }
    __syncthreads();

    u16* Pw = Qs + w * 4096;
    #pragma unroll
    for (int fm = 0; fm < 4; ++fm) {
        #pragma unroll
        for (int r = 0; r < 4; ++r) {
            float m = fmaxf(fmaxf(acc[fm][0][r], acc[fm][1][r]),
                            fmaxf(acc[fm][2][r], acc[fm][3][r]));
            m = fmaxf(m, __shfl_xor(m, 1));
            m = fmaxf(m, __shfl_xor(m, 2));
            m = fmaxf(m, __shfl_xor(m, 4));
            m = fmaxf(m, __shfl_xor(m, 8));
            float e0 = __expf(acc[fm][0][r] - m), e1 = __expf(acc[fm][1][r] - m);
            float e2 = __expf(acc[fm][2][r] - m), e3 = __expf(acc[fm][3][r] - m);
            float s = e0 + e1 + e2 + e3;
            s += __shfl_xor(s, 1); s += __shfl_xor(s, 2);
            s += __shfl_xor(s, 4); s += __shfl_xor(s, 8);
            float rs = 1.0f / s;
            int row = fm * 16 + r0 + r;
            Pw[row * 64 +  0 + fr] = f2bf(e0 * rs);
            Pw[row * 64 + 16 + fr] = f2bf(e1 * rs);
            Pw[row * 64 + 32 + fr] = f2bf(e2 * rs);
            Pw[row * 64 + 48 + fr] = f2bf(e3 * rs);
        }
    }

    f32x4 acc2[4][4];
    #pragma unroll
    for (int i = 0; i < 4; ++i)
        #pragma unroll
        for (int j = 0; j < 4; ++j) acc2[i][j] = (f32x4){0.f, 0.f, 0.f, 0.f};
    #pragma unroll
    for (int ks = 0; ks < 2; ++ks) {
        bf16x8 a[4], bb[4];
        #pragma unroll
        for (int fm = 0; fm < 4; ++fm)
            a[fm] = *(const bf16x8*)&Pw[(fm * 16 + fr) * 64 + ks * 32 + fk];
        #pragma unroll
        for (int fn = 0; fn < 4; ++fn)
            bb[fn] = *(const bf16x8*)&VT[(fn * 16 + fr) * 64 + ks * 32 + fk];
        #pragma unroll
        for (int fm = 0; fm < 4; ++fm)
            #pragma unroll
            for (int fn = 0; fn < 4; ++fn)
                acc2[fm][fn] = __builtin_amdgcn_mfma_f32_16x16x32_bf16(
                    a[fm], bb[fn], acc2[fm][fn], 0, 0, 0);
    }
    __syncthreads();

    u16* X2 = Qs;
    #pragma unroll
    for (int fm = 0; fm < 4; ++fm)
        #pragma unroll
        for (int fn = 0; fn < 4; ++fn)
            #pragma unroll
            for (int r = 0; r < 4; ++r)
                X2[(w * 64 + fm * 16 + r0 + r) * 64 + fn * 16 + fr] = f2bf(acc2[fm][fn][r]);
    __syncthreads();

    {
        const int d = t >> 2, cq = (t & 3) * 64;
        u16* orow = xsa + ((size_t)b * NN + d * 128 + h * 32 + nc) * 256 + cq;
        #pragma unroll
        for (int i = 0; i < 8; ++i) {
            bf16x8 v;
            #pragma unroll
            for (int j = 0; j < 8; ++j) v[j] = (short)X2[(cq + i * 8 + j) * 64 + d];
            *(bf16x8*)&orow[i * 8] = v;
        }
    }
}

extern "C" void kernel_launch(void* const* d_in, const int* in_sizes, int n_in,
                              void* d_out, int out_size, void* d_ws, size_t ws_size,
                              hipStream_t stream) {
    float* out = (float*)d_out;

    static const int expect[14] = {8388608, 8388608, 65536, 65536, 65536, 65536,
                                   524288, 64, 4, 4, 32768, 128, 32768, 128};
    bool ok = (n_in == 14) && (out_size == 8388608);
    if (ok) for (int i = 0; i < 14; ++i) ok = ok && (in_sizes[i] == expect[i]);
    if (!ok) {
        fill_kernel<<<dim3(8192), 256, 0, stream>>>(out, 3000.0f);
        return;
    }
    if (ws_size < 36000000u) {
        fill_kernel<<<dim3(8192), 256, 0, stream>>>(out, 1000.0f);
        return;
    }

    const float* x    = (const float*)d_in[0];
    const float* q    = (const float*)d_in[1];
    const float* Wq   = (const float*)d_in[2];
    const float* Wk   = (const float*)d_in[3];
    const float* Wvca = (const float*)d_in[4];
    const float* Wvsa = (const float*)d_in[5];
    const float* Ew   = (const float*)d_in[6];
    const float* Eb   = (const float*)d_in[7];
    const float* temp = (const float*)d_in[8];
    const float* temp2= (const float*)d_in[9];
    const float* Wo1  = (const float*)d_in[10];
    const float* bo1  = (const float*)d_in[11];
    const float* Wo2  = (const float*)d_in[12];
    const float* bo2  = (const float*)d_in[13];

    u16* Qb = (u16*)d_ws;
    u16* Kb = Qb + (size_t)BNC;          // reused as xsa after calog (stream-ordered)
    u16* xsa = Kb;
    float* fs    = (float*)(Kb + (size_t)BNC);
    float* nq2   = fs;                   // 1024
    float* nk2   = nq2 + 1024;           // 1024
    float* xE    = nk2 + 1024;           // 65536
    float* kp    = xE + 65536;           // 65536
    float* vp    = kp + 65536;           // 65536
    float* calog = vp + 65536;           // 65536
    float* caprob= calog + 65536;        // 65536
    float* M     = caprob + 65536;       // 131072
    float* W2eff = M + 131072;           // 131072
    float* cpart = M;                    // 262144 floats (M+W2eff), consumed before buildm

    // zero only the atomic accumulators: nq2, nk2, xE = 67584 floats
    zero_kernel<<<dim3(264), 256, 0, stream>>>(nq2, 67584);
    gemm128<0, 1><<<dim3(256, 2), 256, 0, stream>>>(q, Wq, 0, Qb, nullptr, nullptr, 0);
    gemm128<0, 1><<<dim3(256, 2), 256, 0, stream>>>(x, Wk, 0, Kb, nullptr, nullptr, 0);
    sqnorm_kernel<<<dim3(4, 2, 16), 256, 0, stream>>>(Qb, Kb, nq2, nk2);
    xe_tiled<<<dim3(4, 4, 16), 256, 0, stream>>>(x, Ew, xE);
    kvproj_kernel<<<dim3(1024, 2), 64, 0, stream>>>(Wk, Wvsa, xE, Eb, kp, vp);
    calog_part<<<dim3(16, 4), 256, 0, stream>>>(Qb, Kb, cpart);
    calog_reduce<<<dim3(256), 256, 0, stream>>>(cpart, calog);
    casoftmax_kernel<<<dim3(1024), 64, 0, stream>>>(calog, nq2, nk2, temp, caprob);
    buildm_kernel<<<dim3(512), 256, 0, stream>>>(caprob, Wo2, M);
    w2eff_kernel<<<dim3(512), 256, 0, stream>>>(M, Wvca, W2eff);
    gemm128<0, 0><<<dim3(256, 1), 256, 0, stream>>>(x, W2eff, 128 * 256, nullptr, out, bo2, 128);
    sa_mfma<<<dim3(32, 16), 256, 0, stream>>>(Qb, kp, vp, nq2, temp2, xsa);
    gemm128<1, 0><<<dim3(256, 1), 256, 0, stream>>>(xsa, Wo1, 0, nullptr, out, bo1, 0);
}

// Round 11
// 190.457 us; speedup vs baseline: 19.9476x; 1.3583x over previous
//
#include <hip/hip_runtime.h>
#include <hip/hip_bf16.h>

// Shapes: B=4, N=8192, C=256, H=4, D=64, P=64
#define NN 8192
#define BNC 8388608   // B*N*C

typedef unsigned short u16;
typedef unsigned int u32;
typedef __attribute__((ext_vector_type(8))) short bf16x8;
typedef __attribute__((ext_vector_type(4))) float f32x4;
typedef __attribute__((ext_vector_type(4))) float float4v;

__device__ __forceinline__ float bf2f(u16 u) {
    union { u32 i; float f; } c; c.i = ((u32)u) << 16; return c.f;
}
__device__ __forceinline__ u16 f2bf(float f) {
    union { float f; u32 i; } c; c.f = f;
    u32 x = c.i;
    u32 r = (x + 0x7fffu + ((x >> 16) & 1u)) >> 16;  // RNE
    return (u16)r;
}

// ---------------- diagnostic fill ----------------
__global__ void fill_kernel(float* __restrict__ out, float val) {
    int base = (blockIdx.x * 256 + threadIdx.x) * 4;
    #pragma unroll
    for (int i = 0; i < 4; ++i) out[base + i] = val;
}

// ---------------- zero ----------------
__global__ void zero_kernel(float* __restrict__ p, int n) {
    int i = blockIdx.x * 256 + threadIdx.x;
    if (i < n) p[i] = 0.f;
}

// ================= MFMA GEMM: C[M][*] = A[M][256] @ Bt[N][256]^T =================
template<int ABF, int OBF>
__global__ __launch_bounds__(256) void gemm128(
    const void* __restrict__ Avoid, const float* __restrict__ Bt, long btstride,
    u16* __restrict__ Obf, float* __restrict__ Of,
    const float* __restrict__ bias, int outoff)
{
    __shared__ u16 As[4096];   // [128][32] bf16 linear
    __shared__ u16 Bs[4096];
    const int t = threadIdx.x, lane = t & 63, w = t >> 6;
    const int wr = w >> 1, wc = w & 1;
    const int fr = lane & 15, fk = (lane >> 4) * 8, r0 = (lane >> 4) * 4;
    const int m0 = blockIdx.x * 128, n0 = blockIdx.y * 128;
    const float* Af = (const float*)Avoid;
    const u16*   Ab = (const u16*)Avoid;
    const float* Btb = Bt + (btstride ? (size_t)(blockIdx.x >> 6) * (size_t)btstride : 0);

    f32x4 acc[4][4];
    #pragma unroll
    for (int i = 0; i < 4; ++i)
        #pragma unroll
        for (int j = 0; j < 4; ++j) acc[i][j] = (f32x4){0.f, 0.f, 0.f, 0.f};

    for (int kt = 0; kt < 8; ++kt) {
        const int k0 = kt * 32;
        #pragma unroll
        for (int i = 0; i < 2; ++i) {
            int c = i * 256 + t, row = c >> 2, k8 = (c & 3) * 8;
            bf16x8 va;
            if (ABF) {
                va = *(const bf16x8*)(Ab + (size_t)(m0 + row) * 256 + k0 + k8);
            } else {
                const float* p = Af + (size_t)(m0 + row) * 256 + k0 + k8;
                float4v f0 = *(const float4v*)p, f1 = *(const float4v*)(p + 4);
                #pragma unroll
                for (int j = 0; j < 4; ++j) {
                    va[j] = (short)f2bf(f0[j]); va[4 + j] = (short)f2bf(f1[j]);
                }
            }
            *(bf16x8*)&As[c * 8] = va;
            const float* pb = Btb + (size_t)(n0 + row) * 256 + k0 + k8;
            float4v g0 = *(const float4v*)pb, g1 = *(const float4v*)(pb + 4);
            bf16x8 vb;
            #pragma unroll
            for (int j = 0; j < 4; ++j) {
                vb[j] = (short)f2bf(g0[j]); vb[4 + j] = (short)f2bf(g1[j]);
            }
            *(bf16x8*)&Bs[c * 8] = vb;
        }
        __syncthreads();
        bf16x8 a[4], b[4];
        #pragma unroll
        for (int fm = 0; fm < 4; ++fm)
            a[fm] = *(const bf16x8*)&As[(wr * 64 + fm * 16 + fr) * 32 + fk];
        #pragma unroll
        for (int fn = 0; fn < 4; ++fn)
            b[fn] = *(const bf16x8*)&Bs[(wc * 64 + fn * 16 + fr) * 32 + fk];
        #pragma unroll
        for (int fm = 0; fm < 4; ++fm)
            #pragma unroll
            for (int fn = 0; fn < 4; ++fn)
                acc[fm][fn] = __builtin_amdgcn_mfma_f32_16x16x32_bf16(
                    a[fm], b[fn], acc[fm][fn], 0, 0, 0);
        __syncthreads();
    }

    #pragma unroll
    for (int fm = 0; fm < 4; ++fm)
        #pragma unroll
        for (int fn = 0; fn < 4; ++fn) {
            int gcol = n0 + wc * 64 + fn * 16 + fr;
            #pragma unroll
            for (int r = 0; r < 4; ++r) {
                size_t grow = (size_t)(m0 + wr * 64 + fm * 16 + r0 + r);
                float v = acc[fm][fn][r];
                if (OBF) Obf[grow * 256 + gcol] = f2bf(v);
                else     Of[grow * 256 + outoff + gcol] = v + bias[gcol];
            }
        }
}

// ================= sqnorm (chunked + atomic; replay-stable since R8) =================
__global__ void sqnorm_kernel(const u16* __restrict__ Qb, const u16* __restrict__ Kb,
                              float* __restrict__ nq2, float* __restrict__ nk2) {
    const int b = blockIdx.x, which = blockIdx.y, ch = blockIdx.z;
    const u16* S = which ? Kb : Qb;
    float* dst = which ? nk2 : nq2;
    const int c = threadIdx.x;
    float s = 0.f;
    for (int n = ch * 512; n < ch * 512 + 512; ++n) {
        float v = bf2f(S[((size_t)b * NN + n) * 256 + c]);
        s += v * v;
    }
    atomicAdd(&dst[b * 256 + c], s);
}

// ================= xE via MFMA: xE[b,kq*64+k][p] += sum_n x[b,n,k]*Ew[p,n] =================
// grid (16 b*kq, 8 nc), 256 thr (4 waves). Each block: 1024 tokens -> atomic into xE.
// Structure cloned from calog_part (verified): transposed x staging, Ew rows direct.
__global__ __launch_bounds__(256) void xe_mfma(
    const float* __restrict__ x, const float* __restrict__ Ew, float* __restrict__ xE)
{
    __shared__ u16 xsT[64][136];   // [k-local][tok]
    __shared__ u16 ewB[64][136];   // [p][tok]
    const int bkq = blockIdx.x, b = bkq >> 2, kq = bkq & 3, nc = blockIdx.y;
    const int t = threadIdx.x, lane = t & 63, w = t >> 6;
    const int fr = lane & 15, fk = (lane >> 4) * 8, r0 = (lane >> 4) * 4;

    f32x4 acc[4][4];
    #pragma unroll
    for (int i = 0; i < 4; ++i)
        #pragma unroll
        for (int j = 0; j < 4; ++j) acc[i][j] = (f32x4){0.f, 0.f, 0.f, 0.f};

    for (int it = 0; it < 8; ++it) {
        const int n0 = nc * 1024 + it * 128;
        // stage x transposed: [64 k][128 tok]
        #pragma unroll
        for (int i = 0; i < 4; ++i) {
            int c = i * 256 + t, tok = c >> 3, kl = (c & 7) * 8;
            const float* p = x + ((size_t)b * NN + n0 + tok) * 256 + kq * 64 + kl;
            float4v f0 = *(const float4v*)p, f1 = *(const float4v*)(p + 4);
            #pragma unroll
            for (int j = 0; j < 4; ++j) {
                xsT[kl + j][tok]     = f2bf(f0[j]);
                xsT[kl + 4 + j][tok] = f2bf(f1[j]);
            }
        }
        // stage Ew: [64 p][128 tok], contiguous in n -> vector stores
        #pragma unroll
        for (int i = 0; i < 4; ++i) {
            int c = i * 256 + t, p = c >> 4, tk8 = (c & 15) * 8;
            const float* pe = Ew + (size_t)p * NN + n0 + tk8;
            float4v g0 = *(const float4v*)pe, g1 = *(const float4v*)(pe + 4);
            bf16x8 v;
            #pragma unroll
            for (int j = 0; j < 4; ++j) {
                v[j] = (short)f2bf(g0[j]); v[4 + j] = (short)f2bf(g1[j]);
            }
            *(bf16x8*)&ewB[p][tk8] = v;
        }
        __syncthreads();
        // wave w consumes tokens w*32..w*32+31
        bf16x8 a[4], bb[4];
        #pragma unroll
        for (int fm = 0; fm < 4; ++fm)
            a[fm] = *(const bf16x8*)&xsT[fm * 16 + fr][w * 32 + fk];
        #pragma unroll
        for (int fn = 0; fn < 4; ++fn)
            bb[fn] = *(const bf16x8*)&ewB[fn * 16 + fr][w * 32 + fk];
        #pragma unroll
        for (int fm = 0; fm < 4; ++fm)
            #pragma unroll
            for (int fn = 0; fn < 4; ++fn)
                acc[fm][fn] = __builtin_amdgcn_mfma_f32_16x16x32_bf16(
                    a[fm], bb[fn], acc[fm][fn], 0, 0, 0);
        __syncthreads();
    }

    // fixed-order wave reduction into Cred (aliases xsT region)
    float* Cred = (float*)&xsT[0][0];
    for (int ph = 0; ph < 4; ++ph) {
        if (w == ph) {
            #pragma unroll
            for (int fm = 0; fm < 4; ++fm)
                #pragma unroll
                for (int fn = 0; fn < 4; ++fn)
                    #pragma unroll
                    for (int r = 0; r < 4; ++r) {
                        int idx = (fm * 16 + r0 + r) * 64 + fn * 16 + fr;
                        if (ph == 0) Cred[idx] = acc[fm][fn][r];
                        else         Cred[idx] += acc[fm][fn][r];
                    }
        }
        __syncthreads();
    }
    float* dst = xE + (size_t)(b * 256 + kq * 64) * 64;
    #pragma unroll
    for (int i = 0; i < 16; ++i) atomicAdd(&dst[i * 256 + t], Cred[i * 256 + t]);
}

// ---------------- kp/vp (kept) ----------------
__global__ void kvproj_kernel(const float* __restrict__ Wk, const float* __restrict__ Wvsa,
                              const float* __restrict__ xE, const float* __restrict__ Eb,
                              float* __restrict__ kp, float* __restrict__ vp) {
    const int b = blockIdx.x >> 8, c = blockIdx.x & 255, z = blockIdx.y, p = threadIdx.x;
    const float* W = z ? Wvsa : Wk;
    float* dst = z ? vp : kp;
    float s = 0.f;
    for (int k = 0; k < 256; ++k)
        s += W[c * 256 + k] * xE[(size_t)(b * 256 + k) * 64 + p];
    dst[(size_t)(b * 256 + c) * 64 + p] = s + Eb[p];
}

// ================= calog via MFMA, deterministic split-N (kept) =================
__global__ __launch_bounds__(256) void calog_part(
    const u16* __restrict__ Qb, const u16* __restrict__ Kb, float* __restrict__ part)
{
    __shared__ u16 QsT[64][136];
    __shared__ u16 KsT[64][136];
    const int bh = blockIdx.x, b = bh >> 2, h = bh & 3, nc = blockIdx.y;
    const int t = threadIdx.x, lane = t & 63, w = t >> 6;
    const int fr = lane & 15, fk = (lane >> 4) * 8, r0 = (lane >> 4) * 4;

    f32x4 acc[4][4];
    #pragma unroll
    for (int i = 0; i < 4; ++i)
        #pragma unroll
        for (int j = 0; j < 4; ++j) acc[i][j] = (f32x4){0.f, 0.f, 0.f, 0.f};

    for (int it = 0; it < 16; ++it) {
        const int n0 = nc * 2048 + it * 128;
        #pragma unroll
        for (int i = 0; i < 4; ++i) {
            int c = i * 256 + t, tok = c >> 3, ch8 = (c & 7) * 8;
            size_t g = ((size_t)b * NN + n0 + tok) * 256 + h * 64 + ch8;
            bf16x8 vq = *(const bf16x8*)(Qb + g);
            bf16x8 vk = *(const bf16x8*)(Kb + g);
            #pragma unroll
            for (int j = 0; j < 8; ++j) {
                QsT[ch8 + j][tok] = (u16)vq[j];
                KsT[ch8 + j][tok] = (u16)vk[j];
            }
        }
        __syncthreads();
        bf16x8 a[4], bb[4];
        #pragma unroll
        for (int fm = 0; fm < 4; ++fm)
            a[fm] = *(const bf16x8*)&QsT[fm * 16 + fr][w * 32 + fk];
        #pragma unroll
        for (int fn = 0; fn < 4; ++fn)
            bb[fn] = *(const bf16x8*)&KsT[fn * 16 + fr][w * 32 + fk];
        #pragma unroll
        for (int fm = 0; fm < 4; ++fm)
            #pragma unroll
            for (int fn = 0; fn < 4; ++fn)
                acc[fm][fn] = __builtin_amdgcn_mfma_f32_16x16x32_bf16(
                    a[fm], bb[fn], acc[fm][fn], 0, 0, 0);
        __syncthreads();
    }

    float* Cred = (float*)&QsT[0][0];
    for (int ph = 0; ph < 4; ++ph) {
        if (w == ph) {
            #pragma unroll
            for (int fm = 0; fm < 4; ++fm)
                #pragma unroll
                for (int fn = 0; fn < 4; ++fn)
                    #pragma unroll
                    for (int r = 0; r < 4; ++r) {
                        int idx = (fm * 16 + r0 + r) * 64 + fn * 16 + fr;
                        if (ph == 0) Cred[idx] = acc[fm][fn][r];
                        else         Cred[idx] += acc[fm][fn][r];
                    }
        }
        __syncthreads();
    }
    float* dst = part + (size_t)nc * 65536 + (size_t)bh * 4096;
    #pragma unroll
    for (int i = 0; i < 16; ++i) dst[i * 256 + t] = Cred[i * 256 + t];
}

__global__ void calog_reduce(const float* __restrict__ part, float* __restrict__ calog) {
    int i = blockIdx.x * 256 + threadIdx.x;
    calog[i] = ((part[i] + part[65536 + i]) + part[131072 + i]) + part[196608 + i];
}

// ---------------- casoftmax (kept) ----------------
__global__ void casoftmax_kernel(const float* __restrict__ calog, const float* __restrict__ nq2,
                                 const float* __restrict__ nk2, const float* __restrict__ temp,
                                 float* __restrict__ caprob) {
    const int row = blockIdx.x;
    const int b = row >> 8, c = row & 255, h = c >> 6;
    const int e = threadIdx.x;
    float nq = fmaxf(sqrtf(nq2[row]), 1e-12f);
    float nk = fmaxf(sqrtf(nk2[b * 256 + h * 64 + e]), 1e-12f);
    float v = calog[row * 64 + e] / (nq * nk) * temp[h];
    __shared__ float red[64];
    red[e] = v; __syncthreads();
    for (int s = 32; s; s >>= 1) { if (e < s) red[e] = fmaxf(red[e], red[e + s]); __syncthreads(); }
    float m = red[0]; __syncthreads();
    float ex = __expf(v - m);
    red[e] = ex; __syncthreads();
    for (int s = 32; s; s >>= 1) { if (e < s) red[e] += red[e + s]; __syncthreads(); }
    caprob[row * 64 + e] = ex / red[0];
}

// ---------------- buildm (kept) ----------------
__global__ void buildm_kernel(const float* __restrict__ caprob, const float* __restrict__ Wo2,
                              float* __restrict__ M) {
    const int b = blockIdx.x >> 7, j = blockIdx.x & 127, c = threadIdx.x;
    const int h = c >> 6, e = c & 63;
    float s = 0.f;
    #pragma unroll 8
    for (int d = 0; d < 64; ++d)
        s += Wo2[j * 256 + h * 64 + d] * caprob[(size_t)(b * 256 + h * 64 + d) * 64 + e];
    M[(size_t)blockIdx.x * 256 + c] = s;
}

// ---------------- w2eff (kept) ----------------
__global__ void w2eff_kernel(const float* __restrict__ M, const float* __restrict__ Wvca,
                             float* __restrict__ W2eff) {
    const int k = threadIdx.x;
    const float* Mrow = M + (size_t)blockIdx.x * 256;
    float s = 0.f;
    for (int c = 0; c < 256; ++c) s += Mrow[c] * Wvca[c * 256 + k];
    W2eff[(size_t)blockIdx.x * 256 + k] = s;
}

// ================= MFMA spatial attention (kept) =================
__global__ __launch_bounds__(256) void sa_mfma(
    const u16* __restrict__ Qb, const float* __restrict__ kp,
    const float* __restrict__ vp, const float* __restrict__ nq2,
    const float* __restrict__ temp2, u16* __restrict__ xsa)
{
    __shared__ char smem[49152];
    u16* Qs = (u16*)smem;
    u16* KT = (u16*)(smem + 32768);
    u16* VT = (u16*)(smem + 40960);
    const int nc = blockIdx.x, bh = blockIdx.y, b = bh >> 2, h = bh & 3;
    const int t = threadIdx.x, lane = t & 63, w = t >> 6;
    const int fr = lane & 15, fk = (lane >> 4) * 8, r0 = (lane >> 4) * 4;

    #pragma unroll
    for (int i = 0; i < 8; ++i) {
        int c = i * 256 + t, tok = c >> 3, ch8 = (c & 7) * 8;
        *(bf16x8*)&Qs[c * 8] =
            *(const bf16x8*)(Qb + ((size_t)b * NN + nc * 256 + tok) * 256 + h * 64 + ch8);
    }
    {
        const int d = t >> 2, p0 = (t & 3) * 16;
        const float rqv = 1.0f / fmaxf(sqrtf(nq2[b * 256 + h * 64 + d]), 1e-12f);
        const float t2 = temp2[h];
        const float* kr = kp + (size_t)(b * 256 + h * 64 + d) * 64 + p0;
        #pragma unroll
        for (int j = 0; j < 16; ++j)
            KT[(p0 + j) * 64 + d] = f2bf(kr[j] * rqv * t2);
    }
    {
        const float* vs = vp + (size_t)(b * 256 + h * 64) * 64;
        #pragma unroll
        for (int i = 0; i < 2; ++i) {
            int c = i * 256 + t;
            bf16x8 v;
            #pragma unroll
            for (int j = 0; j < 8; ++j) v[j] = (short)f2bf(vs[c * 8 + j]);
            *(bf16x8*)&VT[c * 8] = v;
        }
    }
    __syncthreads();

    f32x4 acc[4][4];
    #pragma unroll
    for (int i = 0; i < 4; ++i)
        #pragma unroll
        for (int j = 0; j < 4; ++j) acc[i][j] = (f32x4){0.f, 0.f, 0.f, 0.f};
    #pragma unroll
    for (int ks = 0; ks < 2; ++ks) {
        bf16x8 a[4], bb[4];
        #pragma unroll
        for (int fm = 0; fm < 4; ++fm)
            a[fm] = *(const bf16x8*)&Qs[(w * 64 + fm * 16 + fr) * 64 + ks * 32 + fk];
        #pragma unroll
        for (int fn = 0; fn < 4; ++fn)
            bb[fn] = *(const bf16x8*)&KT[(fn * 16 + fr) * 64 + ks * 32 + fk];
        #pragma unroll
        for (int fm = 0; fm < 4; ++fm)
            #pragma unroll
            for (int fn = 0; fn < 4; ++fn)
                acc[fm][fn] = __builtin_amdgcn_mfma_f32_16x16x32_bf16(
                    a[fm], bb[fn], acc[fm][fn], 0, 0, 0);
    }
    __syncthreads();

    u16* Pw = Qs + w * 4096;
    #pragma unroll
    for (int fm = 0; fm < 4; ++fm) {
        #pragma unroll
        for (int r = 0; r < 4; ++r) {
            float m = fmaxf(fmaxf(acc[fm][0][r], acc[fm][1][r]),
                            fmaxf(acc[fm][2][r], acc[fm][3][r]));
            m = fmaxf(m, __shfl_xor(m, 1));
            m = fmaxf(m, __shfl_xor(m, 2));
            m = fmaxf(m, __shfl_xor(m, 4));
            m = fmaxf(m, __shfl_xor(m, 8));
            float e0 = __expf(acc[fm][0][r] - m), e1 = __expf(acc[fm][1][r] - m);
            float e2 = __expf(acc[fm][2][r] - m), e3 = __expf(acc[fm][3][r] - m);
            float s = e0 + e1 + e2 + e3;
            s += __shfl_xor(s, 1); s += __shfl_xor(s, 2);
            s += __shfl_xor(s, 4); s += __shfl_xor(s, 8);
            float rs = 1.0f / s;
            int row = fm * 16 + r0 + r;
            Pw[row * 64 +  0 + fr] = f2bf(e0 * rs);
            Pw[row * 64 + 16 + fr] = f2bf(e1 * rs);
            Pw[row * 64 + 32 + fr] = f2bf(e2 * rs);
            Pw[row * 64 + 48 + fr] = f2bf(e3 * rs);
        }
    }

    f32x4 acc2[4][4];
    #pragma unroll
    for (int i = 0; i < 4; ++i)
        #pragma unroll
        for (int j = 0; j < 4; ++j) acc2[i][j] = (f32x4){0.f, 0.f, 0.f, 0.f};
    #pragma unroll
    for (int ks = 0; ks < 2; ++ks) {
        bf16x8 a[4], bb[4];
        #pragma unroll
        for (int fm = 0; fm < 4; ++fm)
            a[fm] = *(const bf16x8*)&Pw[(fm * 16 + fr) * 64 + ks * 32 + fk];
        #pragma unroll
        for (int fn = 0; fn < 4; ++fn)
            bb[fn] = *(const bf16x8*)&VT[(fn * 16 + fr) * 64 + ks * 32 + fk];
        #pragma unroll
        for (int fm = 0; fm < 4; ++fm)
            #pragma unroll
            for (int fn = 0; fn < 4; ++fn)
                acc2[fm][fn] = __builtin_amdgcn_mfma_f32_16x16x32_bf16(
                    a[fm], bb[fn], acc2[fm][fn], 0, 0, 0);
    }
    __syncthreads();

    u16* X2 = Qs;
    #pragma unroll
    for (int fm = 0; fm < 4; ++fm)
        #pragma unroll
        for (int fn = 0; fn < 4; ++fn)
            #pragma unroll
            for (int r = 0; r < 4; ++r)
                X2[(w * 64 + fm * 16 + r0 + r) * 64 + fn * 16 + fr] = f2bf(acc2[fm][fn][r]);
    __syncthreads();

    {
        const int d = t >> 2, cq = (t & 3) * 64;
        u16* orow = xsa + ((size_t)b * NN + d * 128 + h * 32 + nc) * 256 + cq;
        #pragma unroll
        for (int i = 0; i < 8; ++i) {
            bf16x8 v;
            #pragma unroll
            for (int j = 0; j < 8; ++j) v[j] = (short)X2[(cq + i * 8 + j) * 64 + d];
            *(bf16x8*)&orow[i * 8] = v;
        }
    }
}

extern "C" void kernel_launch(void* const* d_in, const int* in_sizes, int n_in,
                              void* d_out, int out_size, void* d_ws, size_t ws_size,
                              hipStream_t stream) {
    float* out = (float*)d_out;

    static const int expect[14] = {8388608, 8388608, 65536, 65536, 65536, 65536,
                                   524288, 64, 4, 4, 32768, 128, 32768, 128};
    bool ok = (n_in == 14) && (out_size == 8388608);
    if (ok) for (int i = 0; i < 14; ++i) ok = ok && (in_sizes[i] == expect[i]);
    if (!ok) {
        fill_kernel<<<dim3(8192), 256, 0, stream>>>(out, 3000.0f);
        return;
    }
    if (ws_size < 36000000u) {
        fill_kernel<<<dim3(8192), 256, 0, stream>>>(out, 1000.0f);
        return;
    }

    const float* x    = (const float*)d_in[0];
    const float* q    = (const float*)d_in[1];
    const float* Wq   = (const float*)d_in[2];
    const float* Wk   = (const float*)d_in[3];
    const float* Wvca = (const float*)d_in[4];
    const float* Wvsa = (const float*)d_in[5];
    const float* Ew   = (const float*)d_in[6];
    const float* Eb   = (const float*)d_in[7];
    const float* temp = (const float*)d_in[8];
    const float* temp2= (const float*)d_in[9];
    const float* Wo1  = (const float*)d_in[10];
    const float* bo1  = (const float*)d_in[11];
    const float* Wo2  = (const float*)d_in[12];
    const float* bo2  = (const float*)d_in[13];

    u16* Qb = (u16*)d_ws;
    u16* Kb = Qb + (size_t)BNC;          // reused as xsa after calog (stream-ordered)
    u16* xsa = Kb;
    float* fs    = (float*)(Kb + (size_t)BNC);
    float* nq2   = fs;                   // 1024
    float* nk2   = nq2 + 1024;           // 1024
    float* xE    = nk2 + 1024;           // 65536
    float* kp    = xE + 65536;           // 65536
    float* vp    = kp + 65536;           // 65536
    float* calog = vp + 65536;           // 65536
    float* caprob= calog + 65536;        // 65536
    float* M     = caprob + 65536;       // 131072
    float* W2eff = M + 131072;           // 131072
    float* cpart = M;                    // 262144 floats (M+W2eff), consumed before buildm

    // zero the atomic accumulators: nq2, nk2, xE = 67584 floats
    zero_kernel<<<dim3(264), 256, 0, stream>>>(nq2, 67584);
    gemm128<0, 1><<<dim3(256, 2), 256, 0, stream>>>(q, Wq, 0, Qb, nullptr, nullptr, 0);
    gemm128<0, 1><<<dim3(256, 2), 256, 0, stream>>>(x, Wk, 0, Kb, nullptr, nullptr, 0);
    sqnorm_kernel<<<dim3(4, 2, 16), 256, 0, stream>>>(Qb, Kb, nq2, nk2);
    xe_mfma<<<dim3(16, 8), 256, 0, stream>>>(x, Ew, xE);
    kvproj_kernel<<<dim3(1024, 2), 64, 0, stream>>>(Wk, Wvsa, xE, Eb, kp, vp);
    calog_part<<<dim3(16, 4), 256, 0, stream>>>(Qb, Kb, cpart);
    calog_reduce<<<dim3(256), 256, 0, stream>>>(cpart, calog);
    casoftmax_kernel<<<dim3(1024), 64, 0, stream>>>(calog, nq2, nk2, temp, caprob);
    buildm_kernel<<<dim3(512), 256, 0, stream>>>(caprob, Wo2, M);
    w2eff_kernel<<<dim3(512), 256, 0, stream>>>(M, Wvca, W2eff);
    gemm128<0, 0><<<dim3(256, 1), 256, 0, stream>>>(x, W2eff, 128 * 256, nullptr, out, bo2, 128);
    sa_mfma<<<dim3(32, 16), 256, 0, stream>>>(Qb, kp, vp, nq2, temp2, xsa);
    gemm128<1, 0><<<dim3(256, 1), 256, 0, stream>>>(xsa, Wo1, 0, nullptr, out, bo1, 0);
}

// Round 12
// 157.268 us; speedup vs baseline: 24.1572x; 1.2110x over previous
//
#include <hip/hip_runtime.h>
#include <hip/hip_bf16.h>

// Shapes: B=4, N=8192, C=256, H=4, D=64, P=64
#define NN 8192
#define BNC 8388608   // B*N*C

typedef unsigned short u16;
typedef unsigned int u32;
typedef __attribute__((ext_vector_type(8))) short bf16x8;
typedef __attribute__((ext_vector_type(4))) float f32x4;
typedef __attribute__((ext_vector_type(4))) float float4v;

__device__ __forceinline__ float bf2f(u16 u) {
    union { u32 i; float f; } c; c.i = ((u32)u) << 16; return c.f;
}
__device__ __forceinline__ u16 f2bf(float f) {
    union { float f; u32 i; } c; c.f = f;
    u32 x = c.i;
    u32 r = (x + 0x7fffu + ((x >> 16) & 1u)) >> 16;  // RNE
    return (u16)r;
}

// ---------------- diagnostic fill ----------------
__global__ void fill_kernel(float* __restrict__ out, float val) {
    int base = (blockIdx.x * 256 + threadIdx.x) * 4;
    #pragma unroll
    for (int i = 0; i < 4; ++i) out[base + i] = val;
}

// ---------------- zero ----------------
__global__ void zero_kernel(float* __restrict__ p, int n) {
    int i = blockIdx.x * 256 + threadIdx.x;
    if (i < n) p[i] = 0.f;
}

// ================= fused Q/K GEMM: z=0 (q@Wq^T->Qb), z=1 (x@Wk^T->Kb) =================
__global__ __launch_bounds__(256) void gemm_qkf(
    const float* __restrict__ x, const float* __restrict__ q,
    const float* __restrict__ Wq, const float* __restrict__ Wk,
    u16* __restrict__ Qb, u16* __restrict__ Kb)
{
    __shared__ u16 As[4096];   // [128][32] bf16 linear
    __shared__ u16 Bs[4096];
    const int z = blockIdx.z;
    const float* A = z ? x : q;
    const float* Bt = z ? Wk : Wq;
    u16* O = z ? Kb : Qb;
    const int t = threadIdx.x, lane = t & 63, w = t >> 6;
    const int wr = w >> 1, wc = w & 1;
    const int fr = lane & 15, fk = (lane >> 4) * 8, r0 = (lane >> 4) * 4;
    const int m0 = blockIdx.x * 128, n0 = blockIdx.y * 128;

    f32x4 acc[4][4];
    #pragma unroll
    for (int i = 0; i < 4; ++i)
        #pragma unroll
        for (int j = 0; j < 4; ++j) acc[i][j] = (f32x4){0.f, 0.f, 0.f, 0.f};

    for (int kt = 0; kt < 8; ++kt) {
        const int k0 = kt * 32;
        #pragma unroll
        for (int i = 0; i < 2; ++i) {
            int c = i * 256 + t, row = c >> 2, k8 = (c & 3) * 8;
            const float* p = A + (size_t)(m0 + row) * 256 + k0 + k8;
            float4v f0 = *(const float4v*)p, f1 = *(const float4v*)(p + 4);
            bf16x8 va;
            #pragma unroll
            for (int j = 0; j < 4; ++j) {
                va[j] = (short)f2bf(f0[j]); va[4 + j] = (short)f2bf(f1[j]);
            }
            *(bf16x8*)&As[c * 8] = va;
            const float* pb = Bt + (size_t)(n0 + row) * 256 + k0 + k8;
            float4v g0 = *(const float4v*)pb, g1 = *(const float4v*)(pb + 4);
            bf16x8 vb;
            #pragma unroll
            for (int j = 0; j < 4; ++j) {
                vb[j] = (short)f2bf(g0[j]); vb[4 + j] = (short)f2bf(g1[j]);
            }
            *(bf16x8*)&Bs[c * 8] = vb;
        }
        __syncthreads();
        bf16x8 a[4], b[4];
        #pragma unroll
        for (int fm = 0; fm < 4; ++fm)
            a[fm] = *(const bf16x8*)&As[(wr * 64 + fm * 16 + fr) * 32 + fk];
        #pragma unroll
        for (int fn = 0; fn < 4; ++fn)
            b[fn] = *(const bf16x8*)&Bs[(wc * 64 + fn * 16 + fr) * 32 + fk];
        #pragma unroll
        for (int fm = 0; fm < 4; ++fm)
            #pragma unroll
            for (int fn = 0; fn < 4; ++fn)
                acc[fm][fn] = __builtin_amdgcn_mfma_f32_16x16x32_bf16(
                    a[fm], b[fn], acc[fm][fn], 0, 0, 0);
        __syncthreads();
    }

    #pragma unroll
    for (int fm = 0; fm < 4; ++fm)
        #pragma unroll
        for (int fn = 0; fn < 4; ++fn) {
            int gcol = n0 + wc * 64 + fn * 16 + fr;
            #pragma unroll
            for (int r = 0; r < 4; ++r) {
                size_t grow = (size_t)(m0 + wr * 64 + fm * 16 + r0 + r);
                O[grow * 256 + gcol] = f2bf(acc[fm][fn][r]);
            }
        }
}

// ================= MFMA GEMM: C[M][*] = A[M][256] @ Bt[N][256]^T =================
template<int ABF, int OBF>
__global__ __launch_bounds__(256) void gemm128(
    const void* __restrict__ Avoid, const float* __restrict__ Bt, long btstride,
    u16* __restrict__ Obf, float* __restrict__ Of,
    const float* __restrict__ bias, int outoff)
{
    __shared__ u16 As[4096];
    __shared__ u16 Bs[4096];
    const int t = threadIdx.x, lane = t & 63, w = t >> 6;
    const int wr = w >> 1, wc = w & 1;
    const int fr = lane & 15, fk = (lane >> 4) * 8, r0 = (lane >> 4) * 4;
    const int m0 = blockIdx.x * 128, n0 = blockIdx.y * 128;
    const float* Af = (const float*)Avoid;
    const u16*   Ab = (const u16*)Avoid;
    const float* Btb = Bt + (btstride ? (size_t)(blockIdx.x >> 6) * (size_t)btstride : 0);

    f32x4 acc[4][4];
    #pragma unroll
    for (int i = 0; i < 4; ++i)
        #pragma unroll
        for (int j = 0; j < 4; ++j) acc[i][j] = (f32x4){0.f, 0.f, 0.f, 0.f};

    for (int kt = 0; kt < 8; ++kt) {
        const int k0 = kt * 32;
        #pragma unroll
        for (int i = 0; i < 2; ++i) {
            int c = i * 256 + t, row = c >> 2, k8 = (c & 3) * 8;
            bf16x8 va;
            if (ABF) {
                va = *(const bf16x8*)(Ab + (size_t)(m0 + row) * 256 + k0 + k8);
            } else {
                const float* p = Af + (size_t)(m0 + row) * 256 + k0 + k8;
                float4v f0 = *(const float4v*)p, f1 = *(const float4v*)(p + 4);
                #pragma unroll
                for (int j = 0; j < 4; ++j) {
                    va[j] = (short)f2bf(f0[j]); va[4 + j] = (short)f2bf(f1[j]);
                }
            }
            *(bf16x8*)&As[c * 8] = va;
            const float* pb = Btb + (size_t)(n0 + row) * 256 + k0 + k8;
            float4v g0 = *(const float4v*)pb, g1 = *(const float4v*)(pb + 4);
            bf16x8 vb;
            #pragma unroll
            for (int j = 0; j < 4; ++j) {
                vb[j] = (short)f2bf(g0[j]); vb[4 + j] = (short)f2bf(g1[j]);
            }
            *(bf16x8*)&Bs[c * 8] = vb;
        }
        __syncthreads();
        bf16x8 a[4], b[4];
        #pragma unroll
        for (int fm = 0; fm < 4; ++fm)
            a[fm] = *(const bf16x8*)&As[(wr * 64 + fm * 16 + fr) * 32 + fk];
        #pragma unroll
        for (int fn = 0; fn < 4; ++fn)
            b[fn] = *(const bf16x8*)&Bs[(wc * 64 + fn * 16 + fr) * 32 + fk];
        #pragma unroll
        for (int fm = 0; fm < 4; ++fm)
            #pragma unroll
            for (int fn = 0; fn < 4; ++fn)
                acc[fm][fn] = __builtin_amdgcn_mfma_f32_16x16x32_bf16(
                    a[fm], b[fn], acc[fm][fn], 0, 0, 0);
        __syncthreads();
    }

    #pragma unroll
    for (int fm = 0; fm < 4; ++fm)
        #pragma unroll
        for (int fn = 0; fn < 4; ++fn) {
            int gcol = n0 + wc * 64 + fn * 16 + fr;
            #pragma unroll
            for (int r = 0; r < 4; ++r) {
                size_t grow = (size_t)(m0 + wr * 64 + fm * 16 + r0 + r);
                float v = acc[fm][fn][r];
                if (OBF) Obf[grow * 256 + gcol] = f2bf(v);
                else     Of[grow * 256 + outoff + gcol] = v + bias[gcol];
            }
        }
}

// ================= sqnorm (chunked + atomic; replay-stable since R8) =================
__global__ void sqnorm_kernel(const u16* __restrict__ Qb, const u16* __restrict__ Kb,
                              float* __restrict__ nq2, float* __restrict__ nk2) {
    const int b = blockIdx.x, which = blockIdx.y, ch = blockIdx.z;
    const u16* S = which ? Kb : Qb;
    float* dst = which ? nk2 : nq2;
    const int c = threadIdx.x;
    float s = 0.f;
    for (int n = ch * 512; n < ch * 512 + 512; ++n) {
        float v = bf2f(S[((size_t)b * NN + n) * 256 + c]);
        s += v * v;
    }
    atomicAdd(&dst[b * 256 + c], s);
}

// ================= xE via MFMA (swizzled staging) =================
// grid (16 b*kq, 8 nc), 256 thr. Swizzle col' = tok ^ (((row>>3)&7)<<3).
__global__ __launch_bounds__(256) void xe_mfma(
    const float* __restrict__ x, const float* __restrict__ Ew, float* __restrict__ xE)
{
    __shared__ u16 xsT[64][136];   // [k-local][tok], swizzled
    __shared__ u16 ewB[64][136];   // [p][tok]
    const int bkq = blockIdx.x, b = bkq >> 2, kq = bkq & 3, nc = blockIdx.y;
    const int t = threadIdx.x, lane = t & 63, w = t >> 6;
    const int fr = lane & 15, fk = (lane >> 4) * 8, r0 = (lane >> 4) * 4;

    f32x4 acc[4][4];
    #pragma unroll
    for (int i = 0; i < 4; ++i)
        #pragma unroll
        for (int j = 0; j < 4; ++j) acc[i][j] = (f32x4){0.f, 0.f, 0.f, 0.f};

    for (int it = 0; it < 8; ++it) {
        const int n0 = nc * 1024 + it * 128;
        #pragma unroll
        for (int i = 0; i < 4; ++i) {
            int c = i * 256 + t, tok = c >> 3, kl = (c & 7) * 8;
            const int sw = tok ^ ((kl >> 3) << 3);   // (row>>3)&7 == kl>>3 for rows kl..kl+7
            const float* p = x + ((size_t)b * NN + n0 + tok) * 256 + kq * 64 + kl;
            float4v f0 = *(const float4v*)p, f1 = *(const float4v*)(p + 4);
            #pragma unroll
            for (int j = 0; j < 4; ++j) {
                xsT[kl + j][sw]     = f2bf(f0[j]);
                xsT[kl + 4 + j][sw] = f2bf(f1[j]);
            }
        }
        #pragma unroll
        for (int i = 0; i < 4; ++i) {
            int c = i * 256 + t, p = c >> 4, tk8 = (c & 15) * 8;
            const float* pe = Ew + (size_t)p * NN + n0 + tk8;
            float4v g0 = *(const float4v*)pe, g1 = *(const float4v*)(pe + 4);
            bf16x8 v;
            #pragma unroll
            for (int j = 0; j < 4; ++j) {
                v[j] = (short)f2bf(g0[j]); v[4 + j] = (short)f2bf(g1[j]);
            }
            *(bf16x8*)&ewB[p][tk8] = v;
        }
        __syncthreads();
        bf16x8 a[4], bb[4];
        #pragma unroll
        for (int fm = 0; fm < 4; ++fm) {
            int row = fm * 16 + fr;
            a[fm] = *(const bf16x8*)&xsT[row][(w * 32 + fk) ^ ((((row) >> 3) & 7) << 3)];
        }
        #pragma unroll
        for (int fn = 0; fn < 4; ++fn)
            bb[fn] = *(const bf16x8*)&ewB[fn * 16 + fr][w * 32 + fk];
        #pragma unroll
        for (int fm = 0; fm < 4; ++fm)
            #pragma unroll
            for (int fn = 0; fn < 4; ++fn)
                acc[fm][fn] = __builtin_amdgcn_mfma_f32_16x16x32_bf16(
                    a[fm], bb[fn], acc[fm][fn], 0, 0, 0);
        __syncthreads();
    }

    float* Cred = (float*)&xsT[0][0];
    for (int ph = 0; ph < 4; ++ph) {
        if (w == ph) {
            #pragma unroll
            for (int fm = 0; fm < 4; ++fm)
                #pragma unroll
                for (int fn = 0; fn < 4; ++fn)
                    #pragma unroll
                    for (int r = 0; r < 4; ++r) {
                        int idx = (fm * 16 + r0 + r) * 64 + fn * 16 + fr;
                        if (ph == 0) Cred[idx] = acc[fm][fn][r];
                        else         Cred[idx] += acc[fm][fn][r];
                    }
        }
        __syncthreads();
    }
    float* dst = xE + (size_t)(b * 256 + kq * 64) * 64;
    #pragma unroll
    for (int i = 0; i < 16; ++i) atomicAdd(&dst[i * 256 + t], Cred[i * 256 + t]);
}

// ================= calog via MFMA, deterministic split-N=8, swizzled =================
// grid (16 bh, 8 nc), 256 thr. Each block: 1024 tokens -> part[nc].
__global__ __launch_bounds__(256) void calog_part(
    const u16* __restrict__ Qb, const u16* __restrict__ Kb, float* __restrict__ part)
{
    __shared__ u16 QsT[64][136];
    __shared__ u16 KsT[64][136];
    const int bh = blockIdx.x, b = bh >> 2, h = bh & 3, nc = blockIdx.y;
    const int t = threadIdx.x, lane = t & 63, w = t >> 6;
    const int fr = lane & 15, fk = (lane >> 4) * 8, r0 = (lane >> 4) * 4;

    f32x4 acc[4][4];
    #pragma unroll
    for (int i = 0; i < 4; ++i)
        #pragma unroll
        for (int j = 0; j < 4; ++j) acc[i][j] = (f32x4){0.f, 0.f, 0.f, 0.f};

    for (int it = 0; it < 8; ++it) {
        const int n0 = nc * 1024 + it * 128;
        #pragma unroll
        for (int i = 0; i < 4; ++i) {
            int c = i * 256 + t, tok = c >> 3, ch8 = (c & 7) * 8;
            const int sw = tok ^ ((ch8 >> 3) << 3);
            size_t g = ((size_t)b * NN + n0 + tok) * 256 + h * 64 + ch8;
            bf16x8 vq = *(const bf16x8*)(Qb + g);
            bf16x8 vk = *(const bf16x8*)(Kb + g);
            #pragma unroll
            for (int j = 0; j < 8; ++j) {
                QsT[ch8 + j][sw] = (u16)vq[j];
                KsT[ch8 + j][sw] = (u16)vk[j];
            }
        }
        __syncthreads();
        bf16x8 a[4], bb[4];
        #pragma unroll
        for (int fm = 0; fm < 4; ++fm) {
            int row = fm * 16 + fr;
            a[fm] = *(const bf16x8*)&QsT[row][(w * 32 + fk) ^ (((row >> 3) & 7) << 3)];
        }
        #pragma unroll
        for (int fn = 0; fn < 4; ++fn) {
            int row = fn * 16 + fr;
            bb[fn] = *(const bf16x8*)&KsT[row][(w * 32 + fk) ^ (((row >> 3) & 7) << 3)];
        }
        #pragma unroll
        for (int fm = 0; fm < 4; ++fm)
            #pragma unroll
            for (int fn = 0; fn < 4; ++fn)
                acc[fm][fn] = __builtin_amdgcn_mfma_f32_16x16x32_bf16(
                    a[fm], bb[fn], acc[fm][fn], 0, 0, 0);
        __syncthreads();
    }

    float* Cred = (float*)&QsT[0][0];
    for (int ph = 0; ph < 4; ++ph) {
        if (w == ph) {
            #pragma unroll
            for (int fm = 0; fm < 4; ++fm)
                #pragma unroll
                for (int fn = 0; fn < 4; ++fn)
                    #pragma unroll
                    for (int r = 0; r < 4; ++r) {
                        int idx = (fm * 16 + r0 + r) * 64 + fn * 16 + fr;
                        if (ph == 0) Cred[idx] = acc[fm][fn][r];
                        else         Cred[idx] += acc[fm][fn][r];
                    }
        }
        __syncthreads();
    }
    float* dst = part + (size_t)nc * 65536 + (size_t)bh * 4096;
    #pragma unroll
    for (int i = 0; i < 16; ++i) dst[i * 256 + t] = Cred[i * 256 + t];
}

// fixed-order 8-way sum, in-place safe (reads all parts, then writes calog=part[2])
__global__ void calog_reduce(const float* __restrict__ part, float* __restrict__ calog) {
    int i = blockIdx.x * 256 + threadIdx.x;
    float s = part[i];
    #pragma unroll
    for (int nc = 1; nc < 8; ++nc) s += part[(size_t)nc * 65536 + i];
    calog[i] = s;
}

// ---------------- kp/vp (kept) ----------------
__global__ void kvproj_kernel(const float* __restrict__ Wk, const float* __restrict__ Wvsa,
                              const float* __restrict__ xE, const float* __restrict__ Eb,
                              float* __restrict__ kp, float* __restrict__ vp) {
    const int b = blockIdx.x >> 8, c = blockIdx.x & 255, z = blockIdx.y, p = threadIdx.x;
    const float* W = z ? Wvsa : Wk;
    float* dst = z ? vp : kp;
    float s = 0.f;
    for (int k = 0; k < 256; ++k)
        s += W[c * 256 + k] * xE[(size_t)(b * 256 + k) * 64 + p];
    dst[(size_t)(b * 256 + c) * 64 + p] = s + Eb[p];
}

// ---------------- casoftmax (kept) ----------------
__global__ void casoftmax_kernel(const float* __restrict__ calog, const float* __restrict__ nq2,
                                 const float* __restrict__ nk2, const float* __restrict__ temp,
                                 float* __restrict__ caprob) {
    const int row = blockIdx.x;
    const int b = row >> 8, c = row & 255, h = c >> 6;
    const int e = threadIdx.x;
    float nq = fmaxf(sqrtf(nq2[row]), 1e-12f);
    float nk = fmaxf(sqrtf(nk2[b * 256 + h * 64 + e]), 1e-12f);
    float v = calog[row * 64 + e] / (nq * nk) * temp[h];
    __shared__ float red[64];
    red[e] = v; __syncthreads();
    for (int s = 32; s; s >>= 1) { if (e < s) red[e] = fmaxf(red[e], red[e + s]); __syncthreads(); }
    float m = red[0]; __syncthreads();
    float ex = __expf(v - m);
    red[e] = ex; __syncthreads();
    for (int s = 32; s; s >>= 1) { if (e < s) red[e] += red[e + s]; __syncthreads(); }
    caprob[row * 64 + e] = ex / red[0];
}

// ---------------- buildm (kept) ----------------
__global__ void buildm_kernel(const float* __restrict__ caprob, const float* __restrict__ Wo2,
                              float* __restrict__ M) {
    const int b = blockIdx.x >> 7, j = blockIdx.x & 127, c = threadIdx.x;
    const int h = c >> 6, e = c & 63;
    float s = 0.f;
    #pragma unroll 8
    for (int d = 0; d < 64; ++d)
        s += Wo2[j * 256 + h * 64 + d] * caprob[(size_t)(b * 256 + h * 64 + d) * 64 + e];
    M[(size_t)blockIdx.x * 256 + c] = s;
}

// ---------------- w2eff (kept) ----------------
__global__ void w2eff_kernel(const float* __restrict__ M, const float* __restrict__ Wvca,
                             float* __restrict__ W2eff) {
    const int k = threadIdx.x;
    const float* Mrow = M + (size_t)blockIdx.x * 256;
    float s = 0.f;
    for (int c = 0; c < 256; ++c) s += Mrow[c] * Wvca[c * 256 + k];
    W2eff[(size_t)blockIdx.x * 256 + k] = s;
}

// ================= MFMA spatial attention (kept) =================
__global__ __launch_bounds__(256) void sa_mfma(
    const u16* __restrict__ Qb, const float* __restrict__ kp,
    const float* __restrict__ vp, const float* __restrict__ nq2,
    const float* __restrict__ temp2, u16* __restrict__ xsa)
{
    __shared__ char smem[49152];
    u16* Qs = (u16*)smem;
    u16* KT = (u16*)(smem + 32768);
    u16* VT = (u16*)(smem + 40960);
    const int nc = blockIdx.x, bh = blockIdx.y, b = bh >> 2, h = bh & 3;
    const int t = threadIdx.x, lane = t & 63, w = t >> 6;
    const int fr = lane & 15, fk = (lane >> 4) * 8, r0 = (lane >> 4) * 4;

    #pragma unroll
    for (int i = 0; i < 8; ++i) {
        int c = i * 256 + t, tok = c >> 3, ch8 = (c & 7) * 8;
        *(bf16x8*)&Qs[c * 8] =
            *(const bf16x8*)(Qb + ((size_t)b * NN + nc * 256 + tok) * 256 + h * 64 + ch8);
    }
    {
        const int d = t >> 2, p0 = (t & 3) * 16;
        const float rqv = 1.0f / fmaxf(sqrtf(nq2[b * 256 + h * 64 + d]), 1e-12f);
        const float t2 = temp2[h];
        const float* kr = kp + (size_t)(b * 256 + h * 64 + d) * 64 + p0;
        #pragma unroll
        for (int j = 0; j < 16; ++j)
            KT[(p0 + j) * 64 + d] = f2bf(kr[j] * rqv * t2);
    }
    {
        const float* vs = vp + (size_t)(b * 256 + h * 64) * 64;
        #pragma unroll
        for (int i = 0; i < 2; ++i) {
            int c = i * 256 + t;
            bf16x8 v;
            #pragma unroll
            for (int j = 0; j < 8; ++j) v[j] = (short)f2bf(vs[c * 8 + j]);
            *(bf16x8*)&VT[c * 8] = v;
        }
    }
    __syncthreads();

    f32x4 acc[4][4];
    #pragma unroll
    for (int i = 0; i < 4; ++i)
        #pragma unroll
        for (int j = 0; j < 4; ++j) acc[i][j] = (f32x4){0.f, 0.f, 0.f, 0.f};
    #pragma unroll
    for (int ks = 0; ks < 2; ++ks) {
        bf16x8 a[4], bb[4];
        #pragma unroll
        for (int fm = 0; fm < 4; ++fm)
            a[fm] = *(const bf16x8*)&Qs[(w * 64 + fm * 16 + fr) * 64 + ks * 32 + fk];
        #pragma unroll
        for (int fn = 0; fn < 4; ++fn)
            bb[fn] = *(const bf16x8*)&KT[(fn * 16 + fr) * 64 + ks * 32 + fk];
        #pragma unroll
        for (int fm = 0; fm < 4; ++fm)
            #pragma unroll
            for (int fn = 0; fn < 4; ++fn)
                acc[fm][fn] = __builtin_amdgcn_mfma_f32_16x16x32_bf16(
                    a[fm], bb[fn], acc[fm][fn], 0, 0, 0);
    }
    __syncthreads();

    u16* Pw = Qs + w * 4096;
    #pragma unroll
    for (int fm = 0; fm < 4; ++fm) {
        #pragma unroll
        for (int r = 0; r < 4; ++r) {
            float m = fmaxf(fmaxf(acc[fm][0][r], acc[fm][1][r]),
                            fmaxf(acc[fm][2][r], acc[fm][3][r]));
            m = fmaxf(m, __shfl_xor(m, 1));
            m = fmaxf(m, __shfl_xor(m, 2));
            m = fmaxf(m, __shfl_xor(m, 4));
            m = fmaxf(m, __shfl_xor(m, 8));
            float e0 = __expf(acc[fm][0][r] - m), e1 = __expf(acc[fm][1][r] - m);
            float e2 = __expf(acc[fm][2][r] - m), e3 = __expf(acc[fm][3][r] - m);
            float s = e0 + e1 + e2 + e3;
            s += __shfl_xor(s, 1); s += __shfl_xor(s, 2);
            s += __shfl_xor(s, 4); s += __shfl_xor(s, 8);
            float rs = 1.0f / s;
            int row = fm * 16 + r0 + r;
            Pw[row * 64 +  0 + fr] = f2bf(e0 * rs);
            Pw[row * 64 + 16 + fr] = f2bf(e1 * rs);
            Pw[row * 64 + 32 + fr] = f2bf(e2 * rs);
            Pw[row * 64 + 48 + fr] = f2bf(e3 * rs);
        }
    }

    f32x4 acc2[4][4];
    #pragma unroll
    for (int i = 0; i < 4; ++i)
        #pragma unroll
        for (int j = 0; j < 4; ++j) acc2[i][j] = (f32x4){0.f, 0.f, 0.f, 0.f};
    #pragma unroll
    for (int ks = 0; ks < 2; ++ks) {
        bf16x8 a[4], bb[4];
        #pragma unroll
        for (int fm = 0; fm < 4; ++fm)
            a[fm] = *(const bf16x8*)&Pw[(fm * 16 + fr) * 64 + ks * 32 + fk];
        #pragma unroll
        for (int fn = 0; fn < 4; ++fn)
            bb[fn] = *(const bf16x8*)&VT[(fn * 16 + fr) * 64 + ks * 32 + fk];
        #pragma unroll
        for (int fm = 0; fm < 4; ++fm)
            #pragma unroll
            for (int fn = 0; fn < 4; ++fn)
                acc2[fm][fn] = __builtin_amdgcn_mfma_f32_16x16x32_bf16(
                    a[fm], bb[fn], acc2[fm][fn], 0, 0, 0);
    }
    __syncthreads();

    u16* X2 = Qs;
    #pragma unroll
    for (int fm = 0; fm < 4; ++fm)
        #pragma unroll
        for (int fn = 0; fn < 4; ++fn)
            #pragma unroll
            for (int r = 0; r < 4; ++r)
                X2[(w * 64 + fm * 16 + r0 + r) * 64 + fn * 16 + fr] = f2bf(acc2[fm][fn][r]);
    __syncthreads();

    {
        const int d = t >> 2, cq = (t & 3) * 64;
        u16* orow = xsa + ((size_t)b * NN + d * 128 + h * 32 + nc) * 256 + cq;
        #pragma unroll
        for (int i = 0; i < 8; ++i) {
            bf16x8 v;
            #pragma unroll
            for (int j = 0; j < 8; ++j) v[j] = (short)X2[(cq + i * 8 + j) * 64 + d];
            *(bf16x8*)&orow[i * 8] = v;
        }
    }
}

extern "C" void kernel_launch(void* const* d_in, const int* in_sizes, int n_in,
                              void* d_out, int out_size, void* d_ws, size_t ws_size,
                              hipStream_t stream) {
    float* out = (float*)d_out;

    static const int expect[14] = {8388608, 8388608, 65536, 65536, 65536, 65536,
                                   524288, 64, 4, 4, 32768, 128, 32768, 128};
    bool ok = (n_in == 14) && (out_size == 8388608);
    if (ok) for (int i = 0; i < 14; ++i) ok = ok && (in_sizes[i] == expect[i]);
    if (!ok) {
        fill_kernel<<<dim3(8192), 256, 0, stream>>>(out, 3000.0f);
        return;
    }
    if (ws_size < 36000000u) {
        fill_kernel<<<dim3(8192), 256, 0, stream>>>(out, 1000.0f);
        return;
    }

    const float* x    = (const float*)d_in[0];
    const float* q    = (const float*)d_in[1];
    const float* Wq   = (const float*)d_in[2];
    const float* Wk   = (const float*)d_in[3];
    const float* Wvca = (const float*)d_in[4];
    const float* Wvsa = (const float*)d_in[5];
    const float* Ew   = (const float*)d_in[6];
    const float* Eb   = (const float*)d_in[7];
    const float* temp = (const float*)d_in[8];
    const float* temp2= (const float*)d_in[9];
    const float* Wo1  = (const float*)d_in[10];
    const float* bo1  = (const float*)d_in[11];
    const float* Wo2  = (const float*)d_in[12];
    const float* bo2  = (const float*)d_in[13];

    u16* Qb = (u16*)d_ws;
    u16* Kb = Qb + (size_t)BNC;          // reused as xsa after calog (stream-ordered)
    u16* xsa = Kb;
    float* fs    = (float*)(Kb + (size_t)BNC);
    float* nq2   = fs;                   // 1024
    float* nk2   = nq2 + 1024;           // 1024
    float* xE    = nk2 + 1024;           // 65536
    float* kp    = xE + 65536;           // 65536  = cpart region 0
    float* vp    = kp + 65536;           // 65536  = cpart region 1
    float* calog = vp + 65536;           // 65536  = cpart region 2
    float* caprob= calog + 65536;        // 65536  = cpart region 3
    float* M     = caprob + 65536;       // 131072 = cpart regions 4,5
    float* W2eff = M + 131072;           // 131072 = cpart regions 6,7
    float* cpart = kp;                   // 8 x 65536 partials, consumed before kvproj et al.

    // zero the atomic accumulators: nq2, nk2, xE = 67584 floats
    zero_kernel<<<dim3(264), 256, 0, stream>>>(nq2, 67584);
    gemm_qkf<<<dim3(256, 2, 2), 256, 0, stream>>>(x, q, Wq, Wk, Qb, Kb);
    sqnorm_kernel<<<dim3(4, 2, 16), 256, 0, stream>>>(Qb, Kb, nq2, nk2);
    xe_mfma<<<dim3(16, 8), 256, 0, stream>>>(x, Ew, xE);
    calog_part<<<dim3(16, 8), 256, 0, stream>>>(Qb, Kb, cpart);
    calog_reduce<<<dim3(256), 256, 0, stream>>>(cpart, calog);
    kvproj_kernel<<<dim3(1024, 2), 64, 0, stream>>>(Wk, Wvsa, xE, Eb, kp, vp);
    casoftmax_kernel<<<dim3(1024), 64, 0, stream>>>(calog, nq2, nk2, temp, caprob);
    buildm_kernel<<<dim3(512), 256, 0, stream>>>(caprob, Wo2, M);
    w2eff_kernel<<<dim3(512), 256, 0, stream>>>(M, Wvca, W2eff);
    gemm128<0, 0><<<dim3(256, 1), 256, 0, stream>>>(x, W2eff, 128 * 256, nullptr, out, bo2, 128);
    sa_mfma<<<dim3(32, 16), 256, 0, stream>>>(Qb, kp, vp, nq2, temp2, xsa);
    gemm128<1, 0><<<dim3(256, 1), 256, 0, stream>>>(xsa, Wo1, 0, nullptr, out, bo1, 0);
}

// Round 13
// 140.615 us; speedup vs baseline: 27.0181x; 1.1184x over previous
//
#include <hip/hip_runtime.h>
#include <hip/hip_bf16.h>

// Shapes: B=4, N=8192, C=256, H=4, D=64, P=64
#define NN 8192
#define BNC 8388608   // B*N*C

typedef unsigned short u16;
typedef unsigned int u32;
typedef __attribute__((ext_vector_type(8))) short bf16x8;
typedef __attribute__((ext_vector_type(4))) float f32x4;
typedef __attribute__((ext_vector_type(4))) float float4v;

__device__ __forceinline__ float bf2f(u16 u) {
    union { u32 i; float f; } c; c.i = ((u32)u) << 16; return c.f;
}
__device__ __forceinline__ u16 f2bf(float f) {
    union { float f; u32 i; } c; c.f = f;
    u32 x = c.i;
    u32 r = (x + 0x7fffu + ((x >> 16) & 1u)) >> 16;  // RNE
    return (u16)r;
}

// ---------------- diagnostic fill ----------------
__global__ void fill_kernel(float* __restrict__ out, float val) {
    int base = (blockIdx.x * 256 + threadIdx.x) * 4;
    #pragma unroll
    for (int i = 0; i < 4; ++i) out[base + i] = val;
}

// ---------------- zero ----------------
__global__ void zero_kernel(float* __restrict__ p, int n) {
    int i = blockIdx.x * 256 + threadIdx.x;
    if (i < n) p[i] = 0.f;
}

// ---------------- bulk fp32 -> bf16 conversion (q->qb, x->xb) ----------------
__global__ void conv_kernel(const float* __restrict__ q, const float* __restrict__ x,
                            u16* __restrict__ qb, u16* __restrict__ xb) {
    const float* src = blockIdx.y ? x : q;
    u16* dst = blockIdx.y ? xb : qb;
    size_t i = ((size_t)blockIdx.x * 256 + threadIdx.x) * 8;
    float4v f0 = *(const float4v*)(src + i), f1 = *(const float4v*)(src + i + 4);
    bf16x8 v;
    #pragma unroll
    for (int j = 0; j < 4; ++j) {
        v[j] = (short)f2bf(f0[j]); v[4 + j] = (short)f2bf(f1[j]);
    }
    *(bf16x8*)(dst + i) = v;
}

// ================= fused Q/K GEMM (bf16 A) + column sq-norm epilogue =================
// z=0: qb@Wq^T->Qb (+nq2) ; z=1: xb@Wk^T->Kb (+nk2)
__global__ __launch_bounds__(256) void gemm_qkf(
    const u16* __restrict__ qb, const u16* __restrict__ xb,
    const float* __restrict__ Wq, const float* __restrict__ Wk,
    u16* __restrict__ Qb, u16* __restrict__ Kb,
    float* __restrict__ nq2, float* __restrict__ nk2)
{
    __shared__ u16 As[4096];   // [128][32] bf16 linear
    __shared__ u16 Bs[4096];
    const int z = blockIdx.z;
    const u16* A = z ? xb : qb;
    const float* Bt = z ? Wk : Wq;
    u16* O = z ? Kb : Qb;
    float* dstn = z ? nk2 : nq2;
    const int t = threadIdx.x, lane = t & 63, w = t >> 6;
    const int wr = w >> 1, wc = w & 1;
    const int fr = lane & 15, fk = (lane >> 4) * 8, r0 = (lane >> 4) * 4;
    const int m0 = blockIdx.x * 128, n0 = blockIdx.y * 128;
    const int b = m0 >> 13;

    f32x4 acc[4][4];
    #pragma unroll
    for (int i = 0; i < 4; ++i)
        #pragma unroll
        for (int j = 0; j < 4; ++j) acc[i][j] = (f32x4){0.f, 0.f, 0.f, 0.f};

    for (int kt = 0; kt < 8; ++kt) {
        const int k0 = kt * 32;
        #pragma unroll
        for (int i = 0; i < 2; ++i) {
            int c = i * 256 + t, row = c >> 2, k8 = (c & 3) * 8;
            *(bf16x8*)&As[c * 8] =
                *(const bf16x8*)(A + (size_t)(m0 + row) * 256 + k0 + k8);
            const float* pb = Bt + (size_t)(n0 + row) * 256 + k0 + k8;
            float4v g0 = *(const float4v*)pb, g1 = *(const float4v*)(pb + 4);
            bf16x8 vb;
            #pragma unroll
            for (int j = 0; j < 4; ++j) {
                vb[j] = (short)f2bf(g0[j]); vb[4 + j] = (short)f2bf(g1[j]);
            }
            *(bf16x8*)&Bs[c * 8] = vb;
        }
        __syncthreads();
        bf16x8 a[4], b[4];
        #pragma unroll
        for (int fm = 0; fm < 4; ++fm)
            a[fm] = *(const bf16x8*)&As[(wr * 64 + fm * 16 + fr) * 32 + fk];
        #pragma unroll
        for (int fn = 0; fn < 4; ++fn)
            b[fn] = *(const bf16x8*)&Bs[(wc * 64 + fn * 16 + fr) * 32 + fk];
        #pragma unroll
        for (int fm = 0; fm < 4; ++fm)
            #pragma unroll
            for (int fn = 0; fn < 4; ++fn)
                acc[fm][fn] = __builtin_amdgcn_mfma_f32_16x16x32_bf16(
                    a[fm], b[fn], acc[fm][fn], 0, 0, 0);
        __syncthreads();
    }

    #pragma unroll
    for (int fn = 0; fn < 4; ++fn) {
        int gcol = n0 + wc * 64 + fn * 16 + fr;
        float s = 0.f;
        #pragma unroll
        for (int fm = 0; fm < 4; ++fm) {
            #pragma unroll
            for (int r = 0; r < 4; ++r) {
                size_t grow = (size_t)(m0 + wr * 64 + fm * 16 + r0 + r);
                float v = acc[fm][fn][r];
                O[grow * 256 + gcol] = f2bf(v);
                s += v * v;
            }
        }
        s += __shfl_xor(s, 16);
        s += __shfl_xor(s, 32);
        if (lane < 16) atomicAdd(&dstn[b * 256 + gcol], s);
    }
}

// ================= xE via MFMA (bf16 xb, swizzled staging) =================
__global__ __launch_bounds__(256) void xe_mfma(
    const u16* __restrict__ xb, const float* __restrict__ Ew, float* __restrict__ xE)
{
    __shared__ u16 xsT[64][136];   // [k-local][tok], swizzled
    __shared__ u16 ewB[64][136];   // [p][tok]
    const int bkq = blockIdx.x, b = bkq >> 2, kq = bkq & 3, nc = blockIdx.y;
    const int t = threadIdx.x, lane = t & 63, w = t >> 6;
    const int fr = lane & 15, fk = (lane >> 4) * 8, r0 = (lane >> 4) * 4;

    f32x4 acc[4][4];
    #pragma unroll
    for (int i = 0; i < 4; ++i)
        #pragma unroll
        for (int j = 0; j < 4; ++j) acc[i][j] = (f32x4){0.f, 0.f, 0.f, 0.f};

    for (int it = 0; it < 8; ++it) {
        const int n0 = nc * 1024 + it * 128;
        #pragma unroll
        for (int i = 0; i < 4; ++i) {
            int c = i * 256 + t, tok = c >> 3, kl = (c & 7) * 8;
            const int sw = tok ^ ((kl >> 3) << 3);
            bf16x8 v = *(const bf16x8*)(xb + ((size_t)b * NN + n0 + tok) * 256 + kq * 64 + kl);
            #pragma unroll
            for (int j = 0; j < 8; ++j) xsT[kl + j][sw] = (u16)v[j];
        }
        #pragma unroll
        for (int i = 0; i < 4; ++i) {
            int c = i * 256 + t, p = c >> 4, tk8 = (c & 15) * 8;
            const float* pe = Ew + (size_t)p * NN + n0 + tk8;
            float4v g0 = *(const float4v*)pe, g1 = *(const float4v*)(pe + 4);
            bf16x8 v;
            #pragma unroll
            for (int j = 0; j < 4; ++j) {
                v[j] = (short)f2bf(g0[j]); v[4 + j] = (short)f2bf(g1[j]);
            }
            *(bf16x8*)&ewB[p][tk8] = v;
        }
        __syncthreads();
        bf16x8 a[4], bb[4];
        #pragma unroll
        for (int fm = 0; fm < 4; ++fm) {
            int row = fm * 16 + fr;
            a[fm] = *(const bf16x8*)&xsT[row][(w * 32 + fk) ^ (((row >> 3) & 7) << 3)];
        }
        #pragma unroll
        for (int fn = 0; fn < 4; ++fn)
            bb[fn] = *(const bf16x8*)&ewB[fn * 16 + fr][w * 32 + fk];
        #pragma unroll
        for (int fm = 0; fm < 4; ++fm)
            #pragma unroll
            for (int fn = 0; fn < 4; ++fn)
                acc[fm][fn] = __builtin_amdgcn_mfma_f32_16x16x32_bf16(
                    a[fm], bb[fn], acc[fm][fn], 0, 0, 0);
        __syncthreads();
    }

    float* Cred = (float*)&xsT[0][0];
    for (int ph = 0; ph < 4; ++ph) {
        if (w == ph) {
            #pragma unroll
            for (int fm = 0; fm < 4; ++fm)
                #pragma unroll
                for (int fn = 0; fn < 4; ++fn)
                    #pragma unroll
                    for (int r = 0; r < 4; ++r) {
                        int idx = (fm * 16 + r0 + r) * 64 + fn * 16 + fr;
                        if (ph == 0) Cred[idx] = acc[fm][fn][r];
                        else         Cred[idx] += acc[fm][fn][r];
                    }
        }
        __syncthreads();
    }
    float* dst = xE + (size_t)(b * 256 + kq * 64) * 64;
    #pragma unroll
    for (int i = 0; i < 16; ++i) atomicAdd(&dst[i * 256 + t], Cred[i * 256 + t]);
}

// ================= calog via MFMA, deterministic split-N=8, swizzled =================
__global__ __launch_bounds__(256) void calog_part(
    const u16* __restrict__ Qb, const u16* __restrict__ Kb, float* __restrict__ part)
{
    __shared__ u16 QsT[64][136];
    __shared__ u16 KsT[64][136];
    const int bh = blockIdx.x, b = bh >> 2, h = bh & 3, nc = blockIdx.y;
    const int t = threadIdx.x, lane = t & 63, w = t >> 6;
    const int fr = lane & 15, fk = (lane >> 4) * 8, r0 = (lane >> 4) * 4;

    f32x4 acc[4][4];
    #pragma unroll
    for (int i = 0; i < 4; ++i)
        #pragma unroll
        for (int j = 0; j < 4; ++j) acc[i][j] = (f32x4){0.f, 0.f, 0.f, 0.f};

    for (int it = 0; it < 8; ++it) {
        const int n0 = nc * 1024 + it * 128;
        #pragma unroll
        for (int i = 0; i < 4; ++i) {
            int c = i * 256 + t, tok = c >> 3, ch8 = (c & 7) * 8;
            const int sw = tok ^ ((ch8 >> 3) << 3);
            size_t g = ((size_t)b * NN + n0 + tok) * 256 + h * 64 + ch8;
            bf16x8 vq = *(const bf16x8*)(Qb + g);
            bf16x8 vk = *(const bf16x8*)(Kb + g);
            #pragma unroll
            for (int j = 0; j < 8; ++j) {
                QsT[ch8 + j][sw] = (u16)vq[j];
                KsT[ch8 + j][sw] = (u16)vk[j];
            }
        }
        __syncthreads();
        bf16x8 a[4], bb[4];
        #pragma unroll
        for (int fm = 0; fm < 4; ++fm) {
            int row = fm * 16 + fr;
            a[fm] = *(const bf16x8*)&QsT[row][(w * 32 + fk) ^ (((row >> 3) & 7) << 3)];
        }
        #pragma unroll
        for (int fn = 0; fn < 4; ++fn) {
            int row = fn * 16 + fr;
            bb[fn] = *(const bf16x8*)&KsT[row][(w * 32 + fk) ^ (((row >> 3) & 7) << 3)];
        }
        #pragma unroll
        for (int fm = 0; fm < 4; ++fm)
            #pragma unroll
            for (int fn = 0; fn < 4; ++fn)
                acc[fm][fn] = __builtin_amdgcn_mfma_f32_16x16x32_bf16(
                    a[fm], bb[fn], acc[fm][fn], 0, 0, 0);
        __syncthreads();
    }

    float* Cred = (float*)&QsT[0][0];
    for (int ph = 0; ph < 4; ++ph) {
        if (w == ph) {
            #pragma unroll
            for (int fm = 0; fm < 4; ++fm)
                #pragma unroll
                for (int fn = 0; fn < 4; ++fn)
                    #pragma unroll
                    for (int r = 0; r < 4; ++r) {
                        int idx = (fm * 16 + r0 + r) * 64 + fn * 16 + fr;
                        if (ph == 0) Cred[idx] = acc[fm][fn][r];
                        else         Cred[idx] += acc[fm][fn][r];
                    }
        }
        __syncthreads();
    }
    float* dst = part + (size_t)nc * 65536 + (size_t)bh * 4096;
    #pragma unroll
    for (int i = 0; i < 16; ++i) dst[i * 256 + t] = Cred[i * 256 + t];
}

// ---------------- casoftmax fused with 8-part reduce ----------------
// caprob aliases part[3]: per-thread same-index read-then-write, safe.
__global__ void casoftmax_kernel(const float* __restrict__ part, const float* __restrict__ nq2,
                                 const float* __restrict__ nk2, const float* __restrict__ temp,
                                 float* __restrict__ caprob) {
    const int row = blockIdx.x;
    const int b = row >> 8, c = row & 255, h = c >> 6;
    const int e = threadIdx.x;
    const int i = row * 64 + e;
    float lg = part[i];
    #pragma unroll
    for (int nc = 1; nc < 8; ++nc) lg += part[(size_t)nc * 65536 + i];
    float nq = fmaxf(sqrtf(nq2[row]), 1e-12f);
    float nk = fmaxf(sqrtf(nk2[b * 256 + h * 64 + e]), 1e-12f);
    float v = lg / (nq * nk) * temp[h];
    __shared__ float red[64];
    red[e] = v; __syncthreads();
    for (int s = 32; s; s >>= 1) { if (e < s) red[e] = fmaxf(red[e], red[e + s]); __syncthreads(); }
    float m = red[0]; __syncthreads();
    float ex = __expf(v - m);
    red[e] = ex; __syncthreads();
    for (int s = 32; s; s >>= 1) { if (e < s) red[e] += red[e + s]; __syncthreads(); }
    caprob[i] = ex / red[0];
}

// ---------------- kp/vp (kept) ----------------
__global__ void kvproj_kernel(const float* __restrict__ Wk, const float* __restrict__ Wvsa,
                              const float* __restrict__ xE, const float* __restrict__ Eb,
                              float* __restrict__ kp, float* __restrict__ vp) {
    const int b = blockIdx.x >> 8, c = blockIdx.x & 255, z = blockIdx.y, p = threadIdx.x;
    const float* W = z ? Wvsa : Wk;
    float* dst = z ? vp : kp;
    float s = 0.f;
    for (int k = 0; k < 256; ++k)
        s += W[c * 256 + k] * xE[(size_t)(b * 256 + k) * 64 + p];
    dst[(size_t)(b * 256 + c) * 64 + p] = s + Eb[p];
}

// ---------------- fused buildm + w2eff ----------------
// block = b*128+j : phase1 M-row to LDS, phase2 W2eff row.
__global__ void mw2eff_kernel(const float* __restrict__ caprob, const float* __restrict__ Wo2,
                              const float* __restrict__ Wvca, float* __restrict__ W2eff) {
    __shared__ float Ml[256];
    const int b = blockIdx.x >> 7, j = blockIdx.x & 127;
    const int t = threadIdx.x, h = t >> 6, e = t & 63;
    float s = 0.f;
    #pragma unroll 8
    for (int d = 0; d < 64; ++d)
        s += Wo2[j * 256 + h * 64 + d] * caprob[(size_t)(b * 256 + h * 64 + d) * 64 + e];
    Ml[t] = s;
    __syncthreads();
    float s2 = 0.f;
    for (int c = 0; c < 256; ++c) s2 += Ml[c] * Wvca[c * 256 + t];
    W2eff[(size_t)blockIdx.x * 256 + t] = s2;
}

// ================= MFMA spatial attention (kept) =================
__global__ __launch_bounds__(256) void sa_mfma(
    const u16* __restrict__ Qb, const float* __restrict__ kp,
    const float* __restrict__ vp, const float* __restrict__ nq2,
    const float* __restrict__ temp2, u16* __restrict__ xsa)
{
    __shared__ char smem[49152];
    u16* Qs = (u16*)smem;
    u16* KT = (u16*)(smem + 32768);
    u16* VT = (u16*)(smem + 40960);
    const int nc = blockIdx.x, bh = blockIdx.y, b = bh >> 2, h = bh & 3;
    const int t = threadIdx.x, lane = t & 63, w = t >> 6;
    const int fr = lane & 15, fk = (lane >> 4) * 8, r0 = (lane >> 4) * 4;

    #pragma unroll
    for (int i = 0; i < 8; ++i) {
        int c = i * 256 + t, tok = c >> 3, ch8 = (c & 7) * 8;
        *(bf16x8*)&Qs[c * 8] =
            *(const bf16x8*)(Qb + ((size_t)b * NN + nc * 256 + tok) * 256 + h * 64 + ch8);
    }
    {
        const int d = t >> 2, p0 = (t & 3) * 16;
        const float rqv = 1.0f / fmaxf(sqrtf(nq2[b * 256 + h * 64 + d]), 1e-12f);
        const float t2 = temp2[h];
        const float* kr = kp + (size_t)(b * 256 + h * 64 + d) * 64 + p0;
        #pragma unroll
        for (int j = 0; j < 16; ++j)
            KT[(p0 + j) * 64 + d] = f2bf(kr[j] * rqv * t2);
    }
    {
        const float* vs = vp + (size_t)(b * 256 + h * 64) * 64;
        #pragma unroll
        for (int i = 0; i < 2; ++i) {
            int c = i * 256 + t;
            bf16x8 v;
            #pragma unroll
            for (int j = 0; j < 8; ++j) v[j] = (short)f2bf(vs[c * 8 + j]);
            *(bf16x8*)&VT[c * 8] = v;
        }
    }
    __syncthreads();

    f32x4 acc[4][4];
    #pragma unroll
    for (int i = 0; i < 4; ++i)
        #pragma unroll
        for (int j = 0; j < 4; ++j) acc[i][j] = (f32x4){0.f, 0.f, 0.f, 0.f};
    #pragma unroll
    for (int ks = 0; ks < 2; ++ks) {
        bf16x8 a[4], bb[4];
        #pragma unroll
        for (int fm = 0; fm < 4; ++fm)
            a[fm] = *(const bf16x8*)&Qs[(w * 64 + fm * 16 + fr) * 64 + ks * 32 + fk];
        #pragma unroll
        for (int fn = 0; fn < 4; ++fn)
            bb[fn] = *(const bf16x8*)&KT[(fn * 16 + fr) * 64 + ks * 32 + fk];
        #pragma unroll
        for (int fm = 0; fm < 4; ++fm)
            #pragma unroll
            for (int fn = 0; fn < 4; ++fn)
                acc[fm][fn] = __builtin_amdgcn_mfma_f32_16x16x32_bf16(
                    a[fm], bb[fn], acc[fm][fn], 0, 0, 0);
    }
    __syncthreads();

    u16* Pw = Qs + w * 4096;
    #pragma unroll
    for (int fm = 0; fm < 4; ++fm) {
        #pragma unroll
        for (int r = 0; r < 4; ++r) {
            float m = fmaxf(fmaxf(acc[fm][0][r], acc[fm][1][r]),
                            fmaxf(acc[fm][2][r], acc[fm][3][r]));
            m = fmaxf(m, __shfl_xor(m, 1));
            m = fmaxf(m, __shfl_xor(m, 2));
            m = fmaxf(m, __shfl_xor(m, 4));
            m = fmaxf(m, __shfl_xor(m, 8));
            float e0 = __expf(acc[fm][0][r] - m), e1 = __expf(acc[fm][1][r] - m);
            float e2 = __expf(acc[fm][2][r] - m), e3 = __expf(acc[fm][3][r] - m);
            float s = e0 + e1 + e2 + e3;
            s += __shfl_xor(s, 1); s += __shfl_xor(s, 2);
            s += __shfl_xor(s, 4); s += __shfl_xor(s, 8);
            float rs = 1.0f / s;
            int row = fm * 16 + r0 + r;
            Pw[row * 64 +  0 + fr] = f2bf(e0 * rs);
            Pw[row * 64 + 16 + fr] = f2bf(e1 * rs);
            Pw[row * 64 + 32 + fr] = f2bf(e2 * rs);
            Pw[row * 64 + 48 + fr] = f2bf(e3 * rs);
        }
    }

    f32x4 acc2[4][4];
    #pragma unroll
    for (int i = 0; i < 4; ++i)
        #pragma unroll
        for (int j = 0; j < 4; ++j) acc2[i][j] = (f32x4){0.f, 0.f, 0.f, 0.f};
    #pragma unroll
    for (int ks = 0; ks < 2; ++ks) {
        bf16x8 a[4], bb[4];
        #pragma unroll
        for (int fm = 0; fm < 4; ++fm)
            a[fm] = *(const bf16x8*)&Pw[(fm * 16 + fr) * 64 + ks * 32 + fk];
        #pragma unroll
        for (int fn = 0; fn < 4; ++fn)
            bb[fn] = *(const bf16x8*)&VT[(fn * 16 + fr) * 64 + ks * 32 + fk];
        #pragma unroll
        for (int fm = 0; fm < 4; ++fm)
            #pragma unroll
            for (int fn = 0; fn < 4; ++fn)
                acc2[fm][fn] = __builtin_amdgcn_mfma_f32_16x16x32_bf16(
                    a[fm], bb[fn], acc2[fm][fn], 0, 0, 0);
    }
    __syncthreads();

    u16* X2 = Qs;
    #pragma unroll
    for (int fm = 0; fm < 4; ++fm)
        #pragma unroll
        for (int fn = 0; fn < 4; ++fn)
            #pragma unroll
            for (int r = 0; r < 4; ++r)
                X2[(w * 64 + fm * 16 + r0 + r) * 64 + fn * 16 + fr] = f2bf(acc2[fm][fn][r]);
    __syncthreads();

    {
        const int d = t >> 2, cq = (t & 3) * 64;
        u16* orow = xsa + ((size_t)b * NN + d * 128 + h * 32 + nc) * 256 + cq;
        #pragma unroll
        for (int i = 0; i < 8; ++i) {
            bf16x8 v;
            #pragma unroll
            for (int j = 0; j < 8; ++j) v[j] = (short)X2[(cq + i * 8 + j) * 64 + d];
            *(bf16x8*)&orow[i * 8] = v;
        }
    }
}

// ================= combined output GEMMs =================
// z=0: xsa@Wo1^T + bo1 -> cols 0..127 ; z=1: xb@W2eff[b]^T + bo2 -> cols 128..255
__global__ __launch_bounds__(256) void outgemm(
    const u16* __restrict__ xsa, const u16* __restrict__ xb,
    const float* __restrict__ Wo1, const float* __restrict__ W2eff,
    const float* __restrict__ bo1, const float* __restrict__ bo2,
    float* __restrict__ out)
{
    __shared__ u16 As[4096];
    __shared__ u16 Bs[4096];
    const int z = blockIdx.z;
    const u16* A = z ? xb : xsa;
    const float* Bt = z ? (W2eff + (size_t)(blockIdx.x >> 6) * 128 * 256) : Wo1;
    const float* bias = z ? bo2 : bo1;
    const int outoff = z ? 128 : 0;
    const int t = threadIdx.x, lane = t & 63, w = t >> 6;
    const int wr = w >> 1, wc = w & 1;
    const int fr = lane & 15, fk = (lane >> 4) * 8, r0 = (lane >> 4) * 4;
    const int m0 = blockIdx.x * 128;

    f32x4 acc[4][4];
    #pragma unroll
    for (int i = 0; i < 4; ++i)
        #pragma unroll
        for (int j = 0; j < 4; ++j) acc[i][j] = (f32x4){0.f, 0.f, 0.f, 0.f};

    for (int kt = 0; kt < 8; ++kt) {
        const int k0 = kt * 32;
        #pragma unroll
        for (int i = 0; i < 2; ++i) {
            int c = i * 256 + t, row = c >> 2, k8 = (c & 3) * 8;
            *(bf16x8*)&As[c * 8] =
                *(const bf16x8*)(A + (size_t)(m0 + row) * 256 + k0 + k8);
            const float* pb = Bt + (size_t)row * 256 + k0 + k8;   // 128 B-rows
            float4v g0 = *(const float4v*)pb, g1 = *(const float4v*)(pb + 4);
            bf16x8 vb;
            #pragma unroll
            for (int j = 0; j < 4; ++j) {
                vb[j] = (short)f2bf(g0[j]); vb[4 + j] = (short)f2bf(g1[j]);
            }
            *(bf16x8*)&Bs[c * 8] = vb;
        }
        __syncthreads();
        bf16x8 a[4], b[4];
        #pragma unroll
        for (int fm = 0; fm < 4; ++fm)
            a[fm] = *(const bf16x8*)&As[(wr * 64 + fm * 16 + fr) * 32 + fk];
        #pragma unroll
        for (int fn = 0; fn < 4; ++fn)
            b[fn] = *(const bf16x8*)&Bs[(wc * 64 + fn * 16 + fr) * 32 + fk];
        #pragma unroll
        for (int fm = 0; fm < 4; ++fm)
            #pragma unroll
            for (int fn = 0; fn < 4; ++fn)
                acc[fm][fn] = __builtin_amdgcn_mfma_f32_16x16x32_bf16(
                    a[fm], b[fn], acc[fm][fn], 0, 0, 0);
        __syncthreads();
    }

    #pragma unroll
    for (int fm = 0; fm < 4; ++fm)
        #pragma unroll
        for (int fn = 0; fn < 4; ++fn) {
            int gcol = wc * 64 + fn * 16 + fr;   // 0..127
            #pragma unroll
            for (int r = 0; r < 4; ++r) {
                size_t grow = (size_t)(m0 + wr * 64 + fm * 16 + r0 + r);
                out[grow * 256 + outoff + gcol] = acc[fm][fn][r] + bias[gcol];
            }
        }
}

extern "C" void kernel_launch(void* const* d_in, const int* in_sizes, int n_in,
                              void* d_out, int out_size, void* d_ws, size_t ws_size,
                              hipStream_t stream) {
    float* out = (float*)d_out;

    static const int expect[14] = {8388608, 8388608, 65536, 65536, 65536, 65536,
                                   524288, 64, 4, 4, 32768, 128, 32768, 128};
    bool ok = (n_in == 14) && (out_size == 8388608);
    if (ok) for (int i = 0; i < 14; ++i) ok = ok && (in_sizes[i] == expect[i]);
    if (!ok) {
        fill_kernel<<<dim3(8192), 256, 0, stream>>>(out, 3000.0f);
        return;
    }
    // R1's 169MB-ws build ran bit-identically => ws >= 169MB; fill poison shows 256MB.
    if (ws_size < 70000000u) {
        fill_kernel<<<dim3(8192), 256, 0, stream>>>(out, 1000.0f);
        return;
    }

    const float* x    = (const float*)d_in[0];
    const float* q    = (const float*)d_in[1];
    const float* Wq   = (const float*)d_in[2];
    const float* Wk   = (const float*)d_in[3];
    const float* Wvca = (const float*)d_in[4];
    const float* Wvsa = (const float*)d_in[5];
    const float* Ew   = (const float*)d_in[6];
    const float* Eb   = (const float*)d_in[7];
    const float* temp = (const float*)d_in[8];
    const float* temp2= (const float*)d_in[9];
    const float* Wo1  = (const float*)d_in[10];
    const float* bo1  = (const float*)d_in[11];
    const float* Wo2  = (const float*)d_in[12];
    const float* bo2  = (const float*)d_in[13];

    u16* Qb = (u16*)d_ws;
    u16* Kb = Qb + (size_t)BNC;          // reused as xsa after calog (stream-ordered)
    u16* qb = Kb + (size_t)BNC;
    u16* xb = qb + (size_t)BNC;
    u16* xsa = Kb;
    float* fs    = (float*)(xb + (size_t)BNC);
    float* nq2   = fs;                   // 1024
    float* nk2   = nq2 + 1024;           // 1024
    float* xE    = nk2 + 1024;           // 65536
    float* kp    = xE + 65536;           // cpart region 0
    float* vp    = kp + 65536;           // cpart region 1
    float* caprob= vp + 2 * 65536 + 65536;  // cpart region 3
    float* W2eff = vp + 5 * 65536;       // cpart regions 6,7
    float* cpart = kp;                   // 8 x 65536 partials

    zero_kernel<<<dim3(264), 256, 0, stream>>>(nq2, 67584);   // nq2, nk2, xE
    conv_kernel<<<dim3(4096, 2), 256, 0, stream>>>(q, x, qb, xb);
    gemm_qkf<<<dim3(256, 2, 2), 256, 0, stream>>>(qb, xb, Wq, Wk, Qb, Kb, nq2, nk2);
    xe_mfma<<<dim3(16, 8), 256, 0, stream>>>(xb, Ew, xE);
    calog_part<<<dim3(16, 8), 256, 0, stream>>>(Qb, Kb, cpart);
    casoftmax_kernel<<<dim3(1024), 64, 0, stream>>>(cpart, nq2, nk2, temp, caprob);
    kvproj_kernel<<<dim3(1024, 2), 64, 0, stream>>>(Wk, Wvsa, xE, Eb, kp, vp);
    mw2eff_kernel<<<dim3(512), 256, 0, stream>>>(caprob, Wo2, Wvca, W2eff);
    sa_mfma<<<dim3(32, 16), 256, 0, stream>>>(Qb, kp, vp, nq2, temp2, xsa);
    outgemm<<<dim3(256, 1, 2), 256, 0, stream>>>(xsa, xb, Wo1, W2eff, bo1, bo2, out);
}

// Round 14
// 134.116 us; speedup vs baseline: 28.3273x; 1.0485x over previous
//
#include <hip/hip_runtime.h>
#include <hip/hip_bf16.h>

// Shapes: B=4, N=8192, C=256, H=4, D=64, P=64
#define NN 8192
#define BNC 8388608   // B*N*C

typedef unsigned short u16;
typedef unsigned int u32;
typedef __attribute__((ext_vector_type(8))) short bf16x8;
typedef __attribute__((ext_vector_type(4))) float f32x4;
typedef __attribute__((ext_vector_type(4))) float float4v;

__device__ __forceinline__ float bf2f(u16 u) {
    union { u32 i; float f; } c; c.i = ((u32)u) << 16; return c.f;
}
__device__ __forceinline__ u16 f2bf(float f) {
    union { float f; u32 i; } c; c.f = f;
    u32 x = c.i;
    u32 r = (x + 0x7fffu + ((x >> 16) & 1u)) >> 16;  // RNE
    return (u16)r;
}
// async global -> LDS, 16 bytes per lane (m97 pattern)
__device__ __forceinline__ void gl16(const u16* g, u16* l) {
    __builtin_amdgcn_global_load_lds(
        (const __attribute__((address_space(1))) void*)g,
        (__attribute__((address_space(3))) void*)l, 16, 0, 0);
}

// ---------------- diagnostic fill ----------------
__global__ void fill_kernel(float* __restrict__ out, float val) {
    int base = (blockIdx.x * 256 + threadIdx.x) * 4;
    #pragma unroll
    for (int i = 0; i < 4; ++i) out[base + i] = val;
}

// ---------------- zero ----------------
__global__ void zero_kernel(float* __restrict__ p, int n) {
    int i = blockIdx.x * 256 + threadIdx.x;
    if (i < n) p[i] = 0.f;
}

// ---------------- bulk fp32 -> bf16: q, x, Wq, Wk, Wo1, Ew ----------------
// 8528 blocks x 256 thr x 8 elements = 17,465,344 elements exactly.
__global__ void convall_kernel(const float* __restrict__ q, const float* __restrict__ x,
                               const float* __restrict__ Wq, const float* __restrict__ Wk,
                               const float* __restrict__ Wo1, const float* __restrict__ Ew,
                               u16* __restrict__ qb, u16* __restrict__ xb,
                               u16* __restrict__ Wqb, u16* __restrict__ Wkb,
                               u16* __restrict__ Wo1b, u16* __restrict__ Ewb) {
    size_t e = ((size_t)blockIdx.x * 256 + threadIdx.x) * 8;
    const float* src; u16* dst;
    if (e < 8388608)       { src = q   + e;              dst = qb   + e; }
    else if (e < 16777216) { src = x   + (e - 8388608);  dst = xb   + (e - 8388608); }
    else if (e < 16842752) { src = Wq  + (e - 16777216); dst = Wqb  + (e - 16777216); }
    else if (e < 16908288) { src = Wk  + (e - 16842752); dst = Wkb  + (e - 16842752); }
    else if (e < 16941056) { src = Wo1 + (e - 16908288); dst = Wo1b + (e - 16908288); }
    else                   { src = Ew  + (e - 16941056); dst = Ewb  + (e - 16941056); }
    float4v f0 = *(const float4v*)src, f1 = *(const float4v*)(src + 4);
    bf16x8 v;
    #pragma unroll
    for (int j = 0; j < 4; ++j) {
        v[j] = (short)f2bf(f0[j]); v[4 + j] = (short)f2bf(f1[j]);
    }
    *(bf16x8*)dst = v;
}

// ================= fused Q/K GEMM (all-bf16, global_load_lds) + sq-norm epilogue =================
// z=0: qb@Wqb^T->Qb (+nq2) ; z=1: xb@Wkb^T->Kb (+nk2)
__global__ __launch_bounds__(256) void gemm_qkf(
    const u16* __restrict__ qb, const u16* __restrict__ xb,
    const u16* __restrict__ Wqb, const u16* __restrict__ Wkb,
    u16* __restrict__ Qb, u16* __restrict__ Kb,
    float* __restrict__ nq2, float* __restrict__ nk2)
{
    __shared__ u16 As[4096];   // [128][32] bf16 linear
    __shared__ u16 Bs[4096];
    const int z = blockIdx.z;
    const u16* A = z ? xb : qb;
    const u16* Bt = z ? Wkb : Wqb;
    u16* O = z ? Kb : Qb;
    float* dstn = z ? nk2 : nq2;
    const int t = threadIdx.x, lane = t & 63, w = t >> 6;
    const int wr = w >> 1, wc = w & 1;
    const int fr = lane & 15, fk = (lane >> 4) * 8, r0 = (lane >> 4) * 4;
    const int m0 = blockIdx.x * 128, n0 = blockIdx.y * 128;
    const int b = m0 >> 13;
    const int row0 = t >> 2, k80 = (t & 3) * 8;          // slot for i=0
    const int row1 = (256 + t) >> 2, k81 = ((256 + t) & 3) * 8;

    f32x4 acc[4][4];
    #pragma unroll
    for (int i = 0; i < 4; ++i)
        #pragma unroll
        for (int j = 0; j < 4; ++j) acc[i][j] = (f32x4){0.f, 0.f, 0.f, 0.f};

    for (int kt = 0; kt < 8; ++kt) {
        const int k0 = kt * 32;
        gl16(A  + (size_t)(m0 + row0) * 256 + k0 + k80, &As[t * 8]);
        gl16(A  + (size_t)(m0 + row1) * 256 + k0 + k81, &As[(256 + t) * 8]);
        gl16(Bt + (size_t)(n0 + row0) * 256 + k0 + k80, &Bs[t * 8]);
        gl16(Bt + (size_t)(n0 + row1) * 256 + k0 + k81, &Bs[(256 + t) * 8]);
        __syncthreads();
        bf16x8 a[4], b[4];
        #pragma unroll
        for (int fm = 0; fm < 4; ++fm)
            a[fm] = *(const bf16x8*)&As[(wr * 64 + fm * 16 + fr) * 32 + fk];
        #pragma unroll
        for (int fn = 0; fn < 4; ++fn)
            b[fn] = *(const bf16x8*)&Bs[(wc * 64 + fn * 16 + fr) * 32 + fk];
        #pragma unroll
        for (int fm = 0; fm < 4; ++fm)
            #pragma unroll
            for (int fn = 0; fn < 4; ++fn)
                acc[fm][fn] = __builtin_amdgcn_mfma_f32_16x16x32_bf16(
                    a[fm], b[fn], acc[fm][fn], 0, 0, 0);
        __syncthreads();
    }

    #pragma unroll
    for (int fn = 0; fn < 4; ++fn) {
        int gcol = n0 + wc * 64 + fn * 16 + fr;
        float s = 0.f;
        #pragma unroll
        for (int fm = 0; fm < 4; ++fm) {
            #pragma unroll
            for (int r = 0; r < 4; ++r) {
                size_t grow = (size_t)(m0 + wr * 64 + fm * 16 + r0 + r);
                float v = acc[fm][fn][r];
                O[grow * 256 + gcol] = f2bf(v);
                s += v * v;
            }
        }
        s += __shfl_xor(s, 16);
        s += __shfl_xor(s, 32);
        if (lane < 16) atomicAdd(&dstn[b * 256 + gcol], s);
    }
}

// ================= xE via MFMA (bf16 xb + Ewb, swizzled staging) =================
__global__ __launch_bounds__(256) void xe_mfma(
    const u16* __restrict__ xb, const u16* __restrict__ Ewb, float* __restrict__ xE)
{
    __shared__ u16 xsT[64][136];   // [k-local][tok], swizzled
    __shared__ u16 ewB[64][136];   // [p][tok]
    const int bkq = blockIdx.x, b = bkq >> 2, kq = bkq & 3, nc = blockIdx.y;
    const int t = threadIdx.x, lane = t & 63, w = t >> 6;
    const int fr = lane & 15, fk = (lane >> 4) * 8, r0 = (lane >> 4) * 4;

    f32x4 acc[4][4];
    #pragma unroll
    for (int i = 0; i < 4; ++i)
        #pragma unroll
        for (int j = 0; j < 4; ++j) acc[i][j] = (f32x4){0.f, 0.f, 0.f, 0.f};

    for (int it = 0; it < 8; ++it) {
        const int n0 = nc * 1024 + it * 128;
        #pragma unroll
        for (int i = 0; i < 4; ++i) {
            int c = i * 256 + t, tok = c >> 3, kl = (c & 7) * 8;
            const int sw = tok ^ ((kl >> 3) << 3);
            bf16x8 v = *(const bf16x8*)(xb + ((size_t)b * NN + n0 + tok) * 256 + kq * 64 + kl);
            #pragma unroll
            for (int j = 0; j < 8; ++j) xsT[kl + j][sw] = (u16)v[j];
        }
        #pragma unroll
        for (int i = 0; i < 4; ++i) {
            int c = i * 256 + t, p = c >> 4, tk8 = (c & 15) * 8;
            *(bf16x8*)&ewB[p][tk8] = *(const bf16x8*)(Ewb + (size_t)p * NN + n0 + tk8);
        }
        __syncthreads();
        bf16x8 a[4], bb[4];
        #pragma unroll
        for (int fm = 0; fm < 4; ++fm) {
            int row = fm * 16 + fr;
            a[fm] = *(const bf16x8*)&xsT[row][(w * 32 + fk) ^ (((row >> 3) & 7) << 3)];
        }
        #pragma unroll
        for (int fn = 0; fn < 4; ++fn)
            bb[fn] = *(const bf16x8*)&ewB[fn * 16 + fr][w * 32 + fk];
        #pragma unroll
        for (int fm = 0; fm < 4; ++fm)
            #pragma unroll
            for (int fn = 0; fn < 4; ++fn)
                acc[fm][fn] = __builtin_amdgcn_mfma_f32_16x16x32_bf16(
                    a[fm], bb[fn], acc[fm][fn], 0, 0, 0);
        __syncthreads();
    }

    float* Cred = (float*)&xsT[0][0];
    for (int ph = 0; ph < 4; ++ph) {
        if (w == ph) {
            #pragma unroll
            for (int fm = 0; fm < 4; ++fm)
                #pragma unroll
                for (int fn = 0; fn < 4; ++fn)
                    #pragma unroll
                    for (int r = 0; r < 4; ++r) {
                        int idx = (fm * 16 + r0 + r) * 64 + fn * 16 + fr;
                        if (ph == 0) Cred[idx] = acc[fm][fn][r];
                        else         Cred[idx] += acc[fm][fn][r];
                    }
        }
        __syncthreads();
    }
    float* dst = xE + (size_t)(b * 256 + kq * 64) * 64;
    #pragma unroll
    for (int i = 0; i < 16; ++i) atomicAdd(&dst[i * 256 + t], Cred[i * 256 + t]);
}

// ================= calog via MFMA, deterministic split-N=8, swizzled =================
__global__ __launch_bounds__(256) void calog_part(
    const u16* __restrict__ Qb, const u16* __restrict__ Kb, float* __restrict__ part)
{
    __shared__ u16 QsT[64][136];
    __shared__ u16 KsT[64][136];
    const int bh = blockIdx.x, b = bh >> 2, h = bh & 3, nc = blockIdx.y;
    const int t = threadIdx.x, lane = t & 63, w = t >> 6;
    const int fr = lane & 15, fk = (lane >> 4) * 8, r0 = (lane >> 4) * 4;

    f32x4 acc[4][4];
    #pragma unroll
    for (int i = 0; i < 4; ++i)
        #pragma unroll
        for (int j = 0; j < 4; ++j) acc[i][j] = (f32x4){0.f, 0.f, 0.f, 0.f};

    for (int it = 0; it < 8; ++it) {
        const int n0 = nc * 1024 + it * 128;
        #pragma unroll
        for (int i = 0; i < 4; ++i) {
            int c = i * 256 + t, tok = c >> 3, ch8 = (c & 7) * 8;
            const int sw = tok ^ ((ch8 >> 3) << 3);
            size_t g = ((size_t)b * NN + n0 + tok) * 256 + h * 64 + ch8;
            bf16x8 vq = *(const bf16x8*)(Qb + g);
            bf16x8 vk = *(const bf16x8*)(Kb + g);
            #pragma unroll
            for (int j = 0; j < 8; ++j) {
                QsT[ch8 + j][sw] = (u16)vq[j];
                KsT[ch8 + j][sw] = (u16)vk[j];
            }
        }
        __syncthreads();
        bf16x8 a[4], bb[4];
        #pragma unroll
        for (int fm = 0; fm < 4; ++fm) {
            int row = fm * 16 + fr;
            a[fm] = *(const bf16x8*)&QsT[row][(w * 32 + fk) ^ (((row >> 3) & 7) << 3)];
        }
        #pragma unroll
        for (int fn = 0; fn < 4; ++fn) {
            int row = fn * 16 + fr;
            bb[fn] = *(const bf16x8*)&KsT[row][(w * 32 + fk) ^ (((row >> 3) & 7) << 3)];
        }
        #pragma unroll
        for (int fm = 0; fm < 4; ++fm)
            #pragma unroll
            for (int fn = 0; fn < 4; ++fn)
                acc[fm][fn] = __builtin_amdgcn_mfma_f32_16x16x32_bf16(
                    a[fm], bb[fn], acc[fm][fn], 0, 0, 0);
        __syncthreads();
    }

    float* Cred = (float*)&QsT[0][0];
    for (int ph = 0; ph < 4; ++ph) {
        if (w == ph) {
            #pragma unroll
            for (int fm = 0; fm < 4; ++fm)
                #pragma unroll
                for (int fn = 0; fn < 4; ++fn)
                    #pragma unroll
                    for (int r = 0; r < 4; ++r) {
                        int idx = (fm * 16 + r0 + r) * 64 + fn * 16 + fr;
                        if (ph == 0) Cred[idx] = acc[fm][fn][r];
                        else         Cred[idx] += acc[fm][fn][r];
                    }
        }
        __syncthreads();
    }
    float* dst = part + (size_t)nc * 65536 + (size_t)bh * 4096;
    #pragma unroll
    for (int i = 0; i < 16; ++i) dst[i * 256 + t] = Cred[i * 256 + t];
}

// ---------------- casoftmax fused with 8-part reduce ----------------
__global__ void casoftmax_kernel(const float* __restrict__ part, const float* __restrict__ nq2,
                                 const float* __restrict__ nk2, const float* __restrict__ temp,
                                 float* __restrict__ caprob) {
    const int row = blockIdx.x;
    const int b = row >> 8, c = row & 255, h = c >> 6;
    const int e = threadIdx.x;
    const int i = row * 64 + e;
    float lg = part[i];
    #pragma unroll
    for (int nc = 1; nc < 8; ++nc) lg += part[(size_t)nc * 65536 + i];
    float nq = fmaxf(sqrtf(nq2[row]), 1e-12f);
    float nk = fmaxf(sqrtf(nk2[b * 256 + h * 64 + e]), 1e-12f);
    float v = lg / (nq * nk) * temp[h];
    __shared__ float red[64];
    red[e] = v; __syncthreads();
    for (int s = 32; s; s >>= 1) { if (e < s) red[e] = fmaxf(red[e], red[e + s]); __syncthreads(); }
    float m = red[0]; __syncthreads();
    float ex = __expf(v - m);
    red[e] = ex; __syncthreads();
    for (int s = 32; s; s >>= 1) { if (e < s) red[e] += red[e + s]; __syncthreads(); }
    caprob[i] = ex / red[0];
}

// ---------------- kp/vp (kept) ----------------
__global__ void kvproj_kernel(const float* __restrict__ Wk, const float* __restrict__ Wvsa,
                              const float* __restrict__ xE, const float* __restrict__ Eb,
                              float* __restrict__ kp, float* __restrict__ vp) {
    const int b = blockIdx.x >> 8, c = blockIdx.x & 255, z = blockIdx.y, p = threadIdx.x;
    const float* W = z ? Wvsa : Wk;
    float* dst = z ? vp : kp;
    float s = 0.f;
    for (int k = 0; k < 256; ++k)
        s += W[c * 256 + k] * xE[(size_t)(b * 256 + k) * 64 + p];
    dst[(size_t)(b * 256 + c) * 64 + p] = s + Eb[p];
}

// ---------------- fused buildm + w2eff (bf16 out) ----------------
__global__ void mw2eff_kernel(const float* __restrict__ caprob, const float* __restrict__ Wo2,
                              const float* __restrict__ Wvca, u16* __restrict__ W2effb) {
    __shared__ float Ml[256];
    const int b = blockIdx.x >> 7, j = blockIdx.x & 127;
    const int t = threadIdx.x, h = t >> 6, e = t & 63;
    float s = 0.f;
    #pragma unroll 8
    for (int d = 0; d < 64; ++d)
        s += Wo2[j * 256 + h * 64 + d] * caprob[(size_t)(b * 256 + h * 64 + d) * 64 + e];
    Ml[t] = s;
    __syncthreads();
    float s2 = 0.f;
    for (int c = 0; c < 256; ++c) s2 += Ml[c] * Wvca[c * 256 + t];
    W2effb[(size_t)blockIdx.x * 256 + t] = f2bf(s2);
}

// ================= MFMA spatial attention (kept) =================
__global__ __launch_bounds__(256) void sa_mfma(
    const u16* __restrict__ Qb, const float* __restrict__ kp,
    const float* __restrict__ vp, const float* __restrict__ nq2,
    const float* __restrict__ temp2, u16* __restrict__ xsa)
{
    __shared__ char smem[49152];
    u16* Qs = (u16*)smem;
    u16* KT = (u16*)(smem + 32768);
    u16* VT = (u16*)(smem + 40960);
    const int nc = blockIdx.x, bh = blockIdx.y, b = bh >> 2, h = bh & 3;
    const int t = threadIdx.x, lane = t & 63, w = t >> 6;
    const int fr = lane & 15, fk = (lane >> 4) * 8, r0 = (lane >> 4) * 4;

    #pragma unroll
    for (int i = 0; i < 8; ++i) {
        int c = i * 256 + t, tok = c >> 3, ch8 = (c & 7) * 8;
        *(bf16x8*)&Qs[c * 8] =
            *(const bf16x8*)(Qb + ((size_t)b * NN + nc * 256 + tok) * 256 + h * 64 + ch8);
    }
    {
        const int d = t >> 2, p0 = (t & 3) * 16;
        const float rqv = 1.0f / fmaxf(sqrtf(nq2[b * 256 + h * 64 + d]), 1e-12f);
        const float t2 = temp2[h];
        const float* kr = kp + (size_t)(b * 256 + h * 64 + d) * 64 + p0;
        #pragma unroll
        for (int j = 0; j < 16; ++j)
            KT[(p0 + j) * 64 + d] = f2bf(kr[j] * rqv * t2);
    }
    {
        const float* vs = vp + (size_t)(b * 256 + h * 64) * 64;
        #pragma unroll
        for (int i = 0; i < 2; ++i) {
            int c = i * 256 + t;
            bf16x8 v;
            #pragma unroll
            for (int j = 0; j < 8; ++j) v[j] = (short)f2bf(vs[c * 8 + j]);
            *(bf16x8*)&VT[c * 8] = v;
        }
    }
    __syncthreads();

    f32x4 acc[4][4];
    #pragma unroll
    for (int i = 0; i < 4; ++i)
        #pragma unroll
        for (int j = 0; j < 4; ++j) acc[i][j] = (f32x4){0.f, 0.f, 0.f, 0.f};
    #pragma unroll
    for (int ks = 0; ks < 2; ++ks) {
        bf16x8 a[4], bb[4];
        #pragma unroll
        for (int fm = 0; fm < 4; ++fm)
            a[fm] = *(const bf16x8*)&Qs[(w * 64 + fm * 16 + fr) * 64 + ks * 32 + fk];
        #pragma unroll
        for (int fn = 0; fn < 4; ++fn)
            bb[fn] = *(const bf16x8*)&KT[(fn * 16 + fr) * 64 + ks * 32 + fk];
        #pragma unroll
        for (int fm = 0; fm < 4; ++fm)
            #pragma unroll
            for (int fn = 0; fn < 4; ++fn)
                acc[fm][fn] = __builtin_amdgcn_mfma_f32_16x16x32_bf16(
                    a[fm], bb[fn], acc[fm][fn], 0, 0, 0);
    }
    __syncthreads();

    u16* Pw = Qs + w * 4096;
    #pragma unroll
    for (int fm = 0; fm < 4; ++fm) {
        #pragma unroll
        for (int r = 0; r < 4; ++r) {
            float m = fmaxf(fmaxf(acc[fm][0][r], acc[fm][1][r]),
                            fmaxf(acc[fm][2][r], acc[fm][3][r]));
            m = fmaxf(m, __shfl_xor(m, 1));
            m = fmaxf(m, __shfl_xor(m, 2));
            m = fmaxf(m, __shfl_xor(m, 4));
            m = fmaxf(m, __shfl_xor(m, 8));
            float e0 = __expf(acc[fm][0][r] - m), e1 = __expf(acc[fm][1][r] - m);
            float e2 = __expf(acc[fm][2][r] - m), e3 = __expf(acc[fm][3][r] - m);
            float s = e0 + e1 + e2 + e3;
            s += __shfl_xor(s, 1); s += __shfl_xor(s, 2);
            s += __shfl_xor(s, 4); s += __shfl_xor(s, 8);
            float rs = 1.0f / s;
            int row = fm * 16 + r0 + r;
            Pw[row * 64 +  0 + fr] = f2bf(e0 * rs);
            Pw[row * 64 + 16 + fr] = f2bf(e1 * rs);
            Pw[row * 64 + 32 + fr] = f2bf(e2 * rs);
            Pw[row * 64 + 48 + fr] = f2bf(e3 * rs);
        }
    }

    f32x4 acc2[4][4];
    #pragma unroll
    for (int i = 0; i < 4; ++i)
        #pragma unroll
        for (int j = 0; j < 4; ++j) acc2[i][j] = (f32x4){0.f, 0.f, 0.f, 0.f};
    #pragma unroll
    for (int ks = 0; ks < 2; ++ks) {
        bf16x8 a[4], bb[4];
        #pragma unroll
        for (int fm = 0; fm < 4; ++fm)
            a[fm] = *(const bf16x8*)&Pw[(fm * 16 + fr) * 64 + ks * 32 + fk];
        #pragma unroll
        for (int fn = 0; fn < 4; ++fn)
            bb[fn] = *(const bf16x8*)&VT[(fn * 16 + fr) * 64 + ks * 32 + fk];
        #pragma unroll
        for (int fm = 0; fm < 4; ++fm)
            #pragma unroll
            for (int fn = 0; fn < 4; ++fn)
                acc2[fm][fn] = __builtin_amdgcn_mfma_f32_16x16x32_bf16(
                    a[fm], bb[fn], acc2[fm][fn], 0, 0, 0);
    }
    __syncthreads();

    u16* X2 = Qs;
    #pragma unroll
    for (int fm = 0; fm < 4; ++fm)
        #pragma unroll
        for (int fn = 0; fn < 4; ++fn)
            #pragma unroll
            for (int r = 0; r < 4; ++r)
                X2[(w * 64 + fm * 16 + r0 + r) * 64 + fn * 16 + fr] = f2bf(acc2[fm][fn][r]);
    __syncthreads();

    {
        const int d = t >> 2, cq = (t & 3) * 64;
        u16* orow = xsa + ((size_t)b * NN + d * 128 + h * 32 + nc) * 256 + cq;
        #pragma unroll
        for (int i = 0; i < 8; ++i) {
            bf16x8 v;
            #pragma unroll
            for (int j = 0; j < 8; ++j) v[j] = (short)X2[(cq + i * 8 + j) * 64 + d];
            *(bf16x8*)&orow[i * 8] = v;
        }
    }
}

// ================= combined output GEMMs (all-bf16, global_load_lds) =================
// z=0: xsa@Wo1b^T + bo1 -> cols 0..127 ; z=1: xb@W2effb[b]^T + bo2 -> cols 128..255
__global__ __launch_bounds__(256) void outgemm(
    const u16* __restrict__ xsa, const u16* __restrict__ xb,
    const u16* __restrict__ Wo1b, const u16* __restrict__ W2effb,
    const float* __restrict__ bo1, const float* __restrict__ bo2,
    float* __restrict__ out)
{
    __shared__ u16 As[4096];
    __shared__ u16 Bs[4096];
    const int z = blockIdx.z;
    const u16* A = z ? xb : xsa;
    const u16* Bt = z ? (W2effb + (size_t)(blockIdx.x >> 6) * 128 * 256) : Wo1b;
    const float* bias = z ? bo2 : bo1;
    const int outoff = z ? 128 : 0;
    const int t = threadIdx.x, lane = t & 63, w = t >> 6;
    const int wr = w >> 1, wc = w & 1;
    const int fr = lane & 15, fk = (lane >> 4) * 8, r0 = (lane >> 4) * 4;
    const int m0 = blockIdx.x * 128;
    const int row0 = t >> 2, k80 = (t & 3) * 8;
    const int row1 = (256 + t) >> 2, k81 = ((256 + t) & 3) * 8;

    f32x4 acc[4][4];
    #pragma unroll
    for (int i = 0; i < 4; ++i)
        #pragma unroll
        for (int j = 0; j < 4; ++j) acc[i][j] = (f32x4){0.f, 0.f, 0.f, 0.f};

    for (int kt = 0; kt < 8; ++kt) {
        const int k0 = kt * 32;
        gl16(A  + (size_t)(m0 + row0) * 256 + k0 + k80, &As[t * 8]);
        gl16(A  + (size_t)(m0 + row1) * 256 + k0 + k81, &As[(256 + t) * 8]);
        gl16(Bt + (size_t)row0 * 256 + k0 + k80, &Bs[t * 8]);
        gl16(Bt + (size_t)row1 * 256 + k0 + k81, &Bs[(256 + t) * 8]);
        __syncthreads();
        bf16x8 a[4], b[4];
        #pragma unroll
        for (int fm = 0; fm < 4; ++fm)
            a[fm] = *(const bf16x8*)&As[(wr * 64 + fm * 16 + fr) * 32 + fk];
        #pragma unroll
        for (int fn = 0; fn < 4; ++fn)
            b[fn] = *(const bf16x8*)&Bs[(wc * 64 + fn * 16 + fr) * 32 + fk];
        #pragma unroll
        for (int fm = 0; fm < 4; ++fm)
            #pragma unroll
            for (int fn = 0; fn < 4; ++fn)
                acc[fm][fn] = __builtin_amdgcn_mfma_f32_16x16x32_bf16(
                    a[fm], b[fn], acc[fm][fn], 0, 0, 0);
        __syncthreads();
    }

    #pragma unroll
    for (int fm = 0; fm < 4; ++fm)
        #pragma unroll
        for (int fn = 0; fn < 4; ++fn) {
            int gcol = wc * 64 + fn * 16 + fr;   // 0..127
            #pragma unroll
            for (int r = 0; r < 4; ++r) {
                size_t grow = (size_t)(m0 + wr * 64 + fm * 16 + r0 + r);
                out[grow * 256 + outoff + gcol] = acc[fm][fn][r] + bias[gcol];
            }
        }
}

extern "C" void kernel_launch(void* const* d_in, const int* in_sizes, int n_in,
                              void* d_out, int out_size, void* d_ws, size_t ws_size,
                              hipStream_t stream) {
    float* out = (float*)d_out;

    static const int expect[14] = {8388608, 8388608, 65536, 65536, 65536, 65536,
                                   524288, 64, 4, 4, 32768, 128, 32768, 128};
    bool ok = (n_in == 14) && (out_size == 8388608);
    if (ok) for (int i = 0; i < 14; ++i) ok = ok && (in_sizes[i] == expect[i]);
    if (!ok) {
        fill_kernel<<<dim3(8192), 256, 0, stream>>>(out, 3000.0f);
        return;
    }
    // Poison fill shows ws ~= 256 MB; R1's 169MB layout ran correctly.
    if (ws_size < 80000000u) {
        fill_kernel<<<dim3(8192), 256, 0, stream>>>(out, 1000.0f);
        return;
    }

    const float* x    = (const float*)d_in[0];
    const float* q    = (const float*)d_in[1];
    const float* Wq   = (const float*)d_in[2];
    const float* Wk   = (const float*)d_in[3];
    const float* Wvca = (const float*)d_in[4];
    const float* Wvsa = (const float*)d_in[5];
    const float* Ew   = (const float*)d_in[6];
    const float* Eb   = (const float*)d_in[7];
    const float* temp = (const float*)d_in[8];
    const float* temp2= (const float*)d_in[9];
    const float* Wo1  = (const float*)d_in[10];
    const float* bo1  = (const float*)d_in[11];
    const float* Wo2  = (const float*)d_in[12];
    const float* bo2  = (const float*)d_in[13];

    u16* Qb   = (u16*)d_ws;
    u16* Kb   = Qb + (size_t)BNC;        // reused as xsa after calog (stream-ordered)
    u16* qb   = Kb + (size_t)BNC;
    u16* xb   = qb + (size_t)BNC;
    u16* Wqb  = xb + (size_t)BNC;        // 65536
    u16* Wkb  = Wqb + 65536;             // 65536
    u16* Wo1b = Wkb + 65536;             // 32768
    u16* Ewb  = Wo1b + 32768;            // 524288
    u16* W2effb = Ewb + 524288;          // 131072
    u16* xsa  = Kb;
    float* fs    = (float*)(W2effb + 131072);
    float* nq2   = fs;                   // 1024
    float* nk2   = nq2 + 1024;           // 1024
    float* xE    = nk2 + 1024;           // 65536
    float* kp    = xE + 65536;           // cpart region 0
    float* vp    = kp + 65536;           // cpart region 1
    float* caprob= kp + 3 * 65536;       // cpart region 3
    float* cpart = kp;                   // 8 x 65536 partials

    zero_kernel<<<dim3(264), 256, 0, stream>>>(nq2, 67584);   // nq2, nk2, xE
    convall_kernel<<<dim3(8528), 256, 0, stream>>>(q, x, Wq, Wk, Wo1, Ew,
                                                   qb, xb, Wqb, Wkb, Wo1b, Ewb);
    gemm_qkf<<<dim3(256, 2, 2), 256, 0, stream>>>(qb, xb, Wqb, Wkb, Qb, Kb, nq2, nk2);
    xe_mfma<<<dim3(16, 8), 256, 0, stream>>>(xb, Ewb, xE);
    calog_part<<<dim3(16, 8), 256, 0, stream>>>(Qb, Kb, cpart);
    casoftmax_kernel<<<dim3(1024), 64, 0, stream>>>(cpart, nq2, nk2, temp, caprob);
    kvproj_kernel<<<dim3(1024, 2), 64, 0, stream>>>(Wk, Wvsa, xE, Eb, kp, vp);
    mw2eff_kernel<<<dim3(512), 256, 0, stream>>>(caprob, Wo2, Wvca, W2effb);
    sa_mfma<<<dim3(32, 16), 256, 0, stream>>>(Qb, kp, vp, nq2, temp2, xsa);
    outgemm<<<dim3(256, 1, 2), 256, 0, stream>>>(xsa, xb, Wo1b, W2effb, bo1, bo2, out);
}

// Round 15
// 110.304 us; speedup vs baseline: 34.4427x; 1.2159x over previous
//
#include <hip/hip_runtime.h>
#include <hip/hip_bf16.h>

// Shapes: B=4, N=8192, C=256, H=4, D=64, P=64
#define NN 8192
#define BNC 8388608   // B*N*C

typedef unsigned short u16;
typedef unsigned int u32;
typedef __attribute__((ext_vector_type(8))) short bf16x8;
typedef __attribute__((ext_vector_type(4))) float f32x4;
typedef __attribute__((ext_vector_type(4))) float float4v;

__device__ __forceinline__ float bf2f(u16 u) {
    union { u32 i; float f; } c; c.i = ((u32)u) << 16; return c.f;
}
__device__ __forceinline__ u16 f2bf(float f) {
    union { float f; u32 i; } c; c.f = f;
    u32 x = c.i;
    u32 r = (x + 0x7fffu + ((x >> 16) & 1u)) >> 16;  // RNE
    return (u16)r;
}
// async global -> LDS, 16 bytes per lane (m97 pattern)
__device__ __forceinline__ void gl16(const u16* g, u16* l) {
    __builtin_amdgcn_global_load_lds(
        (const __attribute__((address_space(1))) void*)g,
        (__attribute__((address_space(3))) void*)l, 16, 0, 0);
}

// ---------------- diagnostic fill ----------------
__global__ void fill_kernel(float* __restrict__ out, float val) {
    int base = (blockIdx.x * 256 + threadIdx.x) * 4;
    #pragma unroll
    for (int i = 0; i < 4; ++i) out[base + i] = val;
}

// ================= fused zero + bulk fp32->bf16 conversion =================
// blocks 0..8527: convert q,x,Wq,Wk,Wo1,Ew (17,465,344 elements);
// blocks 8528..8791: zero nq2/nk2/xE (67584 floats).
__global__ void zeroconv_kernel(const float* __restrict__ q, const float* __restrict__ x,
                                const float* __restrict__ Wq, const float* __restrict__ Wk,
                                const float* __restrict__ Wo1, const float* __restrict__ Ew,
                                u16* __restrict__ qb, u16* __restrict__ xb,
                                u16* __restrict__ Wqb, u16* __restrict__ Wkb,
                                u16* __restrict__ Wo1b, u16* __restrict__ Ewb,
                                float* __restrict__ zbase) {
    if (blockIdx.x >= 8528) {
        int i = (blockIdx.x - 8528) * 256 + threadIdx.x;
        if (i < 67584) zbase[i] = 0.f;
        return;
    }
    size_t e = ((size_t)blockIdx.x * 256 + threadIdx.x) * 8;
    const float* src; u16* dst;
    if (e < 8388608)       { src = q   + e;              dst = qb   + e; }
    else if (e < 16777216) { src = x   + (e - 8388608);  dst = xb   + (e - 8388608); }
    else if (e < 16842752) { src = Wq  + (e - 16777216); dst = Wqb  + (e - 16777216); }
    else if (e < 16908288) { src = Wk  + (e - 16842752); dst = Wkb  + (e - 16842752); }
    else if (e < 16941056) { src = Wo1 + (e - 16908288); dst = Wo1b + (e - 16908288); }
    else                   { src = Ew  + (e - 16941056); dst = Ewb  + (e - 16941056); }
    float4v f0 = *(const float4v*)src, f1 = *(const float4v*)(src + 4);
    bf16x8 v;
    #pragma unroll
    for (int j = 0; j < 4; ++j) {
        v[j] = (short)f2bf(f0[j]); v[4 + j] = (short)f2bf(f1[j]);
    }
    *(bf16x8*)dst = v;
}

// ================= fused Q/K GEMM (all-bf16, global_load_lds) + sq-norm epilogue =================
__global__ __launch_bounds__(256) void gemm_qkf(
    const u16* __restrict__ qb, const u16* __restrict__ xb,
    const u16* __restrict__ Wqb, const u16* __restrict__ Wkb,
    u16* __restrict__ Qb, u16* __restrict__ Kb,
    float* __restrict__ nq2, float* __restrict__ nk2)
{
    __shared__ u16 As[4096];   // [128][32] bf16 linear
    __shared__ u16 Bs[4096];
    const int z = blockIdx.z;
    const u16* A = z ? xb : qb;
    const u16* Bt = z ? Wkb : Wqb;
    u16* O = z ? Kb : Qb;
    float* dstn = z ? nk2 : nq2;
    const int t = threadIdx.x, lane = t & 63, w = t >> 6;
    const int wr = w >> 1, wc = w & 1;
    const int fr = lane & 15, fk = (lane >> 4) * 8, r0 = (lane >> 4) * 4;
    const int m0 = blockIdx.x * 128, n0 = blockIdx.y * 128;
    const int b = m0 >> 13;
    const int row0 = t >> 2, k80 = (t & 3) * 8;
    const int row1 = (256 + t) >> 2, k81 = ((256 + t) & 3) * 8;

    f32x4 acc[4][4];
    #pragma unroll
    for (int i = 0; i < 4; ++i)
        #pragma unroll
        for (int j = 0; j < 4; ++j) acc[i][j] = (f32x4){0.f, 0.f, 0.f, 0.f};

    for (int kt = 0; kt < 8; ++kt) {
        const int k0 = kt * 32;
        gl16(A  + (size_t)(m0 + row0) * 256 + k0 + k80, &As[t * 8]);
        gl16(A  + (size_t)(m0 + row1) * 256 + k0 + k81, &As[(256 + t) * 8]);
        gl16(Bt + (size_t)(n0 + row0) * 256 + k0 + k80, &Bs[t * 8]);
        gl16(Bt + (size_t)(n0 + row1) * 256 + k0 + k81, &Bs[(256 + t) * 8]);
        __syncthreads();
        bf16x8 a[4], b[4];
        #pragma unroll
        for (int fm = 0; fm < 4; ++fm)
            a[fm] = *(const bf16x8*)&As[(wr * 64 + fm * 16 + fr) * 32 + fk];
        #pragma unroll
        for (int fn = 0; fn < 4; ++fn)
            b[fn] = *(const bf16x8*)&Bs[(wc * 64 + fn * 16 + fr) * 32 + fk];
        #pragma unroll
        for (int fm = 0; fm < 4; ++fm)
            #pragma unroll
            for (int fn = 0; fn < 4; ++fn)
                acc[fm][fn] = __builtin_amdgcn_mfma_f32_16x16x32_bf16(
                    a[fm], b[fn], acc[fm][fn], 0, 0, 0);
        __syncthreads();
    }

    #pragma unroll
    for (int fn = 0; fn < 4; ++fn) {
        int gcol = n0 + wc * 64 + fn * 16 + fr;
        float s = 0.f;
        #pragma unroll
        for (int fm = 0; fm < 4; ++fm) {
            #pragma unroll
            for (int r = 0; r < 4; ++r) {
                size_t grow = (size_t)(m0 + wr * 64 + fm * 16 + r0 + r);
                float v = acc[fm][fn][r];
                O[grow * 256 + gcol] = f2bf(v);
                s += v * v;
            }
        }
        s += __shfl_xor(s, 16);
        s += __shfl_xor(s, 32);
        if (lane < 16) atomicAdd(&dstn[b * 256 + gcol], s);
    }
}

// ================= fused xE-MFMA + calog-MFMA (independent, co-scheduled) =================
// blocks 0..127: xE (bkq=bx>>3, nc=bx&7); blocks 128..255: calog (bh, nc likewise).
__global__ __launch_bounds__(256) void xecalog_kernel(
    const u16* __restrict__ xb, const u16* __restrict__ Ewb, float* __restrict__ xE,
    const u16* __restrict__ Qb, const u16* __restrict__ Kb, float* __restrict__ cpart)
{
    __shared__ u16 smA[64][136];
    __shared__ u16 smB[64][136];
    const int t = threadIdx.x, lane = t & 63, w = t >> 6;
    const int fr = lane & 15, fk = (lane >> 4) * 8, r0 = (lane >> 4) * 4;

    f32x4 acc[4][4];
    #pragma unroll
    for (int i = 0; i < 4; ++i)
        #pragma unroll
        for (int j = 0; j < 4; ++j) acc[i][j] = (f32x4){0.f, 0.f, 0.f, 0.f};

    if (blockIdx.x < 128) {
        const int bkq = blockIdx.x >> 3, nc = blockIdx.x & 7;
        const int b = bkq >> 2, kq = bkq & 3;
        for (int it = 0; it < 8; ++it) {
            const int n0 = nc * 1024 + it * 128;
            #pragma unroll
            for (int i = 0; i < 4; ++i) {
                int c = i * 256 + t, tok = c >> 3, kl = (c & 7) * 8;
                const int sw = tok ^ ((kl >> 3) << 3);
                bf16x8 v = *(const bf16x8*)(xb + ((size_t)b * NN + n0 + tok) * 256 + kq * 64 + kl);
                #pragma unroll
                for (int j = 0; j < 8; ++j) smA[kl + j][sw] = (u16)v[j];
            }
            #pragma unroll
            for (int i = 0; i < 4; ++i) {
                int c = i * 256 + t, p = c >> 4, tk8 = (c & 15) * 8;
                *(bf16x8*)&smB[p][tk8] = *(const bf16x8*)(Ewb + (size_t)p * NN + n0 + tk8);
            }
            __syncthreads();
            bf16x8 a[4], bb[4];
            #pragma unroll
            for (int fm = 0; fm < 4; ++fm) {
                int row = fm * 16 + fr;
                a[fm] = *(const bf16x8*)&smA[row][(w * 32 + fk) ^ (((row >> 3) & 7) << 3)];
            }
            #pragma unroll
            for (int fn = 0; fn < 4; ++fn)
                bb[fn] = *(const bf16x8*)&smB[fn * 16 + fr][w * 32 + fk];
            #pragma unroll
            for (int fm = 0; fm < 4; ++fm)
                #pragma unroll
                for (int fn = 0; fn < 4; ++fn)
                    acc[fm][fn] = __builtin_amdgcn_mfma_f32_16x16x32_bf16(
                        a[fm], bb[fn], acc[fm][fn], 0, 0, 0);
            __syncthreads();
        }
        float* Cred = (float*)&smA[0][0];
        for (int ph = 0; ph < 4; ++ph) {
            if (w == ph) {
                #pragma unroll
                for (int fm = 0; fm < 4; ++fm)
                    #pragma unroll
                    for (int fn = 0; fn < 4; ++fn)
                        #pragma unroll
                        for (int r = 0; r < 4; ++r) {
                            int idx = (fm * 16 + r0 + r) * 64 + fn * 16 + fr;
                            if (ph == 0) Cred[idx] = acc[fm][fn][r];
                            else         Cred[idx] += acc[fm][fn][r];
                        }
            }
            __syncthreads();
        }
        float* dst = xE + (size_t)(b * 256 + kq * 64) * 64;
        #pragma unroll
        for (int i = 0; i < 16; ++i) atomicAdd(&dst[i * 256 + t], Cred[i * 256 + t]);
    } else {
        const int bx = blockIdx.x - 128;
        const int bh = bx >> 3, nc = bx & 7;
        const int b = bh >> 2, h = bh & 3;
        for (int it = 0; it < 8; ++it) {
            const int n0 = nc * 1024 + it * 128;
            #pragma unroll
            for (int i = 0; i < 4; ++i) {
                int c = i * 256 + t, tok = c >> 3, ch8 = (c & 7) * 8;
                const int sw = tok ^ ((ch8 >> 3) << 3);
                size_t g = ((size_t)b * NN + n0 + tok) * 256 + h * 64 + ch8;
                bf16x8 vq = *(const bf16x8*)(Qb + g);
                bf16x8 vk = *(const bf16x8*)(Kb + g);
                #pragma unroll
                for (int j = 0; j < 8; ++j) {
                    smA[ch8 + j][sw] = (u16)vq[j];
                    smB[ch8 + j][sw] = (u16)vk[j];
                }
            }
            __syncthreads();
            bf16x8 a[4], bb[4];
            #pragma unroll
            for (int fm = 0; fm < 4; ++fm) {
                int row = fm * 16 + fr;
                a[fm] = *(const bf16x8*)&smA[row][(w * 32 + fk) ^ (((row >> 3) & 7) << 3)];
            }
            #pragma unroll
            for (int fn = 0; fn < 4; ++fn) {
                int row = fn * 16 + fr;
                bb[fn] = *(const bf16x8*)&smB[row][(w * 32 + fk) ^ (((row >> 3) & 7) << 3)];
            }
            #pragma unroll
            for (int fm = 0; fm < 4; ++fm)
                #pragma unroll
                for (int fn = 0; fn < 4; ++fn)
                    acc[fm][fn] = __builtin_amdgcn_mfma_f32_16x16x32_bf16(
                        a[fm], bb[fn], acc[fm][fn], 0, 0, 0);
            __syncthreads();
        }
        float* Cred = (float*)&smA[0][0];
        for (int ph = 0; ph < 4; ++ph) {
            if (w == ph) {
                #pragma unroll
                for (int fm = 0; fm < 4; ++fm)
                    #pragma unroll
                    for (int fn = 0; fn < 4; ++fn)
                        #pragma unroll
                        for (int r = 0; r < 4; ++r) {
                            int idx = (fm * 16 + r0 + r) * 64 + fn * 16 + fr;
                            if (ph == 0) Cred[idx] = acc[fm][fn][r];
                            else         Cred[idx] += acc[fm][fn][r];
                        }
            }
            __syncthreads();
        }
        float* dst = cpart + (size_t)nc * 65536 + (size_t)bh * 4096;
        #pragma unroll
        for (int i = 0; i < 16; ++i) dst[i * 256 + t] = Cred[i * 256 + t];
    }
}

// ================= fused casoftmax(+8-part reduce) + kvproj (independent) =================
// blocks 0..1023: casoftmax row=bx ; blocks 1024..3071: kvproj idx=bx-1024.
__global__ void smkv_kernel(const float* __restrict__ cpart, const float* __restrict__ nq2,
                            const float* __restrict__ nk2, const float* __restrict__ temp,
                            float* __restrict__ caprob,
                            const float* __restrict__ Wk, const float* __restrict__ Wvsa,
                            const float* __restrict__ xE, const float* __restrict__ Eb,
                            float* __restrict__ kp, float* __restrict__ vp) {
    if (blockIdx.x < 1024) {
        const int row = blockIdx.x;
        const int b = row >> 8, c = row & 255, h = c >> 6;
        const int e = threadIdx.x;
        const int i = row * 64 + e;
        float lg = cpart[i];
        #pragma unroll
        for (int nc = 1; nc < 8; ++nc) lg += cpart[(size_t)nc * 65536 + i];
        float nq = fmaxf(sqrtf(nq2[row]), 1e-12f);
        float nk = fmaxf(sqrtf(nk2[b * 256 + h * 64 + e]), 1e-12f);
        float v = lg / (nq * nk) * temp[h];
        __shared__ float red[64];
        red[e] = v; __syncthreads();
        for (int s = 32; s; s >>= 1) { if (e < s) red[e] = fmaxf(red[e], red[e + s]); __syncthreads(); }
        float m = red[0]; __syncthreads();
        float ex = __expf(v - m);
        red[e] = ex; __syncthreads();
        for (int s = 32; s; s >>= 1) { if (e < s) red[e] += red[e + s]; __syncthreads(); }
        caprob[i] = ex / red[0];
    } else {
        const int idx = blockIdx.x - 1024;
        const int z = idx >> 10, bc = idx & 1023;
        const int b = bc >> 8, c = bc & 255, p = threadIdx.x;
        const float* W = z ? Wvsa : Wk;
        float* dst = z ? vp : kp;
        float s = 0.f;
        for (int k = 0; k < 256; ++k)
            s += W[c * 256 + k] * xE[(size_t)(b * 256 + k) * 64 + p];
        dst[(size_t)(b * 256 + c) * 64 + p] = s + Eb[p];
    }
}

// ================= fused sa_mfma + mw2eff (independent) =================
// blocks 0..511: sa (nc=bx&31, bh=bx>>5); blocks 512..1023: mw2eff (bx-512).
__global__ __launch_bounds__(256) void samw_kernel(
    const u16* __restrict__ Qb, const float* __restrict__ kp,
    const float* __restrict__ vp, const float* __restrict__ nq2,
    const float* __restrict__ temp2, u16* __restrict__ xsa,
    const float* __restrict__ caprob, const float* __restrict__ Wo2,
    const float* __restrict__ Wvca, u16* __restrict__ W2effb)
{
    __shared__ char smem[49152];
    const int t = threadIdx.x;
    if (blockIdx.x >= 512) {
        float* Ml = (float*)smem;
        const int bj = blockIdx.x - 512;
        const int b = bj >> 7, j = bj & 127;
        const int h = t >> 6, e = t & 63;
        float s = 0.f;
        #pragma unroll 8
        for (int d = 0; d < 64; ++d)
            s += Wo2[j * 256 + h * 64 + d] * caprob[(size_t)(b * 256 + h * 64 + d) * 64 + e];
        Ml[t] = s;
        __syncthreads();
        float s2 = 0.f;
        for (int c = 0; c < 256; ++c) s2 += Ml[c] * Wvca[c * 256 + t];
        W2effb[(size_t)bj * 256 + t] = f2bf(s2);
        return;
    }
    u16* Qs = (u16*)smem;
    u16* KT = (u16*)(smem + 32768);
    u16* VT = (u16*)(smem + 40960);
    const int nc = blockIdx.x & 31, bh = blockIdx.x >> 5, b = bh >> 2, h = bh & 3;
    const int lane = t & 63, w = t >> 6;
    const int fr = lane & 15, fk = (lane >> 4) * 8, r0 = (lane >> 4) * 4;

    #pragma unroll
    for (int i = 0; i < 8; ++i) {
        int c = i * 256 + t, tok = c >> 3, ch8 = (c & 7) * 8;
        *(bf16x8*)&Qs[c * 8] =
            *(const bf16x8*)(Qb + ((size_t)b * NN + nc * 256 + tok) * 256 + h * 64 + ch8);
    }
    {
        const int d = t >> 2, p0 = (t & 3) * 16;
        const float rqv = 1.0f / fmaxf(sqrtf(nq2[b * 256 + h * 64 + d]), 1e-12f);
        const float t2 = temp2[h];
        const float* kr = kp + (size_t)(b * 256 + h * 64 + d) * 64 + p0;
        #pragma unroll
        for (int j = 0; j < 16; ++j)
            KT[(p0 + j) * 64 + d] = f2bf(kr[j] * rqv * t2);
    }
    {
        const float* vs = vp + (size_t)(b * 256 + h * 64) * 64;
        #pragma unroll
        for (int i = 0; i < 2; ++i) {
            int c = i * 256 + t;
            bf16x8 v;
            #pragma unroll
            for (int j = 0; j < 8; ++j) v[j] = (short)f2bf(vs[c * 8 + j]);
            *(bf16x8*)&VT[c * 8] = v;
        }
    }
    __syncthreads();

    f32x4 acc[4][4];
    #pragma unroll
    for (int i = 0; i < 4; ++i)
        #pragma unroll
        for (int j = 0; j < 4; ++j) acc[i][j] = (f32x4){0.f, 0.f, 0.f, 0.f};
    #pragma unroll
    for (int ks = 0; ks < 2; ++ks) {
        bf16x8 a[4], bb[4];
        #pragma unroll
        for (int fm = 0; fm < 4; ++fm)
            a[fm] = *(const bf16x8*)&Qs[(w * 64 + fm * 16 + fr) * 64 + ks * 32 + fk];
        #pragma unroll
        for (int fn = 0; fn < 4; ++fn)
            bb[fn] = *(const bf16x8*)&KT[(fn * 16 + fr) * 64 + ks * 32 + fk];
        #pragma unroll
        for (int fm = 0; fm < 4; ++fm)
            #pragma unroll
            for (int fn = 0; fn < 4; ++fn)
                acc[fm][fn] = __builtin_amdgcn_mfma_f32_16x16x32_bf16(
                    a[fm], bb[fn], acc[fm][fn], 0, 0, 0);
    }
    __syncthreads();

    u16* Pw = Qs + w * 4096;
    #pragma unroll
    for (int fm = 0; fm < 4; ++fm) {
        #pragma unroll
        for (int r = 0; r < 4; ++r) {
            float m = fmaxf(fmaxf(acc[fm][0][r], acc[fm][1][r]),
                            fmaxf(acc[fm][2][r], acc[fm][3][r]));
            m = fmaxf(m, __shfl_xor(m, 1));
            m = fmaxf(m, __shfl_xor(m, 2));
            m = fmaxf(m, __shfl_xor(m, 4));
            m = fmaxf(m, __shfl_xor(m, 8));
            float e0 = __expf(acc[fm][0][r] - m), e1 = __expf(acc[fm][1][r] - m);
            float e2 = __expf(acc[fm][2][r] - m), e3 = __expf(acc[fm][3][r] - m);
            float s = e0 + e1 + e2 + e3;
            s += __shfl_xor(s, 1); s += __shfl_xor(s, 2);
            s += __shfl_xor(s, 4); s += __shfl_xor(s, 8);
            float rs = 1.0f / s;
            int row = fm * 16 + r0 + r;
            Pw[row * 64 +  0 + fr] = f2bf(e0 * rs);
            Pw[row * 64 + 16 + fr] = f2bf(e1 * rs);
            Pw[row * 64 + 32 + fr] = f2bf(e2 * rs);
            Pw[row * 64 + 48 + fr] = f2bf(e3 * rs);
        }
    }

    f32x4 acc2[4][4];
    #pragma unroll
    for (int i = 0; i < 4; ++i)
        #pragma unroll
        for (int j = 0; j < 4; ++j) acc2[i][j] = (f32x4){0.f, 0.f, 0.f, 0.f};
    #pragma unroll
    for (int ks = 0; ks < 2; ++ks) {
        bf16x8 a[4], bb[4];
        #pragma unroll
        for (int fm = 0; fm < 4; ++fm)
            a[fm] = *(const bf16x8*)&Pw[(fm * 16 + fr) * 64 + ks * 32 + fk];
        #pragma unroll
        for (int fn = 0; fn < 4; ++fn)
            bb[fn] = *(const bf16x8*)&VT[(fn * 16 + fr) * 64 + ks * 32 + fk];
        #pragma unroll
        for (int fm = 0; fm < 4; ++fm)
            #pragma unroll
            for (int fn = 0; fn < 4; ++fn)
                acc2[fm][fn] = __builtin_amdgcn_mfma_f32_16x16x32_bf16(
                    a[fm], bb[fn], acc2[fm][fn], 0, 0, 0);
    }
    __syncthreads();

    u16* X2 = Qs;
    #pragma unroll
    for (int fm = 0; fm < 4; ++fm)
        #pragma unroll
        for (int fn = 0; fn < 4; ++fn)
            #pragma unroll
            for (int r = 0; r < 4; ++r)
                X2[(w * 64 + fm * 16 + r0 + r) * 64 + fn * 16 + fr] = f2bf(acc2[fm][fn][r]);
    __syncthreads();

    {
        const int d = t >> 2, cq = (t & 3) * 64;
        u16* orow = xsa + ((size_t)b * NN + d * 128 + h * 32 + nc) * 256 + cq;
        #pragma unroll
        for (int i = 0; i < 8; ++i) {
            bf16x8 v;
            #pragma unroll
            for (int j = 0; j < 8; ++j) v[j] = (short)X2[(cq + i * 8 + j) * 64 + d];
            *(bf16x8*)&orow[i * 8] = v;
        }
    }
}

// ================= combined output GEMMs (all-bf16, global_load_lds) =================
__global__ __launch_bounds__(256) void outgemm(
    const u16* __restrict__ xsa, const u16* __restrict__ xb,
    const u16* __restrict__ Wo1b, const u16* __restrict__ W2effb,
    const float* __restrict__ bo1, const float* __restrict__ bo2,
    float* __restrict__ out)
{
    __shared__ u16 As[4096];
    __shared__ u16 Bs[4096];
    const int z = blockIdx.z;
    const u16* A = z ? xb : xsa;
    const u16* Bt = z ? (W2effb + (size_t)(blockIdx.x >> 6) * 128 * 256) : Wo1b;
    const float* bias = z ? bo2 : bo1;
    const int outoff = z ? 128 : 0;
    const int t = threadIdx.x, lane = t & 63, w = t >> 6;
    const int wr = w >> 1, wc = w & 1;
    const int fr = lane & 15, fk = (lane >> 4) * 8, r0 = (lane >> 4) * 4;
    const int m0 = blockIdx.x * 128;
    const int row0 = t >> 2, k80 = (t & 3) * 8;
    const int row1 = (256 + t) >> 2, k81 = ((256 + t) & 3) * 8;

    f32x4 acc[4][4];
    #pragma unroll
    for (int i = 0; i < 4; ++i)
        #pragma unroll
        for (int j = 0; j < 4; ++j) acc[i][j] = (f32x4){0.f, 0.f, 0.f, 0.f};

    for (int kt = 0; kt < 8; ++kt) {
        const int k0 = kt * 32;
        gl16(A  + (size_t)(m0 + row0) * 256 + k0 + k80, &As[t * 8]);
        gl16(A  + (size_t)(m0 + row1) * 256 + k0 + k81, &As[(256 + t) * 8]);
        gl16(Bt + (size_t)row0 * 256 + k0 + k80, &Bs[t * 8]);
        gl16(Bt + (size_t)row1 * 256 + k0 + k81, &Bs[(256 + t) * 8]);
        __syncthreads();
        bf16x8 a[4], b[4];
        #pragma unroll
        for (int fm = 0; fm < 4; ++fm)
            a[fm] = *(const bf16x8*)&As[(wr * 64 + fm * 16 + fr) * 32 + fk];
        #pragma unroll
        for (int fn = 0; fn < 4; ++fn)
            b[fn] = *(const bf16x8*)&Bs[(wc * 64 + fn * 16 + fr) * 32 + fk];
        #pragma unroll
        for (int fm = 0; fm < 4; ++fm)
            #pragma unroll
            for (int fn = 0; fn < 4; ++fn)
                acc[fm][fn] = __builtin_amdgcn_mfma_f32_16x16x32_bf16(
                    a[fm], b[fn], acc[fm][fn], 0, 0, 0);
        __syncthreads();
    }

    #pragma unroll
    for (int fm = 0; fm < 4; ++fm)
        #pragma unroll
        for (int fn = 0; fn < 4; ++fn) {
            int gcol = wc * 64 + fn * 16 + fr;   // 0..127
            #pragma unroll
            for (int r = 0; r < 4; ++r) {
                size_t grow = (size_t)(m0 + wr * 64 + fm * 16 + r0 + r);
                out[grow * 256 + outoff + gcol] = acc[fm][fn][r] + bias[gcol];
            }
        }
}

extern "C" void kernel_launch(void* const* d_in, const int* in_sizes, int n_in,
                              void* d_out, int out_size, void* d_ws, size_t ws_size,
                              hipStream_t stream) {
    float* out = (float*)d_out;

    static const int expect[14] = {8388608, 8388608, 65536, 65536, 65536, 65536,
                                   524288, 64, 4, 4, 32768, 128, 32768, 128};
    bool ok = (n_in == 14) && (out_size == 8388608);
    if (ok) for (int i = 0; i < 14; ++i) ok = ok && (in_sizes[i] == expect[i]);
    if (!ok) {
        fill_kernel<<<dim3(8192), 256, 0, stream>>>(out, 3000.0f);
        return;
    }
    if (ws_size < 80000000u) {
        fill_kernel<<<dim3(8192), 256, 0, stream>>>(out, 1000.0f);
        return;
    }

    const float* x    = (const float*)d_in[0];
    const float* q    = (const float*)d_in[1];
    const float* Wq   = (const float*)d_in[2];
    const float* Wk   = (const float*)d_in[3];
    const float* Wvca = (const float*)d_in[4];
    const float* Wvsa = (const float*)d_in[5];
    const float* Ew   = (const float*)d_in[6];
    const float* Eb   = (const float*)d_in[7];
    const float* temp = (const float*)d_in[8];
    const float* temp2= (const float*)d_in[9];
    const float* Wo1  = (const float*)d_in[10];
    const float* bo1  = (const float*)d_in[11];
    const float* Wo2  = (const float*)d_in[12];
    const float* bo2  = (const float*)d_in[13];

    u16* Qb   = (u16*)d_ws;
    u16* Kb   = Qb + (size_t)BNC;        // reused as xsa after calog (stream-ordered)
    u16* qb   = Kb + (size_t)BNC;
    u16* xb   = qb + (size_t)BNC;
    u16* Wqb  = xb + (size_t)BNC;        // 65536
    u16* Wkb  = Wqb + 65536;             // 65536
    u16* Wo1b = Wkb + 65536;             // 32768
    u16* Ewb  = Wo1b + 32768;            // 524288
    u16* W2effb = Ewb + 524288;          // 131072
    u16* xsa  = Kb;
    float* fs    = (float*)(W2effb + 131072);
    float* nq2   = fs;                   // 1024
    float* nk2   = nq2 + 1024;           // 1024
    float* xE    = nk2 + 1024;           // 65536
    float* kp    = xE + 65536;           // 65536 (no aliasing)
    float* vp    = kp + 65536;           // 65536
    float* caprob= vp + 65536;           // 65536
    float* cpart = caprob + 65536;       // 524288 (8 x 65536)

    zeroconv_kernel<<<dim3(8792), 256, 0, stream>>>(q, x, Wq, Wk, Wo1, Ew,
                                                    qb, xb, Wqb, Wkb, Wo1b, Ewb, nq2);
    gemm_qkf<<<dim3(256, 2, 2), 256, 0, stream>>>(qb, xb, Wqb, Wkb, Qb, Kb, nq2, nk2);
    xecalog_kernel<<<dim3(256), 256, 0, stream>>>(xb, Ewb, xE, Qb, Kb, cpart);
    smkv_kernel<<<dim3(3072), 64, 0, stream>>>(cpart, nq2, nk2, temp, caprob,
                                               Wk, Wvsa, xE, Eb, kp, vp);
    samw_kernel<<<dim3(1024), 256, 0, stream>>>(Qb, kp, vp, nq2, temp2, xsa,
                                                caprob, Wo2, Wvca, W2effb);
    outgemm<<<dim3(256, 1, 2), 256, 0, stream>>>(xsa, xb, Wo1b, W2effb, bo1, bo2, out);
}